// Round 4
// baseline (2772.264 us; speedup 1.0000x reference)
//
#include <hip/hip_runtime.h>
#include <cstdint>
#include <cstddef>

// GAAPModelB: x->embed->SAGE1->SAGE2->global attention->MLP head. All fp32.
// N=100000 nodes, E=800000 edges, IN=128, H=256, G=512.
// Chunked post-SAGE1 pipeline (~174MB ws); Q folded into WqKT = Wq @ Kmat^T.
// Edge dtype (int32 vs int64) detected at runtime on device.

#define NN 100000
#define NE 800000
#define CR 12800   // chunk rows

// ------------------------------ utility ------------------------------
__global__ void zero_i32_k(int* __restrict__ p, int n) {
  int i = blockIdx.x * 256 + threadIdx.x;
  if (i < n) p[i] = 0;
}

// flag=1 iff edge_index is int64 (odd int32 words of first 256 entries all 0)
__global__ void detect_i64_k(const int* __restrict__ ei, int* __restrict__ flag) {
  int i64 = 1;
  for (int i = 0; i < 256; ++i) {
    if (ei[2 * i + 1] != 0) { i64 = 0; break; }
  }
  *flag = i64;
}

// ------------------------------ CSR build ------------------------------
// int32 layout: src[i]=ei[i], dst[i]=ei[E+i]
// int64 layout: src[i]=ei[2i], dst[i]=ei[2E+2i]  (low words; high words are 0)
__global__ void count_edges_k(const int* __restrict__ ei, const int* __restrict__ flag,
                              int* __restrict__ cnt, int E) {
  int i = blockIdx.x * 256 + threadIdx.x;
  if (i >= E) return;
  const bool i64 = (*flag != 0);
  unsigned d = (unsigned)(i64 ? ei[2 * E + 2 * i] : ei[E + i]);
  if (d < NN) atomicAdd(&cnt[d], 1);
}

// single-block 1024-thread chunked Hillis-Steele inclusive scan over N=100k
__global__ __launch_bounds__(1024)
void scan_k(const int* __restrict__ cnt, int* __restrict__ rowptr,
            int* __restrict__ cursor, int n) {
  __shared__ int buf[1024];
  __shared__ int carry_s;
  const int t = threadIdx.x;
  if (t == 0) { carry_s = 0; rowptr[0] = 0; }
  __syncthreads();
  for (int base = 0; base < n; base += 1024) {
    int i = base + t;
    int v = (i < n) ? cnt[i] : 0;
    buf[t] = v;
    __syncthreads();
    int x = v;
    for (int off = 1; off < 1024; off <<= 1) {
      int add = (t >= off) ? buf[t - off] : 0;
      __syncthreads();
      x += add;
      buf[t] = x;
      __syncthreads();
    }
    int incl = x + carry_s;
    if (i < n) { rowptr[i + 1] = incl; cursor[i] = incl - v; }
    __syncthreads();
    if (t == 1023) carry_s = incl;
    __syncthreads();
  }
}

__global__ void fill_edges_k(const int* __restrict__ ei, const int* __restrict__ flag,
                             int* __restrict__ cursor, int* __restrict__ eidx, int E) {
  int i = blockIdx.x * 256 + threadIdx.x;
  if (i >= E) return;
  const bool i64 = (*flag != 0);
  unsigned s = (unsigned)(i64 ? ei[2 * i] : ei[i]);
  unsigned d = (unsigned)(i64 ? ei[2 * E + 2 * i] : ei[E + i]);
  if (d < NN && s < NN) {
    int p = atomicAdd(&cursor[d], 1);
    if ((unsigned)p < (unsigned)E) eidx[p] = (int)s;
  }
}

// ------------------------------ aggregation (gather, CSR) ------------------------------
// mean over in-neighbors, 64-dim rows: one wave per node, lane = dim
__global__ void agg64_k(const float* __restrict__ X, const int* __restrict__ rowptr,
                        const int* __restrict__ eidx, float* __restrict__ mean,
                        int r0, int M) {
  int nl = blockIdx.x * 4 + (threadIdx.x >> 6);
  int lane = threadIdx.x & 63;
  if (nl >= M) return;
  int node = r0 + nl;
  int s = rowptr[node], e = rowptr[node + 1];
  float acc = 0.f;
  for (int i = s; i < e; ++i) {
    unsigned sc = (unsigned)eidx[i];
    if (sc < NN) acc += X[(size_t)sc * 64 + lane];
  }
  float inv = 1.f / (float)max(e - s, 1);
  mean[(size_t)nl * 64 + lane] = acc * inv;
}

// 256-dim rows: wave per node, lane holds float4 (1KB coalesced row reads)
__global__ void agg256_k(const float* __restrict__ X, const int* __restrict__ rowptr,
                         const int* __restrict__ eidx, float* __restrict__ mean,
                         int r0, int M) {
  int nl = blockIdx.x * 4 + (threadIdx.x >> 6);
  int lane = threadIdx.x & 63;
  if (nl >= M) return;
  int node = r0 + nl;
  int s = rowptr[node], e = rowptr[node + 1];
  float4 acc = make_float4(0.f, 0.f, 0.f, 0.f);
  for (int i = s; i < e; ++i) {
    unsigned sc = (unsigned)eidx[i];
    if (sc < NN) {
      const float4 v = ((const float4*)(X + (size_t)sc * 256))[lane];
      acc.x += v.x; acc.y += v.y; acc.z += v.z; acc.w += v.w;
    }
  }
  float inv = 1.f / (float)max(e - s, 1);
  acc.x *= inv; acc.y *= inv; acc.z *= inv; acc.w *= inv;
  ((float4*)(mean + (size_t)nl * 256))[lane] = acc;
}

// ------------------------------ generic fp32 GEMM ------------------------------
// C[M,Nc] = act(A1@B1 + (A2?A2@B2:0) + bias). BM=128, BN=64, BK=16, 256 thr, 8x4 micro.
// BT: B stored row-major [Nc,K] (used for WqKT = Wq @ Kmat^T).
template<bool RELU, bool BT>
__global__ __launch_bounds__(256)
void gemm_dual_k(const float* __restrict__ A1, const float* __restrict__ B1, int K1,
                 const float* __restrict__ A2, const float* __restrict__ B2, int K2,
                 const float* __restrict__ bias, float* __restrict__ C, int M, int Nc) {
  __shared__ float As[16][136];
  __shared__ float Bs[16][72];
  const int tid = threadIdx.x;
  const int tx = tid & 15;   // 16 col groups * 4
  const int ty = tid >> 4;   // 16 row groups * 8
  const int bm = blockIdx.x * 128;
  const int bn = blockIdx.y * 64;
  float acc[8][4];
#pragma unroll
  for (int i = 0; i < 8; ++i)
#pragma unroll
    for (int j = 0; j < 4; ++j) acc[i][j] = 0.f;

  for (int pass = 0; pass < 2; ++pass) {
    const float* A = pass ? A2 : A1;
    const float* B = pass ? B2 : B1;
    const int K = pass ? K2 : K1;
    if (A == nullptr) break;
    for (int k0 = 0; k0 < K; k0 += 16) {
      // A tile: 128 rows x 16 k, stored transposed As[k][row]
      {
        const int r0 = tid >> 2;          // 0..63
        const int c = (tid & 3) * 4;      // 0,4,8,12
#pragma unroll
        for (int h = 0; h < 2; ++h) {
          int r = r0 + h * 64;
          int row = bm + r;
          float4 v = make_float4(0.f, 0.f, 0.f, 0.f);
          if (row < M) v = *(const float4*)(A + (size_t)row * K + (k0 + c));
          As[c + 0][r] = v.x; As[c + 1][r] = v.y; As[c + 2][r] = v.z; As[c + 3][r] = v.w;
        }
      }
      if (!BT) {
        const int kk = tid >> 4;          // 0..15
        const int nn = (tid & 15) * 4;    // 0..60
        float4 v = *(const float4*)(B + (size_t)(k0 + kk) * Nc + (bn + nn));
        Bs[kk][nn + 0] = v.x; Bs[kk][nn + 1] = v.y; Bs[kk][nn + 2] = v.z; Bs[kk][nn + 3] = v.w;
      } else {
        const int n = tid >> 2;           // 0..63
        const int c = (tid & 3) * 4;
        float4 v = *(const float4*)(B + (size_t)(bn + n) * K + (k0 + c));
        Bs[c + 0][n] = v.x; Bs[c + 1][n] = v.y; Bs[c + 2][n] = v.z; Bs[c + 3][n] = v.w;
      }
      __syncthreads();
#pragma unroll
      for (int kk = 0; kk < 16; ++kk) {
        float a[8], b[4];
        *(float4*)&a[0] = *(const float4*)&As[kk][ty * 8];
        *(float4*)&a[4] = *(const float4*)&As[kk][ty * 8 + 4];
        *(float4*)&b[0] = *(const float4*)&Bs[kk][tx * 4];
#pragma unroll
        for (int i = 0; i < 8; ++i)
#pragma unroll
          for (int j = 0; j < 4; ++j)
            acc[i][j] = fmaf(a[i], b[j], acc[i][j]);
      }
      __syncthreads();
    }
  }
  float bv[4] = {0.f, 0.f, 0.f, 0.f};
  if (bias) *(float4*)bv = *(const float4*)(bias + bn + tx * 4);
#pragma unroll
  for (int i = 0; i < 8; ++i) {
    int row = bm + ty * 8 + i;
    if (row < M) {
      float4 o;
      o.x = acc[i][0] + bv[0]; o.y = acc[i][1] + bv[1];
      o.z = acc[i][2] + bv[2]; o.w = acc[i][3] + bv[3];
      if (RELU) {
        o.x = fmaxf(o.x, 0.f); o.y = fmaxf(o.y, 0.f);
        o.z = fmaxf(o.z, 0.f); o.w = fmaxf(o.w, 0.f);
      }
      *(float4*)(C + (size_t)row * Nc + bn + tx * 4) = o;
    }
  }
}

// ------------------------------ sbias[g] = dot(bq, Kmat[g]) ------------------------------
__global__ void sbias_k(const float* __restrict__ bq, const float* __restrict__ Kmat,
                        float* __restrict__ sbias) {
  int g = blockIdx.x * 4 + (threadIdx.x >> 6);
  int lane = threadIdx.x & 63;
  if (g >= 512) return;
  float4 kv = ((const float4*)(Kmat + (size_t)g * 256))[lane];
  float4 bv = ((const float4*)bq)[lane];
  float p = kv.x * bv.x + kv.y * bv.y + kv.z * bv.z + kv.w * bv.w;
  for (int off = 32; off; off >>= 1) p += __shfl_xor(p, off);
  if (lane == 0) sbias[g] = p;
}

// ------------------------------ row softmax over 512 logits ------------------------------
__global__ void softmax_rows_k(float* __restrict__ S, int M) {
  int row = blockIdx.x * 4 + (threadIdx.x >> 6);
  int lane = threadIdx.x & 63;
  if (row >= M) return;
  float4* p = (float4*)(S + (size_t)row * 512);
  float4 a = p[lane];
  float4 b = p[lane + 64];
  const float sc = 0.0625f;  // 1/sqrt(256)
  a.x *= sc; a.y *= sc; a.z *= sc; a.w *= sc;
  b.x *= sc; b.y *= sc; b.z *= sc; b.w *= sc;
  float m = fmaxf(fmaxf(fmaxf(a.x, a.y), fmaxf(a.z, a.w)),
                  fmaxf(fmaxf(b.x, b.y), fmaxf(b.z, b.w)));
  for (int off = 32; off; off >>= 1) m = fmaxf(m, __shfl_xor(m, off));
  a.x = expf(a.x - m); a.y = expf(a.y - m); a.z = expf(a.z - m); a.w = expf(a.w - m);
  b.x = expf(b.x - m); b.y = expf(b.y - m); b.z = expf(b.z - m); b.w = expf(b.w - m);
  float s = a.x + a.y + a.z + a.w + b.x + b.y + b.z + b.w;
  for (int off = 32; off; off >>= 1) s += __shfl_xor(s, off);
  float inv = 1.f / s;
  a.x *= inv; a.y *= inv; a.z *= inv; a.w *= inv;
  b.x *= inv; b.y *= inv; b.z *= inv; b.w *= inv;
  p[lane] = a; p[lane + 64] = b;
}

// ------------------------------ final head: out = hidden @ Wm2 + bm2 ------------------------------
__global__ void out_k(const float* __restrict__ hidden, const float* __restrict__ Wm2,
                      const float* __restrict__ bm2, float* __restrict__ out, int M) {
  int row = blockIdx.x * 4 + (threadIdx.x >> 6);
  int lane = threadIdx.x & 63;
  if (row >= M) return;
  float4 hv = ((const float4*)(hidden + (size_t)row * 256))[lane];
  int k = lane * 4;
  float p0 = hv.x * Wm2[(k + 0) * 2 + 0] + hv.y * Wm2[(k + 1) * 2 + 0] +
             hv.z * Wm2[(k + 2) * 2 + 0] + hv.w * Wm2[(k + 3) * 2 + 0];
  float p1 = hv.x * Wm2[(k + 0) * 2 + 1] + hv.y * Wm2[(k + 1) * 2 + 1] +
             hv.z * Wm2[(k + 2) * 2 + 1] + hv.w * Wm2[(k + 3) * 2 + 1];
  for (int off = 32; off; off >>= 1) {
    p0 += __shfl_xor(p0, off);
    p1 += __shfl_xor(p1, off);
  }
  if (lane == 0) {
    out[(size_t)row * 2 + 0] = p0 + bm2[0];
    out[(size_t)row * 2 + 1] = p1 + bm2[1];
  }
}

// ------------------------------ launch ------------------------------
extern "C" void kernel_launch(void* const* d_in, const int* in_sizes, int n_in,
                              void* d_out, int out_size, void* d_ws, size_t ws_size,
                              hipStream_t stream) {
  const int N = NN, E = NE;
  const float* x   = (const float*)d_in[0];
  const int*   ei  = (const int*)d_in[1];
  const float* gc  = (const float*)d_in[2];
  const float* Wp  = (const float*)d_in[3];
  const float* bp  = (const float*)d_in[4];
  const float* W1l = (const float*)d_in[5];
  const float* b1l = (const float*)d_in[6];
  const float* W1r = (const float*)d_in[7];
  const float* W2l = (const float*)d_in[8];
  const float* b2l = (const float*)d_in[9];
  const float* W2r = (const float*)d_in[10];
  const float* Wq  = (const float*)d_in[11];
  const float* bq  = (const float*)d_in[12];
  const float* Wk  = (const float*)d_in[13];
  const float* bk  = (const float*)d_in[14];
  const float* Wv  = (const float*)d_in[15];
  const float* bv  = (const float*)d_in[16];
  const float* Wm1 = (const float*)d_in[17];
  const float* bm1 = (const float*)d_in[18];
  const float* Wm2 = (const float*)d_in[19];
  const float* bm2 = (const float*)d_in[20];
  float* out = (float*)d_out;

  // workspace layout — peak ~174MB
  char* base = (char*)d_ws;
  size_t off = 0;
  auto take = [&](size_t bytes) -> void* {
    void* r = base + off;
    off += (bytes + 255) & ~(size_t)255;
    return r;
  };
  int* cnt    = (int*)take((size_t)N * 4);
  int* rowptr = (int*)take((size_t)(N + 1) * 4);
  int* cursor = (int*)take((size_t)N * 4);
  int* eidx   = (int*)take((size_t)E * 4);
  int* eflag  = (int*)take(256);
  float* Kmat = (float*)take((size_t)512 * 256 * 4);
  float* Vmat = (float*)take((size_t)512 * 256 * 4);
  float* WqKT = (float*)take((size_t)256 * 512 * 4);
  float* sbias = (float*)take((size_t)512 * 4);
  float* h    = (float*)take((size_t)N * 256 * 4);          // full-size, live whole run
  float* ch   = (float*)take((size_t)CR * 1280 * 4);        // chunk region (65.5MB)
  if (off > ws_size) return;  // insufficient scratch -> clean absmax failure, not a fault

  // chunk-region sublayout (h2_c | S_c | g_c | hidden_c); pre-loop overlays:
  float* h2_c     = ch;
  float* S_c      = ch + (size_t)CR * 256;
  float* g_c      = ch + (size_t)CR * 768;
  float* hidden_c = ch + (size_t)CR * 1024;
  float* mean2_c  = S_c;                    // dead before S_c written
  float* x_emb    = ch;                     // pre-loop only
  float* mean1    = ch + (size_t)N * 64;    // pre-loop only

  const int MB = (N + 127) / 128;
  dim3 thr(256);

  // CSR build
  zero_i32_k<<<(N + 255) / 256, thr, 0, stream>>>(cnt, N);
  detect_i64_k<<<1, 1, 0, stream>>>(ei, eflag);
  count_edges_k<<<(E + 255) / 256, thr, 0, stream>>>(ei, eflag, cnt, E);
  scan_k<<<1, 1024, 0, stream>>>(cnt, rowptr, cursor, N);
  fill_edges_k<<<(E + 255) / 256, thr, 0, stream>>>(ei, eflag, cursor, eidx, E);

  // x_emb = relu(x @ Wp + bp)            [N,128]@[128,64]
  gemm_dual_k<true, false><<<dim3(MB, 1), thr, 0, stream>>>(
      x, Wp, 128, nullptr, nullptr, 0, bp, x_emb, N, 64);
  // SAGE1: h = relu(mean1 @ W1l + x_emb @ W1r + b1l)
  agg64_k<<<(N + 3) / 4, thr, 0, stream>>>(x_emb, rowptr, eidx, mean1, 0, N);
  gemm_dual_k<true, false><<<dim3(MB, 4), thr, 0, stream>>>(
      mean1, W1l, 64, x_emb, W1r, 64, b1l, h, N, 256);

  // attention preprocessing (node-independent)
  gemm_dual_k<false, false><<<dim3(4, 4), thr, 0, stream>>>(
      gc, Wk, 256, nullptr, nullptr, 0, bk, Kmat, 512, 256);
  gemm_dual_k<false, false><<<dim3(4, 4), thr, 0, stream>>>(
      gc, Wv, 256, nullptr, nullptr, 0, bv, Vmat, 512, 256);
  gemm_dual_k<false, true><<<dim3(2, 8), thr, 0, stream>>>(
      Wq, Kmat, 256, nullptr, nullptr, 0, nullptr, WqKT, 256, 512);  // Wq @ Kmat^T
  sbias_k<<<128, thr, 0, stream>>>(bq, Kmat, sbias);

  // chunked: SAGE2 + attention + MLP head, rows [r0, r0+CRc)
  for (int r0 = 0; r0 < N; r0 += CR) {
    const int CRc = (N - r0 < CR) ? (N - r0) : CR;
    const int MBc = (CRc + 127) / 128;
    // mean2_c = mean aggregate of h over in-neighbors
    agg256_k<<<(CRc + 3) / 4, thr, 0, stream>>>(h, rowptr, eidx, mean2_c, r0, CRc);
    // h2_c = mean2_c @ W2l + h[r0:] @ W2r + b2l       (no relu)
    gemm_dual_k<false, false><<<dim3(MBc, 4), thr, 0, stream>>>(
        mean2_c, W2l, 256, h + (size_t)r0 * 256, W2r, 256, b2l, h2_c, CRc, 256);
    // S_c = h2_c @ WqKT + sbias                        [CRc,512]
    gemm_dual_k<false, false><<<dim3(MBc, 8), thr, 0, stream>>>(
        h2_c, WqKT, 256, nullptr, nullptr, 0, sbias, S_c, CRc, 512);
    // softmax rows (scale 1/16 inside)
    softmax_rows_k<<<(CRc + 3) / 4, thr, 0, stream>>>(S_c, CRc);
    // g_c = P @ V
    gemm_dual_k<false, false><<<dim3(MBc, 4), thr, 0, stream>>>(
        S_c, Vmat, 512, nullptr, nullptr, 0, nullptr, g_c, CRc, 256);
    // hidden_c = relu(h2_c @ Wm1[0:256] + g_c @ Wm1[256:512] + bm1)
    gemm_dual_k<true, false><<<dim3(MBc, 4), thr, 0, stream>>>(
        h2_c, Wm1, 256, g_c, Wm1 + 256 * 256, 256, bm1, hidden_c, CRc, 256);
    // out rows
    out_k<<<(CRc + 3) / 4, thr, 0, stream>>>(hidden_c, Wm2, bm2, out + (size_t)r0 * 2, CRc);
  }
}

// Round 5
// 1216.252 us; speedup vs baseline: 2.2794x; 2.2794x over previous
//
#include <hip/hip_runtime.h>
#include <cstdint>
#include <cstddef>

// GAAPModelB on MI355X: bf16-MFMA GEMM stack + CSR gather aggregation.
// N=100000, E=800000, IN=128, H=256, G=512. Chunked post-SAGE1 pipeline.

#define NN 100000
#define NE 800000
#define CR 12800   // chunk rows
#define NB1 98     // ceil(100000/1024) scan blocks

typedef __attribute__((ext_vector_type(8))) short short8;
typedef __attribute__((ext_vector_type(4))) float f32x4;

__device__ __forceinline__ float b2f(ushort u) {
  union { unsigned u; float f; } v; v.u = ((unsigned)u) << 16; return v.f;
}
__device__ __forceinline__ ushort f2b(float f) {
  union { float f; unsigned u; } v; v.f = f;
  unsigned r = v.u + 0x7FFFu + ((v.u >> 16) & 1u);
  return (ushort)(r >> 16);
}
__device__ __forceinline__ void gl_lds16(const void* g, void* l) {
  __builtin_amdgcn_global_load_lds((const __attribute__((address_space(1))) void*)g,
                                   (__attribute__((address_space(3))) void*)l, 16, 0, 0);
}

// ------------------------------ utility ------------------------------
__global__ void zero_i32_k(int* __restrict__ p, int n) {
  int i = blockIdx.x * 256 + threadIdx.x;
  if (i < n) p[i] = 0;
}

__global__ void detect_i64_k(const int* __restrict__ ei, int* __restrict__ flag) {
  int i64 = 1;
  for (int i = 0; i < 256; ++i) {
    if (ei[2 * i + 1] != 0) { i64 = 0; break; }
  }
  *flag = i64;
}

// f32 -> bf16 flat, 4 elems/thread
__global__ void cvt4_k(const float* __restrict__ src, ushort* __restrict__ dst, int n4) {
  int i = blockIdx.x * 256 + threadIdx.x;
  if (i < n4) {
    float4 v = ((const float4*)src)[i];
    ushort4 o; o.x = f2b(v.x); o.y = f2b(v.y); o.z = f2b(v.z); o.w = f2b(v.w);
    ((ushort4*)dst)[i] = o;
  }
}

// transpose-convert: dst[c*R + r] = bf16(src[(row_off+r)*C + c])   (dst is [C,R])
__global__ void tcvt_k(const float* __restrict__ src, ushort* __restrict__ dst,
                       int R, int C, int row_off) {
  int i = blockIdx.x * 256 + threadIdx.x;
  if (i < R * C) {
    int r = i / C, c = i % C;
    dst[(size_t)c * R + r] = f2b(src[(size_t)(row_off + r) * C + c]);
  }
}

// ------------------------------ CSR build ------------------------------
__global__ void count_edges_k(const int* __restrict__ ei, const int* __restrict__ flag,
                              int* __restrict__ cnt, int E) {
  int i = blockIdx.x * 256 + threadIdx.x;
  if (i >= E) return;
  const bool i64 = (*flag != 0);
  unsigned d = (unsigned)(i64 ? ei[2 * E + 2 * i] : ei[E + i]);
  if (d < NN) atomicAdd(&cnt[d], 1);
}

// hierarchical scan: 1024 elems/block
__global__ __launch_bounds__(256)
void scan1_k(const int* __restrict__ cnt, int* __restrict__ rowptr,
             int* __restrict__ bsum, int n) {
  __shared__ int ls[256];
  const int b = blockIdx.x, t = threadIdx.x;
  const int base = b * 1024 + t * 4;
  int v[4]; int s = 0;
#pragma unroll
  for (int j = 0; j < 4; ++j) { int i = base + j; v[j] = (i < n) ? cnt[i] : 0; s += v[j]; }
  ls[t] = s; __syncthreads();
  int x = s;
  for (int o = 1; o < 256; o <<= 1) {
    int a = (t >= o) ? ls[t - o] : 0; __syncthreads();
    x += a; ls[t] = x; __syncthreads();
  }
  int run = x - s;
#pragma unroll
  for (int j = 0; j < 4; ++j) { run += v[j]; int i = base + j; if (i < n) rowptr[i + 1] = run; }
  if (t == 255) bsum[b] = x;
}

__global__ void scan2_k(const int* __restrict__ bsum, int* __restrict__ boff, int nb) {
  __shared__ int ls[128];
  int t = threadIdx.x;
  int v = (t < nb) ? bsum[t] : 0;
  ls[t] = v; __syncthreads();
  int x = v;
  for (int o = 1; o < 128; o <<= 1) {
    int a = (t >= o) ? ls[t - o] : 0; __syncthreads();
    x += a; ls[t] = x; __syncthreads();
  }
  if (t < nb) boff[t] = x - v;
}

__global__ void scan3_k(const int* __restrict__ cnt, int* __restrict__ rowptr,
                        int* __restrict__ cursor, const int* __restrict__ boff, int n) {
  int i = blockIdx.x * 256 + threadIdx.x;
  if (i == 0) rowptr[0] = 0;
  if (i < n) {
    int r = rowptr[i + 1] + boff[i >> 10];
    rowptr[i + 1] = r;
    cursor[i] = r - cnt[i];
  }
}

__global__ void fill_edges_k(const int* __restrict__ ei, const int* __restrict__ flag,
                             int* __restrict__ cursor, int* __restrict__ eidx, int E) {
  int i = blockIdx.x * 256 + threadIdx.x;
  if (i >= E) return;
  const bool i64 = (*flag != 0);
  unsigned s = (unsigned)(i64 ? ei[2 * i] : ei[i]);
  unsigned d = (unsigned)(i64 ? ei[2 * E + 2 * i] : ei[E + i]);
  if (d < NN && s < NN) {
    int p = atomicAdd(&cursor[d], 1);
    if ((unsigned)p < (unsigned)E) eidx[p] = (int)s;
  }
}

// ------------------------------ aggregation (bf16 in/out, f32 accum) ------------------------------
__global__ void agg64_k(const ushort* __restrict__ X, const int* __restrict__ rowptr,
                        const int* __restrict__ eidx, ushort* __restrict__ mean,
                        int r0, int M) {
  int nl = blockIdx.x * 4 + (threadIdx.x >> 6);
  int lane = threadIdx.x & 63;
  if (nl >= M) return;
  int node = r0 + nl;
  int s = rowptr[node], e = rowptr[node + 1];
  float acc = 0.f;
  for (int i = s; i < e; ++i) {
    unsigned sc = (unsigned)eidx[i];
    if (sc < NN) acc += b2f(X[(size_t)sc * 64 + lane]);
  }
  float inv = 1.f / (float)max(e - s, 1);
  mean[(size_t)nl * 64 + lane] = f2b(acc * inv);
}

__global__ void agg256_k(const ushort* __restrict__ X, const int* __restrict__ rowptr,
                         const int* __restrict__ eidx, ushort* __restrict__ mean,
                         int r0, int M) {
  int nl = blockIdx.x * 4 + (threadIdx.x >> 6);
  int lane = threadIdx.x & 63;
  if (nl >= M) return;
  int node = r0 + nl;
  int s = rowptr[node], e = rowptr[node + 1];
  float a0 = 0.f, a1 = 0.f, a2 = 0.f, a3 = 0.f;
  for (int i = s; i < e; ++i) {
    unsigned sc = (unsigned)eidx[i];
    if (sc < NN) {
      ushort4 v = ((const ushort4*)(X + (size_t)sc * 256))[lane];
      a0 += b2f(v.x); a1 += b2f(v.y); a2 += b2f(v.z); a3 += b2f(v.w);
    }
  }
  float inv = 1.f / (float)max(e - s, 1);
  ushort4 o; o.x = f2b(a0 * inv); o.y = f2b(a1 * inv); o.z = f2b(a2 * inv); o.w = f2b(a3 * inv);
  ((ushort4*)(mean + (size_t)nl * 256))[lane] = o;
}

// ------------------------------ bf16 MFMA GEMM ------------------------------
// C[M,Nc] = act(A1@B1^T? ...): A [M,K] bf16 row-major, BT [Nc,K] bf16 row-major
// (BT[n][k] = B[k][n]), dual A/B pass, f32 bias, out f32 or bf16.
// BM=128, BN in {64,128}, BK=64, 256 thr = 4 waves (2x2), 16x16x32 MFMA.
// LDS tiles [rows][64] bf16 with XOR slot swizzle (kb ^= row&7), staged via
// global_load_lds w/ pre-swizzled global source (linear LDS dest).
template<int BN, bool RELU, bool OUTBF>
__global__ __launch_bounds__(256)
void mfma_gemm_k(const ushort* __restrict__ A1, const ushort* __restrict__ BT1, int K1,
                 const ushort* __restrict__ A2, const ushort* __restrict__ BT2, int K2,
                 const float* __restrict__ bias, void* __restrict__ Cv, int M, int Nc) {
  constexpr int NR = BN / 32;    // n-fragments per wave
  constexpr int WTN = BN / 2;    // wave tile cols
  __shared__ __align__(16) char As[128 * 64 * 2];
  __shared__ __align__(16) char Bs[BN * 64 * 2];
  const int tid = threadIdx.x;
  const int l = tid & 63;
  const int w = tid >> 6;
  const int wm = w >> 1, wn = w & 1;
  const int bm = blockIdx.x * 128, bn = blockIdx.y * BN;
  const int r15 = l & 15, g4 = l >> 4;

  f32x4 acc[4][NR];
  const f32x4 zz = {0.f, 0.f, 0.f, 0.f};
#pragma unroll
  for (int m = 0; m < 4; ++m)
#pragma unroll
    for (int n = 0; n < NR; ++n) acc[m][n] = zz;

  for (int pass = 0; pass < 2; ++pass) {
    const ushort* A = pass ? A2 : A1;
    const ushort* BT = pass ? BT2 : BT1;
    const int K = pass ? K2 : K1;
    if (!A) break;
    for (int k0 = 0; k0 < K; k0 += 64) {
      // stage A tile [128][64] bf16: 1024 x 16B, source pre-swizzled
#pragma unroll
      for (int p = 0; p < 4; ++p) {
        int idx = tid + p * 256;
        int row = idx >> 3, slot = idx & 7;
        int kb = slot ^ (row & 7);
        int grow = bm + row; if (grow >= M) grow = M - 1;
        gl_lds16(A + (size_t)grow * K + k0 + kb * 8, As + idx * 16);
      }
      // stage B tile [BN][64]
#pragma unroll
      for (int p = 0; p < BN / 32; ++p) {
        int idx = tid + p * 256;
        int row = idx >> 3, slot = idx & 7;
        int kb = slot ^ (row & 7);
        gl_lds16(BT + (size_t)(bn + row) * K + k0 + kb * 8, Bs + idx * 16);
      }
      __syncthreads();
#pragma unroll
      for (int s = 0; s < 2; ++s) {
        short8 a[4], b[NR];
        const int slotx = (((s * 4 + g4) ^ (r15 & 7)) << 4);
#pragma unroll
        for (int m = 0; m < 4; ++m) {
          int row = wm * 64 + m * 16 + r15;
          a[m] = *(const short8*)(As + row * 128 + slotx);
        }
#pragma unroll
        for (int n = 0; n < NR; ++n) {
          int row = wn * WTN + n * 16 + r15;
          b[n] = *(const short8*)(Bs + row * 128 + slotx);
        }
#pragma unroll
        for (int m = 0; m < 4; ++m)
#pragma unroll
          for (int n = 0; n < NR; ++n)
            acc[m][n] = __builtin_amdgcn_mfma_f32_16x16x32_bf16(a[m], b[n], acc[m][n], 0, 0, 0);
      }
      __syncthreads();
    }
  }
  // epilogue: D lane map col = l&15, row = (l>>4)*4 + j
#pragma unroll
  for (int n = 0; n < NR; ++n) {
    int col = bn + wn * WTN + n * 16 + r15;
    float bv = bias ? bias[col] : 0.f;
#pragma unroll
    for (int m = 0; m < 4; ++m) {
#pragma unroll
      for (int j = 0; j < 4; ++j) {
        int row = bm + wm * 64 + m * 16 + g4 * 4 + j;
        if (row < M) {
          float v = acc[m][n][j] + bv;
          if (RELU) v = fmaxf(v, 0.f);
          if (OUTBF) ((ushort*)Cv)[(size_t)row * Nc + col] = f2b(v);
          else       ((float*)Cv)[(size_t)row * Nc + col] = v;
        }
      }
    }
  }
}

// ------------------------------ sbias[g] = dot(bq, Kmat[g]) ------------------------------
__global__ void sbias_k(const float* __restrict__ bq, const ushort* __restrict__ Kmat,
                        float* __restrict__ sbias) {
  int g = blockIdx.x * 4 + (threadIdx.x >> 6);
  int lane = threadIdx.x & 63;
  if (g >= 512) return;
  ushort4 kv = ((const ushort4*)(Kmat + (size_t)g * 256))[lane];
  float4 bv = ((const float4*)bq)[lane];
  float p = b2f(kv.x) * bv.x + b2f(kv.y) * bv.y + b2f(kv.z) * bv.z + b2f(kv.w) * bv.w;
  for (int off = 32; off; off >>= 1) p += __shfl_xor(p, off);
  if (lane == 0) sbias[g] = p;
}

// ------------------------------ softmax (f32 in, bf16 out), scale 1/16 ------------------------------
__global__ void softmax_k(const float* __restrict__ S, ushort* __restrict__ P, int M) {
  int row = blockIdx.x * 4 + (threadIdx.x >> 6);
  int lane = threadIdx.x & 63;
  if (row >= M) return;
  const float4* p = (const float4*)(S + (size_t)row * 512);
  float4 a = p[lane];
  float4 b = p[lane + 64];
  const float sc = 0.0625f;
  a.x *= sc; a.y *= sc; a.z *= sc; a.w *= sc;
  b.x *= sc; b.y *= sc; b.z *= sc; b.w *= sc;
  float m = fmaxf(fmaxf(fmaxf(a.x, a.y), fmaxf(a.z, a.w)),
                  fmaxf(fmaxf(b.x, b.y), fmaxf(b.z, b.w)));
  for (int off = 32; off; off >>= 1) m = fmaxf(m, __shfl_xor(m, off));
  a.x = expf(a.x - m); a.y = expf(a.y - m); a.z = expf(a.z - m); a.w = expf(a.w - m);
  b.x = expf(b.x - m); b.y = expf(b.y - m); b.z = expf(b.z - m); b.w = expf(b.w - m);
  float s = a.x + a.y + a.z + a.w + b.x + b.y + b.z + b.w;
  for (int off = 32; off; off >>= 1) s += __shfl_xor(s, off);
  float inv = 1.f / s;
  ushort4 oa, ob;
  oa.x = f2b(a.x * inv); oa.y = f2b(a.y * inv); oa.z = f2b(a.z * inv); oa.w = f2b(a.w * inv);
  ob.x = f2b(b.x * inv); ob.y = f2b(b.y * inv); ob.z = f2b(b.z * inv); ob.w = f2b(b.w * inv);
  ushort4* q = (ushort4*)(P + (size_t)row * 512);
  q[lane] = oa;
  q[lane + 64] = ob;
}

// ------------------------------ final head ------------------------------
__global__ void out_k(const ushort* __restrict__ hidden, const float* __restrict__ Wm2,
                      const float* __restrict__ bm2, float* __restrict__ out, int M) {
  int row = blockIdx.x * 4 + (threadIdx.x >> 6);
  int lane = threadIdx.x & 63;
  if (row >= M) return;
  ushort4 hv = ((const ushort4*)(hidden + (size_t)row * 256))[lane];
  float h0 = b2f(hv.x), h1 = b2f(hv.y), h2 = b2f(hv.z), h3 = b2f(hv.w);
  int k = lane * 4;
  float p0 = h0 * Wm2[(k + 0) * 2 + 0] + h1 * Wm2[(k + 1) * 2 + 0] +
             h2 * Wm2[(k + 2) * 2 + 0] + h3 * Wm2[(k + 3) * 2 + 0];
  float p1 = h0 * Wm2[(k + 0) * 2 + 1] + h1 * Wm2[(k + 1) * 2 + 1] +
             h2 * Wm2[(k + 2) * 2 + 1] + h3 * Wm2[(k + 3) * 2 + 1];
  for (int off = 32; off; off >>= 1) {
    p0 += __shfl_xor(p0, off);
    p1 += __shfl_xor(p1, off);
  }
  if (lane == 0) {
    out[(size_t)row * 2 + 0] = p0 + bm2[0];
    out[(size_t)row * 2 + 1] = p1 + bm2[1];
  }
}

// ------------------------------ launch ------------------------------
extern "C" void kernel_launch(void* const* d_in, const int* in_sizes, int n_in,
                              void* d_out, int out_size, void* d_ws, size_t ws_size,
                              hipStream_t stream) {
  const int N = NN, E = NE;
  const float* x   = (const float*)d_in[0];
  const int*   ei  = (const int*)d_in[1];
  const float* gc  = (const float*)d_in[2];
  const float* Wp  = (const float*)d_in[3];
  const float* bp  = (const float*)d_in[4];
  const float* W1l = (const float*)d_in[5];
  const float* b1l = (const float*)d_in[6];
  const float* W1r = (const float*)d_in[7];
  const float* W2l = (const float*)d_in[8];
  const float* b2l = (const float*)d_in[9];
  const float* W2r = (const float*)d_in[10];
  const float* Wq  = (const float*)d_in[11];
  const float* bq  = (const float*)d_in[12];
  const float* Wk  = (const float*)d_in[13];
  const float* bk  = (const float*)d_in[14];
  const float* Wv  = (const float*)d_in[15];
  const float* bv  = (const float*)d_in[16];
  const float* Wm1 = (const float*)d_in[17];
  const float* bm1 = (const float*)d_in[18];
  const float* Wm2 = (const float*)d_in[19];
  const float* bm2 = (const float*)d_in[20];
  float* out = (float*)d_out;

  char* base = (char*)d_ws;
  size_t off = 0;
  auto take = [&](size_t bytes) -> void* {
    void* r = base + off;
    off += (bytes + 255) & ~(size_t)255;
    return r;
  };
  // CSR + misc
  int* cnt    = (int*)take((size_t)N * 4);
  int* rowptr = (int*)take((size_t)(N + 1) * 4);
  int* cursor = (int*)take((size_t)N * 4);
  int* eidx   = (int*)take((size_t)E * 4);
  int* eflag  = (int*)take(256);
  int* bsum   = (int*)take(NB1 * 4);
  int* boff   = (int*)take(NB1 * 4);
  // bf16 weights (transposed [Nc,K] unless noted)
  ushort* WpT   = (ushort*)take((size_t)64 * 128 * 2);
  ushort* W1lT  = (ushort*)take((size_t)256 * 64 * 2);
  ushort* W1rT  = (ushort*)take((size_t)256 * 64 * 2);
  ushort* W2lT  = (ushort*)take((size_t)256 * 256 * 2);
  ushort* W2rT  = (ushort*)take((size_t)256 * 256 * 2);
  ushort* WkT   = (ushort*)take((size_t)256 * 256 * 2);
  ushort* WvT   = (ushort*)take((size_t)256 * 256 * 2);
  ushort* Wqb   = (ushort*)take((size_t)256 * 256 * 2);   // plain cvt (acts as BT of Wq^T)
  ushort* Wm1aT = (ushort*)take((size_t)256 * 256 * 2);
  ushort* Wm1bT = (ushort*)take((size_t)256 * 256 * 2);
  // attention small
  ushort* gcb   = (ushort*)take((size_t)512 * 256 * 2);
  ushort* Kmatb = (ushort*)take((size_t)512 * 256 * 2);
  float*  Vmatf = (float*)take((size_t)512 * 256 * 4);
  ushort* VT    = (ushort*)take((size_t)256 * 512 * 2);
  ushort* KWqT  = (ushort*)take((size_t)512 * 256 * 2);
  float*  sbias = (float*)take((size_t)512 * 4);
  // shared region U: pre-loop {xb, x_emb, mean1} then chunk buffers
  const size_t szU_pre = (size_t)N * 128 * 2 + (size_t)N * 64 * 2 + (size_t)N * 64 * 2;
  const size_t szU_chunk = (size_t)CR * 5120;
  char* U = (char*)take(szU_pre > szU_chunk ? szU_pre : szU_chunk);
  ushort* h = (ushort*)take((size_t)N * 256 * 2);   // live across whole run
  if (off > ws_size) return;

  ushort* xb    = (ushort*)U;
  ushort* x_emb = (ushort*)(U + (size_t)N * 128 * 2);
  ushort* mean1 = (ushort*)(U + (size_t)N * 128 * 2 + (size_t)N * 64 * 2);
  ushort* mean2_c  = (ushort*)U;                                  // CR*256 bf16
  ushort* h2_c     = (ushort*)(U + (size_t)CR * 512);
  float*  S_c      = (float*)(U + (size_t)CR * 1024);             // CR*512 f32
  ushort* Pb_c     = (ushort*)(U + (size_t)CR * 3072);            // CR*512 bf16
  ushort* g_c      = (ushort*)(U + (size_t)CR * 4096);
  ushort* hidden_c = (ushort*)(U + (size_t)CR * 4608);

  const int MB = (N + 127) / 128;
  dim3 thr(256);

  // CSR build
  zero_i32_k<<<(N + 255) / 256, thr, 0, stream>>>(cnt, N);
  detect_i64_k<<<1, 1, 0, stream>>>(ei, eflag);
  count_edges_k<<<(E + 255) / 256, thr, 0, stream>>>(ei, eflag, cnt, E);
  scan1_k<<<NB1, thr, 0, stream>>>(cnt, rowptr, bsum, N);
  scan2_k<<<1, 128, 0, stream>>>(bsum, boff, NB1);
  scan3_k<<<(N + 255) / 256, thr, 0, stream>>>(cnt, rowptr, cursor, boff, N);
  fill_edges_k<<<(E + 255) / 256, thr, 0, stream>>>(ei, eflag, cursor, eidx, E);

  // convert inputs + weights to bf16
  cvt4_k<<<(N * 128 / 4 + 255) / 256, thr, 0, stream>>>(x, xb, N * 128 / 4);
  cvt4_k<<<(512 * 256 / 4 + 255) / 256, thr, 0, stream>>>(gc, gcb, 512 * 256 / 4);
  cvt4_k<<<(256 * 256 / 4 + 255) / 256, thr, 0, stream>>>(Wq, Wqb, 256 * 256 / 4);
  tcvt_k<<<(128 * 64 + 255) / 256, thr, 0, stream>>>(Wp, WpT, 128, 64, 0);
  tcvt_k<<<(64 * 256 + 255) / 256, thr, 0, stream>>>(W1l, W1lT, 64, 256, 0);
  tcvt_k<<<(64 * 256 + 255) / 256, thr, 0, stream>>>(W1r, W1rT, 64, 256, 0);
  tcvt_k<<<(256 * 256 + 255) / 256, thr, 0, stream>>>(W2l, W2lT, 256, 256, 0);
  tcvt_k<<<(256 * 256 + 255) / 256, thr, 0, stream>>>(W2r, W2rT, 256, 256, 0);
  tcvt_k<<<(256 * 256 + 255) / 256, thr, 0, stream>>>(Wk, WkT, 256, 256, 0);
  tcvt_k<<<(256 * 256 + 255) / 256, thr, 0, stream>>>(Wv, WvT, 256, 256, 0);
  tcvt_k<<<(256 * 256 + 255) / 256, thr, 0, stream>>>(Wm1, Wm1aT, 256, 256, 0);
  tcvt_k<<<(256 * 256 + 255) / 256, thr, 0, stream>>>(Wm1, Wm1bT, 256, 256, 256);

  // attention pre: Kmat(bf16), Vmat(f32->VT), KWqT = Kmat @ Wq^T, sbias
  mfma_gemm_k<128, false, true><<<dim3(4, 2), thr, 0, stream>>>(
      gcb, WkT, 256, nullptr, nullptr, 0, bk, Kmatb, 512, 256);
  mfma_gemm_k<128, false, false><<<dim3(4, 2), thr, 0, stream>>>(
      gcb, WvT, 256, nullptr, nullptr, 0, bv, Vmatf, 512, 256);
  tcvt_k<<<(512 * 256 + 255) / 256, thr, 0, stream>>>(Vmatf, VT, 512, 256, 0);
  mfma_gemm_k<128, false, true><<<dim3(4, 2), thr, 0, stream>>>(
      Kmatb, Wqb, 256, nullptr, nullptr, 0, nullptr, KWqT, 512, 256);
  sbias_k<<<128, thr, 0, stream>>>(bq, Kmatb, sbias);

  // embed: x_emb = relu(xb @ Wp + bp)
  mfma_gemm_k<64, true, true><<<dim3(MB, 1), thr, 0, stream>>>(
      xb, WpT, 128, nullptr, nullptr, 0, bp, x_emb, N, 64);
  // SAGE1
  agg64_k<<<(N + 3) / 4, thr, 0, stream>>>(x_emb, rowptr, eidx, mean1, 0, N);
  mfma_gemm_k<128, true, true><<<dim3(MB, 2), thr, 0, stream>>>(
      mean1, W1lT, 64, x_emb, W1rT, 64, b1l, h, N, 256);

  // chunked SAGE2 + attention + MLP head
  for (int r0 = 0; r0 < N; r0 += CR) {
    const int CRc = (N - r0 < CR) ? (N - r0) : CR;
    const int MBc = (CRc + 127) / 128;
    agg256_k<<<(CRc + 3) / 4, thr, 0, stream>>>(h, rowptr, eidx, mean2_c, r0, CRc);
    mfma_gemm_k<128, false, true><<<dim3(MBc, 2), thr, 0, stream>>>(
        mean2_c, W2lT, 256, h + (size_t)r0 * 256, W2rT, 256, b2l, h2_c, CRc, 256);
    mfma_gemm_k<128, false, false><<<dim3(MBc, 4), thr, 0, stream>>>(
        h2_c, KWqT, 256, nullptr, nullptr, 0, sbias, S_c, CRc, 512);
    softmax_k<<<(CRc + 3) / 4, thr, 0, stream>>>(S_c, Pb_c, CRc);
    mfma_gemm_k<128, false, true><<<dim3(MBc, 2), thr, 0, stream>>>(
        Pb_c, VT, 512, nullptr, nullptr, 0, nullptr, g_c, CRc, 256);
    mfma_gemm_k<128, true, true><<<dim3(MBc, 2), thr, 0, stream>>>(
        h2_c, Wm1aT, 256, g_c, Wm1bT, 256, bm1, hidden_c, CRc, 256);
    out_k<<<(CRc + 3) / 4, thr, 0, stream>>>(hidden_c, Wm2, bm2, out + (size_t)r0 * 2, CRc);
  }
}

// Round 6
// 831.445 us; speedup vs baseline: 3.3343x; 1.4628x over previous
//
#include <hip/hip_runtime.h>
#include <cstdint>
#include <cstddef>

// GAAPModelB on MI355X: bf16-MFMA GEMM stack + CSR gather aggregation.
// N=100000, E=800000, IN=128, H=256, G=512. Chunked post-SAGE1 pipeline.
// R6: edge-parallel agg64 (4 slots/wave), unroll-2 agg256, CR=32768 with
// bf16 in-place softmax (S/P shared buffer), merged weight-cvt kernel.

#define NN 100000
#define NE 800000
#define CR 32768   // chunk rows
#define NB1 98     // ceil(100000/1024) scan blocks

typedef __attribute__((ext_vector_type(8))) short short8;
typedef __attribute__((ext_vector_type(4))) float f32x4;

__device__ __forceinline__ float b2f(ushort u) {
  union { unsigned u; float f; } v; v.u = ((unsigned)u) << 16; return v.f;
}
__device__ __forceinline__ ushort f2b(float f) {
  union { float f; unsigned u; } v; v.f = f;
  unsigned r = v.u + 0x7FFFu + ((v.u >> 16) & 1u);
  return (ushort)(r >> 16);
}
__device__ __forceinline__ void gl_lds16(const void* g, void* l) {
  __builtin_amdgcn_global_load_lds((const __attribute__((address_space(1))) void*)g,
                                   (__attribute__((address_space(3))) void*)l, 16, 0, 0);
}

// ------------------------------ utility ------------------------------
__global__ void zero_i32_k(int* __restrict__ p, int n) {
  int i = blockIdx.x * 256 + threadIdx.x;
  if (i < n) p[i] = 0;
}

__global__ void detect_i64_k(const int* __restrict__ ei, int* __restrict__ flag) {
  int i64 = 1;
  for (int i = 0; i < 256; ++i) {
    if (ei[2 * i + 1] != 0) { i64 = 0; break; }
  }
  *flag = i64;
}

// f32 -> bf16 flat, 4 elems/thread (big arrays)
__global__ void cvt4_k(const float* __restrict__ src, ushort* __restrict__ dst, int n4) {
  int i = blockIdx.x * 256 + threadIdx.x;
  if (i < n4) {
    float4 v = ((const float4*)src)[i];
    ushort4 o; o.x = f2b(v.x); o.y = f2b(v.y); o.z = f2b(v.z); o.w = f2b(v.w);
    ((ushort4*)dst)[i] = o;
  }
}

// transpose-convert: dst[c*R + r] = bf16(src[(row_off+r)*C + c])
__global__ void tcvt_k(const float* __restrict__ src, ushort* __restrict__ dst,
                       int R, int C, int row_off) {
  int i = blockIdx.x * 256 + threadIdx.x;
  if (i < R * C) {
    int r = i / C, c = i % C;
    dst[(size_t)c * R + r] = f2b(src[(size_t)(row_off + r) * C + c]);
  }
}

// merged small weight conversions: 11 jobs, grid.y = job
#define NJOB 11
struct CvtJobs {
  const float* src[NJOB];
  ushort* dst[NJOB];
  int R[NJOB], C[NJOB], off[NJOB], tr[NJOB];
};
__global__ void wcvt_k(CvtJobs jb) {
  const int j = blockIdx.y;
  const int Cj = jb.C[j], Rj = jb.R[j];
  const int n = Rj * Cj;
  for (int i = blockIdx.x * 256 + threadIdx.x; i < n; i += gridDim.x * 256) {
    if (jb.tr[j]) {
      int r = i / Cj, c = i % Cj;
      jb.dst[j][(size_t)c * Rj + r] = f2b(jb.src[j][(size_t)(jb.off[j] + r) * Cj + c]);
    } else {
      jb.dst[j][i] = f2b(jb.src[j][i]);
    }
  }
}

// ------------------------------ CSR build ------------------------------
__global__ void count_edges_k(const int* __restrict__ ei, const int* __restrict__ flag,
                              int* __restrict__ cnt, int E) {
  int i = blockIdx.x * 256 + threadIdx.x;
  if (i >= E) return;
  const bool i64 = (*flag != 0);
  unsigned d = (unsigned)(i64 ? ei[2 * E + 2 * i] : ei[E + i]);
  if (d < NN) atomicAdd(&cnt[d], 1);
}

__global__ __launch_bounds__(256)
void scan1_k(const int* __restrict__ cnt, int* __restrict__ rowptr,
             int* __restrict__ bsum, int n) {
  __shared__ int ls[256];
  const int b = blockIdx.x, t = threadIdx.x;
  const int base = b * 1024 + t * 4;
  int v[4]; int s = 0;
#pragma unroll
  for (int j = 0; j < 4; ++j) { int i = base + j; v[j] = (i < n) ? cnt[i] : 0; s += v[j]; }
  ls[t] = s; __syncthreads();
  int x = s;
  for (int o = 1; o < 256; o <<= 1) {
    int a = (t >= o) ? ls[t - o] : 0; __syncthreads();
    x += a; ls[t] = x; __syncthreads();
  }
  int run = x - s;
#pragma unroll
  for (int j = 0; j < 4; ++j) { run += v[j]; int i = base + j; if (i < n) rowptr[i + 1] = run; }
  if (t == 255) bsum[b] = x;
}

__global__ void scan2_k(const int* __restrict__ bsum, int* __restrict__ boff, int nb) {
  __shared__ int ls[128];
  int t = threadIdx.x;
  int v = (t < nb) ? bsum[t] : 0;
  ls[t] = v; __syncthreads();
  int x = v;
  for (int o = 1; o < 128; o <<= 1) {
    int a = (t >= o) ? ls[t - o] : 0; __syncthreads();
    x += a; ls[t] = x; __syncthreads();
  }
  if (t < nb) boff[t] = x - v;
}

__global__ void scan3_k(const int* __restrict__ cnt, int* __restrict__ rowptr,
                        int* __restrict__ cursor, const int* __restrict__ boff, int n) {
  int i = blockIdx.x * 256 + threadIdx.x;
  if (i == 0) rowptr[0] = 0;
  if (i < n) {
    int r = rowptr[i + 1] + boff[i >> 10];
    rowptr[i + 1] = r;
    cursor[i] = r - cnt[i];
  }
}

__global__ void fill_edges_k(const int* __restrict__ ei, const int* __restrict__ flag,
                             int* __restrict__ cursor, int* __restrict__ eidx, int E) {
  int i = blockIdx.x * 256 + threadIdx.x;
  if (i >= E) return;
  const bool i64 = (*flag != 0);
  unsigned s = (unsigned)(i64 ? ei[2 * i] : ei[i]);
  unsigned d = (unsigned)(i64 ? ei[2 * E + 2 * i] : ei[E + i]);
  if (d < NN && s < NN) {
    int p = atomicAdd(&cursor[d], 1);
    if ((unsigned)p < (unsigned)E) eidx[p] = (int)s;
  }
}

// ------------------------------ aggregation ------------------------------
// agg64: wave = 4 edge-slots x 16 dim-lanes (ushort4). Dependent chain /4.
__global__ void agg64_k(const ushort* __restrict__ X, const int* __restrict__ rowptr,
                        const int* __restrict__ eidx, ushort* __restrict__ mean,
                        int r0, int M) {
  int nl = blockIdx.x * 4 + (threadIdx.x >> 6);
  int l = threadIdx.x & 63;
  int e4 = l >> 4;      // edge slot 0..3
  int d4 = l & 15;      // dim group (4 dims)
  if (nl >= M) return;
  int node = r0 + nl;
  int s = rowptr[node], e = rowptr[node + 1];
  float a0 = 0.f, a1 = 0.f, a2 = 0.f, a3 = 0.f;
  for (int i = s + e4; i < e; i += 4) {
    unsigned sc = (unsigned)eidx[i];
    if (sc < NN) {
      ushort4 v = ((const ushort4*)(X + (size_t)sc * 64))[d4];
      a0 += b2f(v.x); a1 += b2f(v.y); a2 += b2f(v.z); a3 += b2f(v.w);
    }
  }
  a0 += __shfl_xor(a0, 16); a0 += __shfl_xor(a0, 32);
  a1 += __shfl_xor(a1, 16); a1 += __shfl_xor(a1, 32);
  a2 += __shfl_xor(a2, 16); a2 += __shfl_xor(a2, 32);
  a3 += __shfl_xor(a3, 16); a3 += __shfl_xor(a3, 32);
  if (e4 == 0) {
    float inv = 1.f / (float)max(e - s, 1);
    ushort4 o; o.x = f2b(a0 * inv); o.y = f2b(a1 * inv); o.z = f2b(a2 * inv); o.w = f2b(a3 * inv);
    ((ushort4*)(mean + (size_t)nl * 64))[d4] = o;
  }
}

// agg256: wave per node, unroll-2 independent accumulators for load ILP
__global__ void agg256_k(const ushort* __restrict__ X, const int* __restrict__ rowptr,
                         const int* __restrict__ eidx, ushort* __restrict__ mean,
                         int r0, int M) {
  int nl = blockIdx.x * 4 + (threadIdx.x >> 6);
  int lane = threadIdx.x & 63;
  if (nl >= M) return;
  int node = r0 + nl;
  int s = rowptr[node], e = rowptr[node + 1];
  float a0 = 0.f, a1 = 0.f, a2 = 0.f, a3 = 0.f;
  float c0 = 0.f, c1 = 0.f, c2 = 0.f, c3 = 0.f;
  int i = s;
  for (; i + 1 < e; i += 2) {
    unsigned s0 = (unsigned)eidx[i];
    unsigned s1 = (unsigned)eidx[i + 1];
    if (s0 < NN) {
      ushort4 v = ((const ushort4*)(X + (size_t)s0 * 256))[lane];
      a0 += b2f(v.x); a1 += b2f(v.y); a2 += b2f(v.z); a3 += b2f(v.w);
    }
    if (s1 < NN) {
      ushort4 v = ((const ushort4*)(X + (size_t)s1 * 256))[lane];
      c0 += b2f(v.x); c1 += b2f(v.y); c2 += b2f(v.z); c3 += b2f(v.w);
    }
  }
  if (i < e) {
    unsigned s0 = (unsigned)eidx[i];
    if (s0 < NN) {
      ushort4 v = ((const ushort4*)(X + (size_t)s0 * 256))[lane];
      a0 += b2f(v.x); a1 += b2f(v.y); a2 += b2f(v.z); a3 += b2f(v.w);
    }
  }
  a0 += c0; a1 += c1; a2 += c2; a3 += c3;
  float inv = 1.f / (float)max(e - s, 1);
  ushort4 o; o.x = f2b(a0 * inv); o.y = f2b(a1 * inv); o.z = f2b(a2 * inv); o.w = f2b(a3 * inv);
  ((ushort4*)(mean + (size_t)nl * 256))[lane] = o;
}

// ------------------------------ bf16 MFMA GEMM ------------------------------
// C[M,Nc] = act(A1@B1 + A2@B2 + bias): A [M,K] bf16 rm, BT [Nc,K] bf16 rm.
// BM=128, BN in {64,128}, BK=64, 256 thr = 4 waves (2x2), 16x16x32 MFMA.
// XOR slot swizzle (kb ^= row&7), global_load_lds w/ pre-swizzled source.
template<int BN, bool RELU, bool OUTBF>
__global__ __launch_bounds__(256)
void mfma_gemm_k(const ushort* __restrict__ A1, const ushort* __restrict__ BT1, int K1,
                 const ushort* __restrict__ A2, const ushort* __restrict__ BT2, int K2,
                 const float* __restrict__ bias, void* __restrict__ Cv, int M, int Nc) {
  constexpr int NR = BN / 32;
  constexpr int WTN = BN / 2;
  __shared__ __align__(16) char As[128 * 64 * 2];
  __shared__ __align__(16) char Bs[BN * 64 * 2];
  const int tid = threadIdx.x;
  const int l = tid & 63;
  const int w = tid >> 6;
  const int wm = w >> 1, wn = w & 1;
  const int bm = blockIdx.x * 128, bn = blockIdx.y * BN;
  const int r15 = l & 15, g4 = l >> 4;

  f32x4 acc[4][NR];
  const f32x4 zz = {0.f, 0.f, 0.f, 0.f};
#pragma unroll
  for (int m = 0; m < 4; ++m)
#pragma unroll
    for (int n = 0; n < NR; ++n) acc[m][n] = zz;

  for (int pass = 0; pass < 2; ++pass) {
    const ushort* A = pass ? A2 : A1;
    const ushort* BT = pass ? BT2 : BT1;
    const int K = pass ? K2 : K1;
    if (!A) break;
    for (int k0 = 0; k0 < K; k0 += 64) {
#pragma unroll
      for (int p = 0; p < 4; ++p) {
        int idx = tid + p * 256;
        int row = idx >> 3, slot = idx & 7;
        int kb = slot ^ (row & 7);
        int grow = bm + row; if (grow >= M) grow = M - 1;
        gl_lds16(A + (size_t)grow * K + k0 + kb * 8, As + idx * 16);
      }
#pragma unroll
      for (int p = 0; p < BN / 32; ++p) {
        int idx = tid + p * 256;
        int row = idx >> 3, slot = idx & 7;
        int kb = slot ^ (row & 7);
        gl_lds16(BT + (size_t)(bn + row) * K + k0 + kb * 8, Bs + idx * 16);
      }
      __syncthreads();
#pragma unroll
      for (int s = 0; s < 2; ++s) {
        short8 a[4], b[NR];
        const int slotx = (((s * 4 + g4) ^ (r15 & 7)) << 4);
#pragma unroll
        for (int m = 0; m < 4; ++m) {
          int row = wm * 64 + m * 16 + r15;
          a[m] = *(const short8*)(As + row * 128 + slotx);
        }
#pragma unroll
        for (int n = 0; n < NR; ++n) {
          int row = wn * WTN + n * 16 + r15;
          b[n] = *(const short8*)(Bs + row * 128 + slotx);
        }
#pragma unroll
        for (int m = 0; m < 4; ++m)
#pragma unroll
          for (int n = 0; n < NR; ++n)
            acc[m][n] = __builtin_amdgcn_mfma_f32_16x16x32_bf16(a[m], b[n], acc[m][n], 0, 0, 0);
      }
      __syncthreads();
    }
  }
#pragma unroll
  for (int n = 0; n < NR; ++n) {
    int col = bn + wn * WTN + n * 16 + r15;
    float bv = bias ? bias[col] : 0.f;
#pragma unroll
    for (int m = 0; m < 4; ++m) {
#pragma unroll
      for (int j = 0; j < 4; ++j) {
        int row = bm + wm * 64 + m * 16 + g4 * 4 + j;
        if (row < M) {
          float v = acc[m][n][j] + bv;
          if (RELU) v = fmaxf(v, 0.f);
          if (OUTBF) ((ushort*)Cv)[(size_t)row * Nc + col] = f2b(v);
          else       ((float*)Cv)[(size_t)row * Nc + col] = v;
        }
      }
    }
  }
}

// ------------------------------ sbias[g] = dot(bq, Kmat[g]) ------------------------------
__global__ void sbias_k(const float* __restrict__ bq, const ushort* __restrict__ Kmat,
                        float* __restrict__ sbias) {
  int g = blockIdx.x * 4 + (threadIdx.x >> 6);
  int lane = threadIdx.x & 63;
  if (g >= 512) return;
  ushort4 kv = ((const ushort4*)(Kmat + (size_t)g * 256))[lane];
  float4 bv = ((const float4*)bq)[lane];
  float p = b2f(kv.x) * bv.x + b2f(kv.y) * bv.y + b2f(kv.z) * bv.z + b2f(kv.w) * bv.w;
  for (int off = 32; off; off >>= 1) p += __shfl_xor(p, off);
  if (lane == 0) sbias[g] = p;
}

// ------------------------------ softmax in place (bf16 logits -> bf16 P), scale 1/16 ------------------------------
__global__ void softmax_k(ushort* __restrict__ SP, int M) {
  int row = blockIdx.x * 4 + (threadIdx.x >> 6);
  int lane = threadIdx.x & 63;
  if (row >= M) return;
  ushort4* p = (ushort4*)(SP + (size_t)row * 512);
  ushort4 ua = p[lane];
  ushort4 ub = p[lane + 64];
  const float sc = 0.0625f;
  float ax = b2f(ua.x) * sc, ay = b2f(ua.y) * sc, az = b2f(ua.z) * sc, aw = b2f(ua.w) * sc;
  float bx = b2f(ub.x) * sc, by = b2f(ub.y) * sc, bz = b2f(ub.z) * sc, bw = b2f(ub.w) * sc;
  float m = fmaxf(fmaxf(fmaxf(ax, ay), fmaxf(az, aw)),
                  fmaxf(fmaxf(bx, by), fmaxf(bz, bw)));
  for (int off = 32; off; off >>= 1) m = fmaxf(m, __shfl_xor(m, off));
  ax = expf(ax - m); ay = expf(ay - m); az = expf(az - m); aw = expf(aw - m);
  bx = expf(bx - m); by = expf(by - m); bz = expf(bz - m); bw = expf(bw - m);
  float s = ax + ay + az + aw + bx + by + bz + bw;
  for (int off = 32; off; off >>= 1) s += __shfl_xor(s, off);
  float inv = 1.f / s;
  ushort4 oa, ob;
  oa.x = f2b(ax * inv); oa.y = f2b(ay * inv); oa.z = f2b(az * inv); oa.w = f2b(aw * inv);
  ob.x = f2b(bx * inv); ob.y = f2b(by * inv); ob.z = f2b(bz * inv); ob.w = f2b(bw * inv);
  p[lane] = oa;
  p[lane + 64] = ob;
}

// ------------------------------ final head ------------------------------
__global__ void out_k(const ushort* __restrict__ hidden, const float* __restrict__ Wm2,
                      const float* __restrict__ bm2, float* __restrict__ out, int M) {
  int row = blockIdx.x * 4 + (threadIdx.x >> 6);
  int lane = threadIdx.x & 63;
  if (row >= M) return;
  ushort4 hv = ((const ushort4*)(hidden + (size_t)row * 256))[lane];
  float h0 = b2f(hv.x), h1 = b2f(hv.y), h2 = b2f(hv.z), h3 = b2f(hv.w);
  int k = lane * 4;
  float p0 = h0 * Wm2[(k + 0) * 2 + 0] + h1 * Wm2[(k + 1) * 2 + 0] +
             h2 * Wm2[(k + 2) * 2 + 0] + h3 * Wm2[(k + 3) * 2 + 0];
  float p1 = h0 * Wm2[(k + 0) * 2 + 1] + h1 * Wm2[(k + 1) * 2 + 1] +
             h2 * Wm2[(k + 2) * 2 + 1] + h3 * Wm2[(k + 3) * 2 + 1];
  for (int off = 32; off; off >>= 1) {
    p0 += __shfl_xor(p0, off);
    p1 += __shfl_xor(p1, off);
  }
  if (lane == 0) {
    out[(size_t)row * 2 + 0] = p0 + bm2[0];
    out[(size_t)row * 2 + 1] = p1 + bm2[1];
  }
}

// ------------------------------ launch ------------------------------
extern "C" void kernel_launch(void* const* d_in, const int* in_sizes, int n_in,
                              void* d_out, int out_size, void* d_ws, size_t ws_size,
                              hipStream_t stream) {
  const int N = NN, E = NE;
  const float* x   = (const float*)d_in[0];
  const int*   ei  = (const int*)d_in[1];
  const float* gc  = (const float*)d_in[2];
  const float* Wp  = (const float*)d_in[3];
  const float* bp  = (const float*)d_in[4];
  const float* W1l = (const float*)d_in[5];
  const float* b1l = (const float*)d_in[6];
  const float* W1r = (const float*)d_in[7];
  const float* W2l = (const float*)d_in[8];
  const float* b2l = (const float*)d_in[9];
  const float* W2r = (const float*)d_in[10];
  const float* Wq  = (const float*)d_in[11];
  const float* bq  = (const float*)d_in[12];
  const float* Wk  = (const float*)d_in[13];
  const float* bk  = (const float*)d_in[14];
  const float* Wv  = (const float*)d_in[15];
  const float* bv  = (const float*)d_in[16];
  const float* Wm1 = (const float*)d_in[17];
  const float* bm1 = (const float*)d_in[18];
  const float* Wm2 = (const float*)d_in[19];
  const float* bm2 = (const float*)d_in[20];
  float* out = (float*)d_out;

  char* base = (char*)d_ws;
  size_t off = 0;
  auto take = [&](size_t bytes) -> void* {
    void* r = base + off;
    off += (bytes + 255) & ~(size_t)255;
    return r;
  };
  // CSR + misc
  int* cnt    = (int*)take((size_t)N * 4);
  int* rowptr = (int*)take((size_t)(N + 1) * 4);
  int* cursor = (int*)take((size_t)N * 4);
  int* eidx   = (int*)take((size_t)E * 4);
  int* eflag  = (int*)take(256);
  int* bsum   = (int*)take(NB1 * 4);
  int* boff   = (int*)take(NB1 * 4);
  // bf16 weights
  ushort* WpT   = (ushort*)take((size_t)64 * 128 * 2);
  ushort* W1lT  = (ushort*)take((size_t)256 * 64 * 2);
  ushort* W1rT  = (ushort*)take((size_t)256 * 64 * 2);
  ushort* W2lT  = (ushort*)take((size_t)256 * 256 * 2);
  ushort* W2rT  = (ushort*)take((size_t)256 * 256 * 2);
  ushort* WkT   = (ushort*)take((size_t)256 * 256 * 2);
  ushort* WvT   = (ushort*)take((size_t)256 * 256 * 2);
  ushort* Wqb   = (ushort*)take((size_t)256 * 256 * 2);
  ushort* Wm1aT = (ushort*)take((size_t)256 * 256 * 2);
  ushort* Wm1bT = (ushort*)take((size_t)256 * 256 * 2);
  // attention small
  ushort* gcb   = (ushort*)take((size_t)512 * 256 * 2);
  ushort* Kmatb = (ushort*)take((size_t)512 * 256 * 2);
  float*  Vmatf = (float*)take((size_t)512 * 256 * 4);
  ushort* VT    = (ushort*)take((size_t)256 * 512 * 2);
  ushort* KWqT  = (ushort*)take((size_t)512 * 256 * 2);
  float*  sbias = (float*)take((size_t)512 * 4);
  // region U: pre-loop {xb, x_emb, mean1} then chunk buffers (3072B/row)
  const size_t szU_pre = (size_t)N * 128 * 2 + (size_t)N * 64 * 2 + (size_t)N * 64 * 2;
  const size_t szU_chunk = (size_t)CR * 3072;
  char* U = (char*)take(szU_pre > szU_chunk ? szU_pre : szU_chunk);
  ushort* h = (ushort*)take((size_t)N * 256 * 2);   // live whole run
  if (off > ws_size) return;

  ushort* xb    = (ushort*)U;
  ushort* x_emb = (ushort*)(U + (size_t)N * 128 * 2);
  ushort* mean1 = (ushort*)(U + (size_t)N * 128 * 2 + (size_t)N * 64 * 2);
  ushort* mean2_c  = (ushort*)U;                        // CR*256 bf16
  ushort* h2_c     = (ushort*)(U + (size_t)CR * 512);   // CR*256 bf16
  ushort* SP_c     = (ushort*)(U + (size_t)CR * 1024);  // CR*512 bf16 (S then P)
  ushort* g_c      = (ushort*)(U + (size_t)CR * 2048);  // CR*256 bf16
  ushort* hidden_c = (ushort*)(U + (size_t)CR * 2560);  // CR*256 bf16

  const int MB = (N + 127) / 128;
  dim3 thr(256);

  // CSR build
  zero_i32_k<<<(N + 255) / 256, thr, 0, stream>>>(cnt, N);
  detect_i64_k<<<1, 1, 0, stream>>>(ei, eflag);
  count_edges_k<<<(E + 255) / 256, thr, 0, stream>>>(ei, eflag, cnt, E);
  scan1_k<<<NB1, thr, 0, stream>>>(cnt, rowptr, bsum, N);
  scan2_k<<<1, 128, 0, stream>>>(bsum, boff, NB1);
  scan3_k<<<(N + 255) / 256, thr, 0, stream>>>(cnt, rowptr, cursor, boff, N);
  fill_edges_k<<<(E + 255) / 256, thr, 0, stream>>>(ei, eflag, cursor, eidx, E);

  // input conversion (big) + merged weight conversions
  cvt4_k<<<(N * 128 / 4 + 255) / 256, thr, 0, stream>>>(x, xb, N * 128 / 4);
  {
    CvtJobs jb;
    const float* s_[NJOB] = {gc, Wq, Wp, W1l, W1r, W2l, W2r, Wk, Wv, Wm1, Wm1};
    ushort* d_[NJOB] = {gcb, Wqb, WpT, W1lT, W1rT, W2lT, W2rT, WkT, WvT, Wm1aT, Wm1bT};
    int R_[NJOB] = {512, 256, 128, 64, 64, 256, 256, 256, 256, 256, 256};
    int C_[NJOB] = {256, 256, 64, 256, 256, 256, 256, 256, 256, 256, 256};
    int o_[NJOB] = {0, 0, 0, 0, 0, 0, 0, 0, 0, 0, 256};
    int t_[NJOB] = {0, 0, 1, 1, 1, 1, 1, 1, 1, 1, 1};
    for (int j = 0; j < NJOB; ++j) {
      jb.src[j] = s_[j]; jb.dst[j] = d_[j]; jb.R[j] = R_[j]; jb.C[j] = C_[j];
      jb.off[j] = o_[j]; jb.tr[j] = t_[j];
    }
    wcvt_k<<<dim3(32, NJOB), thr, 0, stream>>>(jb);
  }

  // attention pre: Kmat(bf16), Vmat(f32)->VT, KWqT = Kmat @ Wq^T, sbias
  mfma_gemm_k<128, false, true><<<dim3(4, 2), thr, 0, stream>>>(
      gcb, WkT, 256, nullptr, nullptr, 0, bk, Kmatb, 512, 256);
  mfma_gemm_k<128, false, false><<<dim3(4, 2), thr, 0, stream>>>(
      gcb, WvT, 256, nullptr, nullptr, 0, bv, Vmatf, 512, 256);
  tcvt_k<<<(512 * 256 + 255) / 256, thr, 0, stream>>>(Vmatf, VT, 512, 256, 0);
  mfma_gemm_k<128, false, true><<<dim3(4, 2), thr, 0, stream>>>(
      Kmatb, Wqb, 256, nullptr, nullptr, 0, nullptr, KWqT, 512, 256);
  sbias_k<<<128, thr, 0, stream>>>(bq, Kmatb, sbias);

  // embed: x_emb = relu(xb @ Wp + bp)
  mfma_gemm_k<64, true, true><<<dim3(MB, 1), thr, 0, stream>>>(
      xb, WpT, 128, nullptr, nullptr, 0, bp, x_emb, N, 64);
  // SAGE1
  agg64_k<<<(N + 3) / 4, thr, 0, stream>>>(x_emb, rowptr, eidx, mean1, 0, N);
  mfma_gemm_k<128, true, true><<<dim3(MB, 2), thr, 0, stream>>>(
      mean1, W1lT, 64, x_emb, W1rT, 64, b1l, h, N, 256);

  // chunked SAGE2 + attention + MLP head
  for (int r0 = 0; r0 < N; r0 += CR) {
    const int CRc = (N - r0 < CR) ? (N - r0) : CR;
    const int MBc = (CRc + 127) / 128;
    agg256_k<<<(CRc + 3) / 4, thr, 0, stream>>>(h, rowptr, eidx, mean2_c, r0, CRc);
    mfma_gemm_k<128, false, true><<<dim3(MBc, 2), thr, 0, stream>>>(
        mean2_c, W2lT, 256, h + (size_t)r0 * 256, W2rT, 256, b2l, h2_c, CRc, 256);
    mfma_gemm_k<128, false, true><<<dim3(MBc, 4), thr, 0, stream>>>(
        h2_c, KWqT, 256, nullptr, nullptr, 0, sbias, SP_c, CRc, 512);
    softmax_k<<<(CRc + 3) / 4, thr, 0, stream>>>(SP_c, CRc);
    mfma_gemm_k<128, false, true><<<dim3(MBc, 2), thr, 0, stream>>>(
        SP_c, VT, 512, nullptr, nullptr, 0, nullptr, g_c, CRc, 256);
    mfma_gemm_k<128, true, true><<<dim3(MBc, 2), thr, 0, stream>>>(
        h2_c, Wm1aT, 256, g_c, Wm1bT, 256, bm1, hidden_c, CRc, 256);
    out_k<<<(CRc + 3) / 4, thr, 0, stream>>>(hidden_c, Wm2, bm2, out + (size_t)r0 * 2, CRc);
  }
}

// Round 7
// 825.974 us; speedup vs baseline: 3.3564x; 1.0066x over previous
//
#include <hip/hip_runtime.h>
#include <cstdint>
#include <cstddef>

// GAAPModelB on MI355X: bf16-MFMA GEMM stack + CSR gather aggregation.
// N=100000, E=800000, IN=128, H=256, G=512. Chunked post-SAGE1 pipeline.
// R7: parallel dtype-detect, 4-edge/thread vectorized CSR build (atomic
// latency hiding), 2-slot x ushort8 agg256.

#define NN 100000
#define NE 800000
#define CR 32768   // chunk rows
#define NB1 98     // ceil(100000/1024) scan blocks

typedef __attribute__((ext_vector_type(8))) short short8;
typedef __attribute__((ext_vector_type(8))) unsigned short ushort8;
typedef __attribute__((ext_vector_type(4))) float f32x4;

__device__ __forceinline__ float b2f(ushort u) {
  union { unsigned u; float f; } v; v.u = ((unsigned)u) << 16; return v.f;
}
__device__ __forceinline__ ushort f2b(float f) {
  union { float f; unsigned u; } v; v.f = f;
  unsigned r = v.u + 0x7FFFu + ((v.u >> 16) & 1u);
  return (ushort)(r >> 16);
}
__device__ __forceinline__ void gl_lds16(const void* g, void* l) {
  __builtin_amdgcn_global_load_lds((const __attribute__((address_space(1))) void*)g,
                                   (__attribute__((address_space(3))) void*)l, 16, 0, 0);
}

// ------------------------------ utility ------------------------------
__global__ void zero_i32_k(int* __restrict__ p, int n) {
  int i = blockIdx.x * 256 + threadIdx.x;
  if (i < n) p[i] = 0;
}

// flag=1 iff edge_index is int64 (odd words of first 256 entries all zero)
__global__ void detect_i64_k(const int* __restrict__ ei, int* __restrict__ flag) {
  __shared__ int ok;
  int t = threadIdx.x;
  if (t == 0) ok = 1;
  __syncthreads();
  if (ei[2 * t + 1] != 0) ok = 0;
  __syncthreads();
  if (t == 0) *flag = ok;
}

// f32 -> bf16 flat, 4 elems/thread (big arrays)
__global__ void cvt4_k(const float* __restrict__ src, ushort* __restrict__ dst, int n4) {
  int i = blockIdx.x * 256 + threadIdx.x;
  if (i < n4) {
    float4 v = ((const float4*)src)[i];
    ushort4 o; o.x = f2b(v.x); o.y = f2b(v.y); o.z = f2b(v.z); o.w = f2b(v.w);
    ((ushort4*)dst)[i] = o;
  }
}

// transpose-convert: dst[c*R + r] = bf16(src[(row_off+r)*C + c])
__global__ void tcvt_k(const float* __restrict__ src, ushort* __restrict__ dst,
                       int R, int C, int row_off) {
  int i = blockIdx.x * 256 + threadIdx.x;
  if (i < R * C) {
    int r = i / C, c = i % C;
    dst[(size_t)c * R + r] = f2b(src[(size_t)(row_off + r) * C + c]);
  }
}

// merged small weight conversions: 11 jobs, grid.y = job
#define NJOB 11
struct CvtJobs {
  const float* src[NJOB];
  ushort* dst[NJOB];
  int R[NJOB], C[NJOB], off[NJOB], tr[NJOB];
};
__global__ void wcvt_k(CvtJobs jb) {
  const int j = blockIdx.y;
  const int Cj = jb.C[j], Rj = jb.R[j];
  const int n = Rj * Cj;
  for (int i = blockIdx.x * 256 + threadIdx.x; i < n; i += gridDim.x * 256) {
    if (jb.tr[j]) {
      int r = i / Cj, c = i % Cj;
      jb.dst[j][(size_t)c * Rj + r] = f2b(jb.src[j][(size_t)(jb.off[j] + r) * Cj + c]);
    } else {
      jb.dst[j][i] = f2b(jb.src[j][i]);
    }
  }
}

// ------------------------------ CSR build (4 edges/thread) ------------------------------
__device__ __forceinline__ void load_edges4(const int* __restrict__ ei, bool i64, int E,
                                            int i0, int* s, int* d, bool need_src) {
  if (!i64) {
    if (need_src) {
      int4 s4 = *(const int4*)(ei + i0);
      s[0] = s4.x; s[1] = s4.y; s[2] = s4.z; s[3] = s4.w;
    }
    int4 d4 = *(const int4*)(ei + E + i0);
    d[0] = d4.x; d[1] = d4.y; d[2] = d4.z; d[3] = d4.w;
  } else {
    if (need_src) {
      int4 p0 = *(const int4*)(ei + 2 * i0);
      int4 p1 = *(const int4*)(ei + 2 * i0 + 4);
      s[0] = p0.x; s[1] = p0.z; s[2] = p1.x; s[3] = p1.z;
    }
    int4 q0 = *(const int4*)(ei + 2 * E + 2 * i0);
    int4 q1 = *(const int4*)(ei + 2 * E + 2 * i0 + 4);
    d[0] = q0.x; d[1] = q0.z; d[2] = q1.x; d[3] = q1.z;
  }
}

__global__ void count_edges_k(const int* __restrict__ ei, const int* __restrict__ flag,
                              int* __restrict__ cnt, int E) {
  int i0 = (blockIdx.x * 256 + threadIdx.x) * 4;
  if (i0 >= E) return;
  const bool i64 = (*flag != 0);
  int s[4], d[4];
  load_edges4(ei, i64, E, i0, s, d, false);
#pragma unroll
  for (int j = 0; j < 4; ++j) {
    unsigned dd = (unsigned)d[j];
    if (i0 + j < E && dd < NN) atomicAdd(&cnt[dd], 1);
  }
}

__global__ __launch_bounds__(256)
void scan1_k(const int* __restrict__ cnt, int* __restrict__ rowptr,
             int* __restrict__ bsum, int n) {
  __shared__ int ls[256];
  const int b = blockIdx.x, t = threadIdx.x;
  const int base = b * 1024 + t * 4;
  int v[4]; int s = 0;
#pragma unroll
  for (int j = 0; j < 4; ++j) { int i = base + j; v[j] = (i < n) ? cnt[i] : 0; s += v[j]; }
  ls[t] = s; __syncthreads();
  int x = s;
  for (int o = 1; o < 256; o <<= 1) {
    int a = (t >= o) ? ls[t - o] : 0; __syncthreads();
    x += a; ls[t] = x; __syncthreads();
  }
  int run = x - s;
#pragma unroll
  for (int j = 0; j < 4; ++j) { run += v[j]; int i = base + j; if (i < n) rowptr[i + 1] = run; }
  if (t == 255) bsum[b] = x;
}

__global__ void scan2_k(const int* __restrict__ bsum, int* __restrict__ boff, int nb) {
  __shared__ int ls[128];
  int t = threadIdx.x;
  int v = (t < nb) ? bsum[t] : 0;
  ls[t] = v; __syncthreads();
  int x = v;
  for (int o = 1; o < 128; o <<= 1) {
    int a = (t >= o) ? ls[t - o] : 0; __syncthreads();
    x += a; ls[t] = x; __syncthreads();
  }
  if (t < nb) boff[t] = x - v;
}

__global__ void scan3_k(const int* __restrict__ cnt, int* __restrict__ rowptr,
                        int* __restrict__ cursor, const int* __restrict__ boff, int n) {
  int i = blockIdx.x * 256 + threadIdx.x;
  if (i == 0) rowptr[0] = 0;
  if (i < n) {
    int r = rowptr[i + 1] + boff[i >> 10];
    rowptr[i + 1] = r;
    cursor[i] = r - cnt[i];
  }
}

__global__ void fill_edges_k(const int* __restrict__ ei, const int* __restrict__ flag,
                             int* __restrict__ cursor, int* __restrict__ eidx, int E) {
  int i0 = (blockIdx.x * 256 + threadIdx.x) * 4;
  if (i0 >= E) return;
  const bool i64 = (*flag != 0);
  int s[4], d[4];
  load_edges4(ei, i64, E, i0, s, d, true);
#pragma unroll
  for (int j = 0; j < 4; ++j) {
    unsigned ss = (unsigned)s[j];
    unsigned dd = (unsigned)d[j];
    if (i0 + j < E && dd < NN && ss < NN) {
      int p = atomicAdd(&cursor[dd], 1);
      if ((unsigned)p < (unsigned)E) eidx[p] = (int)ss;
    }
  }
}

// ------------------------------ aggregation ------------------------------
// agg64: wave = 4 edge-slots x 16 dim-lanes (ushort4). Dependent chain /4.
__global__ void agg64_k(const ushort* __restrict__ X, const int* __restrict__ rowptr,
                        const int* __restrict__ eidx, ushort* __restrict__ mean,
                        int r0, int M) {
  int nl = blockIdx.x * 4 + (threadIdx.x >> 6);
  int l = threadIdx.x & 63;
  int e4 = l >> 4;      // edge slot 0..3
  int d4 = l & 15;      // dim group (4 dims)
  if (nl >= M) return;
  int node = r0 + nl;
  int s = rowptr[node], e = rowptr[node + 1];
  float a0 = 0.f, a1 = 0.f, a2 = 0.f, a3 = 0.f;
  for (int i = s + e4; i < e; i += 4) {
    unsigned sc = (unsigned)eidx[i];
    if (sc < NN) {
      ushort4 v = ((const ushort4*)(X + (size_t)sc * 64))[d4];
      a0 += b2f(v.x); a1 += b2f(v.y); a2 += b2f(v.z); a3 += b2f(v.w);
    }
  }
  a0 += __shfl_xor(a0, 16); a0 += __shfl_xor(a0, 32);
  a1 += __shfl_xor(a1, 16); a1 += __shfl_xor(a1, 32);
  a2 += __shfl_xor(a2, 16); a2 += __shfl_xor(a2, 32);
  a3 += __shfl_xor(a3, 16); a3 += __shfl_xor(a3, 32);
  if (e4 == 0) {
    float inv = 1.f / (float)max(e - s, 1);
    ushort4 o; o.x = f2b(a0 * inv); o.y = f2b(a1 * inv); o.z = f2b(a2 * inv); o.w = f2b(a3 * inv);
    ((ushort4*)(mean + (size_t)nl * 64))[d4] = o;
  }
}

// agg256: wave = 2 edge-slots x 32 lanes x ushort8 (512B row), unroll-2.
__global__ void agg256_k(const ushort* __restrict__ X, const int* __restrict__ rowptr,
                         const int* __restrict__ eidx, ushort* __restrict__ mean,
                         int r0, int M) {
  int nl = blockIdx.x * 4 + (threadIdx.x >> 6);
  int l = threadIdx.x & 63;
  int g = l >> 5;       // edge slot 0..1
  int d = l & 31;       // 8-dim group
  if (nl >= M) return;
  int node = r0 + nl;
  int s = rowptr[node], e = rowptr[node + 1];
  float a[8], c[8];
#pragma unroll
  for (int k = 0; k < 8; ++k) { a[k] = 0.f; c[k] = 0.f; }
  for (int i = s + g; i < e; i += 4) {
    unsigned s0 = (unsigned)eidx[i];
    if (s0 < NN) {
      ushort8 v = *(const ushort8*)(X + (size_t)s0 * 256 + d * 8);
#pragma unroll
      for (int k = 0; k < 8; ++k) a[k] += b2f((ushort)v[k]);
    }
    int i2 = i + 2;
    if (i2 < e) {
      unsigned s1 = (unsigned)eidx[i2];
      if (s1 < NN) {
        ushort8 v = *(const ushort8*)(X + (size_t)s1 * 256 + d * 8);
#pragma unroll
        for (int k = 0; k < 8; ++k) c[k] += b2f((ushort)v[k]);
      }
    }
  }
  float inv = 1.f / (float)max(e - s, 1);
  ushort8 o;
#pragma unroll
  for (int k = 0; k < 8; ++k) {
    float t = a[k] + c[k];
    t += __shfl_xor(t, 32);
    o[k] = (short)f2b(t * inv);
  }
  if (g == 0) *(ushort8*)(mean + (size_t)nl * 256 + d * 8) = o;
}

// ------------------------------ bf16 MFMA GEMM ------------------------------
// C[M,Nc] = act(A1@B1 + A2@B2 + bias): A [M,K] bf16 rm, BT [Nc,K] bf16 rm.
// BM=128, BN in {64,128}, BK=64, 256 thr = 4 waves (2x2), 16x16x32 MFMA.
// XOR slot swizzle (kb ^= row&7), global_load_lds w/ pre-swizzled source.
template<int BN, bool RELU, bool OUTBF>
__global__ __launch_bounds__(256)
void mfma_gemm_k(const ushort* __restrict__ A1, const ushort* __restrict__ BT1, int K1,
                 const ushort* __restrict__ A2, const ushort* __restrict__ BT2, int K2,
                 const float* __restrict__ bias, void* __restrict__ Cv, int M, int Nc) {
  constexpr int NR = BN / 32;
  constexpr int WTN = BN / 2;
  __shared__ __align__(16) char As[128 * 64 * 2];
  __shared__ __align__(16) char Bs[BN * 64 * 2];
  const int tid = threadIdx.x;
  const int l = tid & 63;
  const int w = tid >> 6;
  const int wm = w >> 1, wn = w & 1;
  const int bm = blockIdx.x * 128, bn = blockIdx.y * BN;
  const int r15 = l & 15, g4 = l >> 4;

  f32x4 acc[4][NR];
  const f32x4 zz = {0.f, 0.f, 0.f, 0.f};
#pragma unroll
  for (int m = 0; m < 4; ++m)
#pragma unroll
    for (int n = 0; n < NR; ++n) acc[m][n] = zz;

  for (int pass = 0; pass < 2; ++pass) {
    const ushort* A = pass ? A2 : A1;
    const ushort* BT = pass ? BT2 : BT1;
    const int K = pass ? K2 : K1;
    if (!A) break;
    for (int k0 = 0; k0 < K; k0 += 64) {
#pragma unroll
      for (int p = 0; p < 4; ++p) {
        int idx = tid + p * 256;
        int row = idx >> 3, slot = idx & 7;
        int kb = slot ^ (row & 7);
        int grow = bm + row; if (grow >= M) grow = M - 1;
        gl_lds16(A + (size_t)grow * K + k0 + kb * 8, As + idx * 16);
      }
#pragma unroll
      for (int p = 0; p < BN / 32; ++p) {
        int idx = tid + p * 256;
        int row = idx >> 3, slot = idx & 7;
        int kb = slot ^ (row & 7);
        gl_lds16(BT + (size_t)(bn + row) * K + k0 + kb * 8, Bs + idx * 16);
      }
      __syncthreads();
#pragma unroll
      for (int s = 0; s < 2; ++s) {
        short8 a[4], b[NR];
        const int slotx = (((s * 4 + g4) ^ (r15 & 7)) << 4);
#pragma unroll
        for (int m = 0; m < 4; ++m) {
          int row = wm * 64 + m * 16 + r15;
          a[m] = *(const short8*)(As + row * 128 + slotx);
        }
#pragma unroll
        for (int n = 0; n < NR; ++n) {
          int row = wn * WTN + n * 16 + r15;
          b[n] = *(const short8*)(Bs + row * 128 + slotx);
        }
#pragma unroll
        for (int m = 0; m < 4; ++m)
#pragma unroll
          for (int n = 0; n < NR; ++n)
            acc[m][n] = __builtin_amdgcn_mfma_f32_16x16x32_bf16(a[m], b[n], acc[m][n], 0, 0, 0);
      }
      __syncthreads();
    }
  }
#pragma unroll
  for (int n = 0; n < NR; ++n) {
    int col = bn + wn * WTN + n * 16 + r15;
    float bv = bias ? bias[col] : 0.f;
#pragma unroll
    for (int m = 0; m < 4; ++m) {
#pragma unroll
      for (int j = 0; j < 4; ++j) {
        int row = bm + wm * 64 + m * 16 + g4 * 4 + j;
        if (row < M) {
          float v = acc[m][n][j] + bv;
          if (RELU) v = fmaxf(v, 0.f);
          if (OUTBF) ((ushort*)Cv)[(size_t)row * Nc + col] = f2b(v);
          else       ((float*)Cv)[(size_t)row * Nc + col] = v;
        }
      }
    }
  }
}

// ------------------------------ sbias[g] = dot(bq, Kmat[g]) ------------------------------
__global__ void sbias_k(const float* __restrict__ bq, const ushort* __restrict__ Kmat,
                        float* __restrict__ sbias) {
  int g = blockIdx.x * 4 + (threadIdx.x >> 6);
  int lane = threadIdx.x & 63;
  if (g >= 512) return;
  ushort4 kv = ((const ushort4*)(Kmat + (size_t)g * 256))[lane];
  float4 bv = ((const float4*)bq)[lane];
  float p = b2f(kv.x) * bv.x + b2f(kv.y) * bv.y + b2f(kv.z) * bv.z + b2f(kv.w) * bv.w;
  for (int off = 32; off; off >>= 1) p += __shfl_xor(p, off);
  if (lane == 0) sbias[g] = p;
}

// ------------------------------ softmax in place (bf16 logits -> bf16 P), scale 1/16 ------------------------------
__global__ void softmax_k(ushort* __restrict__ SP, int M) {
  int row = blockIdx.x * 4 + (threadIdx.x >> 6);
  int lane = threadIdx.x & 63;
  if (row >= M) return;
  ushort4* p = (ushort4*)(SP + (size_t)row * 512);
  ushort4 ua = p[lane];
  ushort4 ub = p[lane + 64];
  const float sc = 0.0625f;
  float ax = b2f(ua.x) * sc, ay = b2f(ua.y) * sc, az = b2f(ua.z) * sc, aw = b2f(ua.w) * sc;
  float bx = b2f(ub.x) * sc, by = b2f(ub.y) * sc, bz = b2f(ub.z) * sc, bw = b2f(ub.w) * sc;
  float m = fmaxf(fmaxf(fmaxf(ax, ay), fmaxf(az, aw)),
                  fmaxf(fmaxf(bx, by), fmaxf(bz, bw)));
  for (int off = 32; off; off >>= 1) m = fmaxf(m, __shfl_xor(m, off));
  ax = expf(ax - m); ay = expf(ay - m); az = expf(az - m); aw = expf(aw - m);
  bx = expf(bx - m); by = expf(by - m); bz = expf(bz - m); bw = expf(bw - m);
  float s = ax + ay + az + aw + bx + by + bz + bw;
  for (int off = 32; off; off >>= 1) s += __shfl_xor(s, off);
  float inv = 1.f / s;
  ushort4 oa, ob;
  oa.x = f2b(ax * inv); oa.y = f2b(ay * inv); oa.z = f2b(az * inv); oa.w = f2b(aw * inv);
  ob.x = f2b(bx * inv); ob.y = f2b(by * inv); ob.z = f2b(bz * inv); ob.w = f2b(bw * inv);
  p[lane] = oa;
  p[lane + 64] = ob;
}

// ------------------------------ final head ------------------------------
__global__ void out_k(const ushort* __restrict__ hidden, const float* __restrict__ Wm2,
                      const float* __restrict__ bm2, float* __restrict__ out, int M) {
  int row = blockIdx.x * 4 + (threadIdx.x >> 6);
  int lane = threadIdx.x & 63;
  if (row >= M) return;
  ushort4 hv = ((const ushort4*)(hidden + (size_t)row * 256))[lane];
  float h0 = b2f(hv.x), h1 = b2f(hv.y), h2 = b2f(hv.z), h3 = b2f(hv.w);
  int k = lane * 4;
  float p0 = h0 * Wm2[(k + 0) * 2 + 0] + h1 * Wm2[(k + 1) * 2 + 0] +
             h2 * Wm2[(k + 2) * 2 + 0] + h3 * Wm2[(k + 3) * 2 + 0];
  float p1 = h0 * Wm2[(k + 0) * 2 + 1] + h1 * Wm2[(k + 1) * 2 + 1] +
             h2 * Wm2[(k + 2) * 2 + 1] + h3 * Wm2[(k + 3) * 2 + 1];
  for (int off = 32; off; off >>= 1) {
    p0 += __shfl_xor(p0, off);
    p1 += __shfl_xor(p1, off);
  }
  if (lane == 0) {
    out[(size_t)row * 2 + 0] = p0 + bm2[0];
    out[(size_t)row * 2 + 1] = p1 + bm2[1];
  }
}

// ------------------------------ launch ------------------------------
extern "C" void kernel_launch(void* const* d_in, const int* in_sizes, int n_in,
                              void* d_out, int out_size, void* d_ws, size_t ws_size,
                              hipStream_t stream) {
  const int N = NN, E = NE;
  const float* x   = (const float*)d_in[0];
  const int*   ei  = (const int*)d_in[1];
  const float* gc  = (const float*)d_in[2];
  const float* Wp  = (const float*)d_in[3];
  const float* bp  = (const float*)d_in[4];
  const float* W1l = (const float*)d_in[5];
  const float* b1l = (const float*)d_in[6];
  const float* W1r = (const float*)d_in[7];
  const float* W2l = (const float*)d_in[8];
  const float* b2l = (const float*)d_in[9];
  const float* W2r = (const float*)d_in[10];
  const float* Wq  = (const float*)d_in[11];
  const float* bq  = (const float*)d_in[12];
  const float* Wk  = (const float*)d_in[13];
  const float* bk  = (const float*)d_in[14];
  const float* Wv  = (const float*)d_in[15];
  const float* bv  = (const float*)d_in[16];
  const float* Wm1 = (const float*)d_in[17];
  const float* bm1 = (const float*)d_in[18];
  const float* Wm2 = (const float*)d_in[19];
  const float* bm2 = (const float*)d_in[20];
  float* out = (float*)d_out;

  char* base = (char*)d_ws;
  size_t off = 0;
  auto take = [&](size_t bytes) -> void* {
    void* r = base + off;
    off += (bytes + 255) & ~(size_t)255;
    return r;
  };
  // CSR + misc
  int* cnt    = (int*)take((size_t)N * 4);
  int* rowptr = (int*)take((size_t)(N + 1) * 4);
  int* cursor = (int*)take((size_t)N * 4);
  int* eidx   = (int*)take((size_t)E * 4);
  int* eflag  = (int*)take(256);
  int* bsum   = (int*)take(NB1 * 4);
  int* boff   = (int*)take(NB1 * 4);
  // bf16 weights
  ushort* WpT   = (ushort*)take((size_t)64 * 128 * 2);
  ushort* W1lT  = (ushort*)take((size_t)256 * 64 * 2);
  ushort* W1rT  = (ushort*)take((size_t)256 * 64 * 2);
  ushort* W2lT  = (ushort*)take((size_t)256 * 256 * 2);
  ushort* W2rT  = (ushort*)take((size_t)256 * 256 * 2);
  ushort* WkT   = (ushort*)take((size_t)256 * 256 * 2);
  ushort* WvT   = (ushort*)take((size_t)256 * 256 * 2);
  ushort* Wqb   = (ushort*)take((size_t)256 * 256 * 2);
  ushort* Wm1aT = (ushort*)take((size_t)256 * 256 * 2);
  ushort* Wm1bT = (ushort*)take((size_t)256 * 256 * 2);
  // attention small
  ushort* gcb   = (ushort*)take((size_t)512 * 256 * 2);
  ushort* Kmatb = (ushort*)take((size_t)512 * 256 * 2);
  float*  Vmatf = (float*)take((size_t)512 * 256 * 4);
  ushort* VT    = (ushort*)take((size_t)256 * 512 * 2);
  ushort* KWqT  = (ushort*)take((size_t)512 * 256 * 2);
  float*  sbias = (float*)take((size_t)512 * 4);
  // region U: pre-loop {xb, x_emb, mean1} then chunk buffers (3072B/row)
  const size_t szU_pre = (size_t)N * 128 * 2 + (size_t)N * 64 * 2 + (size_t)N * 64 * 2;
  const size_t szU_chunk = (size_t)CR * 3072;
  char* U = (char*)take(szU_pre > szU_chunk ? szU_pre : szU_chunk);
  ushort* h = (ushort*)take((size_t)N * 256 * 2);   // live whole run
  if (off > ws_size) return;

  ushort* xb    = (ushort*)U;
  ushort* x_emb = (ushort*)(U + (size_t)N * 128 * 2);
  ushort* mean1 = (ushort*)(U + (size_t)N * 128 * 2 + (size_t)N * 64 * 2);
  ushort* mean2_c  = (ushort*)U;                        // CR*256 bf16
  ushort* h2_c     = (ushort*)(U + (size_t)CR * 512);   // CR*256 bf16
  ushort* SP_c     = (ushort*)(U + (size_t)CR * 1024);  // CR*512 bf16 (S then P)
  ushort* g_c      = (ushort*)(U + (size_t)CR * 2048);  // CR*256 bf16
  ushort* hidden_c = (ushort*)(U + (size_t)CR * 2560);  // CR*256 bf16

  const int MB = (N + 127) / 128;
  dim3 thr(256);

  // CSR build
  zero_i32_k<<<(N + 255) / 256, thr, 0, stream>>>(cnt, N);
  detect_i64_k<<<1, 256, 0, stream>>>(ei, eflag);
  count_edges_k<<<(E / 4 + 255) / 256, thr, 0, stream>>>(ei, eflag, cnt, E);
  scan1_k<<<NB1, thr, 0, stream>>>(cnt, rowptr, bsum, N);
  scan2_k<<<1, 128, 0, stream>>>(bsum, boff, NB1);
  scan3_k<<<(N + 255) / 256, thr, 0, stream>>>(cnt, rowptr, cursor, boff, N);
  fill_edges_k<<<(E / 4 + 255) / 256, thr, 0, stream>>>(ei, eflag, cursor, eidx, E);

  // input conversion (big) + merged weight conversions
  cvt4_k<<<(N * 128 / 4 + 255) / 256, thr, 0, stream>>>(x, xb, N * 128 / 4);
  {
    CvtJobs jb;
    const float* s_[NJOB] = {gc, Wq, Wp, W1l, W1r, W2l, W2r, Wk, Wv, Wm1, Wm1};
    ushort* d_[NJOB] = {gcb, Wqb, WpT, W1lT, W1rT, W2lT, W2rT, WkT, WvT, Wm1aT, Wm1bT};
    int R_[NJOB] = {512, 256, 128, 64, 64, 256, 256, 256, 256, 256, 256};
    int C_[NJOB] = {256, 256, 64, 256, 256, 256, 256, 256, 256, 256, 256};
    int o_[NJOB] = {0, 0, 0, 0, 0, 0, 0, 0, 0, 0, 256};
    int t_[NJOB] = {0, 0, 1, 1, 1, 1, 1, 1, 1, 1, 1};
    for (int j = 0; j < NJOB; ++j) {
      jb.src[j] = s_[j]; jb.dst[j] = d_[j]; jb.R[j] = R_[j]; jb.C[j] = C_[j];
      jb.off[j] = o_[j]; jb.tr[j] = t_[j];
    }
    wcvt_k<<<dim3(32, NJOB), thr, 0, stream>>>(jb);
  }

  // attention pre: Kmat(bf16), Vmat(f32)->VT, KWqT = Kmat @ Wq^T, sbias
  mfma_gemm_k<128, false, true><<<dim3(4, 2), thr, 0, stream>>>(
      gcb, WkT, 256, nullptr, nullptr, 0, bk, Kmatb, 512, 256);
  mfma_gemm_k<128, false, false><<<dim3(4, 2), thr, 0, stream>>>(
      gcb, WvT, 256, nullptr, nullptr, 0, bv, Vmatf, 512, 256);
  tcvt_k<<<(512 * 256 + 255) / 256, thr, 0, stream>>>(Vmatf, VT, 512, 256, 0);
  mfma_gemm_k<128, false, true><<<dim3(4, 2), thr, 0, stream>>>(
      Kmatb, Wqb, 256, nullptr, nullptr, 0, nullptr, KWqT, 512, 256);
  sbias_k<<<128, thr, 0, stream>>>(bq, Kmatb, sbias);

  // embed: x_emb = relu(xb @ Wp + bp)
  mfma_gemm_k<64, true, true><<<dim3(MB, 1), thr, 0, stream>>>(
      xb, WpT, 128, nullptr, nullptr, 0, bp, x_emb, N, 64);
  // SAGE1
  agg64_k<<<(N + 3) / 4, thr, 0, stream>>>(x_emb, rowptr, eidx, mean1, 0, N);
  mfma_gemm_k<128, true, true><<<dim3(MB, 2), thr, 0, stream>>>(
      mean1, W1lT, 64, x_emb, W1rT, 64, b1l, h, N, 256);

  // chunked SAGE2 + attention + MLP head
  for (int r0 = 0; r0 < N; r0 += CR) {
    const int CRc = (N - r0 < CR) ? (N - r0) : CR;
    const int MBc = (CRc + 127) / 128;
    agg256_k<<<(CRc + 3) / 4, thr, 0, stream>>>(h, rowptr, eidx, mean2_c, r0, CRc);
    mfma_gemm_k<128, false, true><<<dim3(MBc, 2), thr, 0, stream>>>(
        mean2_c, W2lT, 256, h + (size_t)r0 * 256, W2rT, 256, b2l, h2_c, CRc, 256);
    mfma_gemm_k<128, false, true><<<dim3(MBc, 4), thr, 0, stream>>>(
        h2_c, KWqT, 256, nullptr, nullptr, 0, sbias, SP_c, CRc, 512);
    softmax_k<<<(CRc + 3) / 4, thr, 0, stream>>>(SP_c, CRc);
    mfma_gemm_k<128, false, true><<<dim3(MBc, 2), thr, 0, stream>>>(
        SP_c, VT, 512, nullptr, nullptr, 0, nullptr, g_c, CRc, 256);
    mfma_gemm_k<128, true, true><<<dim3(MBc, 2), thr, 0, stream>>>(
        h2_c, Wm1aT, 256, g_c, Wm1bT, 256, bm1, hidden_c, CRc, 256);
    out_k<<<(CRc + 3) / 4, thr, 0, stream>>>(hidden_c, Wm2, bm2, out + (size_t)r0 * 2, CRc);
  }
}

// Round 8
// 766.895 us; speedup vs baseline: 3.6149x; 1.0770x over previous
//
#include <hip/hip_runtime.h>
#include <cstdint>
#include <cstddef>

// GAAPModelB on MI355X: bf16-MFMA GEMM stack + CSR gather aggregation.
// N=100000, E=800000, IN=128, H=256, G=512. Chunked post-SAGE1 pipeline.
// R8: CSR kernels reverted to 1 edge/thread (R7's 4/thr was slower: random
// 64B-line write-bound, needs TLP not ILP). MLP GEMM fused with output head
// (BN=256 + in-register 256->2 dot, removes hidden buffer + out_k).

#define NN 100000
#define NE 800000
#define CR 32768   // chunk rows
#define NB1 98     // ceil(100000/1024) scan blocks

typedef __attribute__((ext_vector_type(8))) short short8;
typedef __attribute__((ext_vector_type(8))) unsigned short ushort8;
typedef __attribute__((ext_vector_type(4))) float f32x4;

__device__ __forceinline__ float b2f(ushort u) {
  union { unsigned u; float f; } v; v.u = ((unsigned)u) << 16; return v.f;
}
__device__ __forceinline__ ushort f2b(float f) {
  union { float f; unsigned u; } v; v.f = f;
  unsigned r = v.u + 0x7FFFu + ((v.u >> 16) & 1u);
  return (ushort)(r >> 16);
}
__device__ __forceinline__ void gl_lds16(const void* g, void* l) {
  __builtin_amdgcn_global_load_lds((const __attribute__((address_space(1))) void*)g,
                                   (__attribute__((address_space(3))) void*)l, 16, 0, 0);
}

// ------------------------------ utility ------------------------------
__global__ void zero_i32_k(int* __restrict__ p, int n) {
  int i = blockIdx.x * 256 + threadIdx.x;
  if (i < n) p[i] = 0;
}

// flag=1 iff edge_index is int64 (odd words of first 256 entries all zero)
__global__ void detect_i64_k(const int* __restrict__ ei, int* __restrict__ flag) {
  __shared__ int ok;
  int t = threadIdx.x;
  if (t == 0) ok = 1;
  __syncthreads();
  if (ei[2 * t + 1] != 0) ok = 0;
  __syncthreads();
  if (t == 0) *flag = ok;
}

// f32 -> bf16 flat, 4 elems/thread (big arrays)
__global__ void cvt4_k(const float* __restrict__ src, ushort* __restrict__ dst, int n4) {
  int i = blockIdx.x * 256 + threadIdx.x;
  if (i < n4) {
    float4 v = ((const float4*)src)[i];
    ushort4 o; o.x = f2b(v.x); o.y = f2b(v.y); o.z = f2b(v.z); o.w = f2b(v.w);
    ((ushort4*)dst)[i] = o;
  }
}

// transpose-convert: dst[c*R + r] = bf16(src[(row_off+r)*C + c])
__global__ void tcvt_k(const float* __restrict__ src, ushort* __restrict__ dst,
                       int R, int C, int row_off) {
  int i = blockIdx.x * 256 + threadIdx.x;
  if (i < R * C) {
    int r = i / C, c = i % C;
    dst[(size_t)c * R + r] = f2b(src[(size_t)(row_off + r) * C + c]);
  }
}

// merged small weight conversions: 11 jobs, grid.y = job
#define NJOB 11
struct CvtJobs {
  const float* src[NJOB];
  ushort* dst[NJOB];
  int R[NJOB], C[NJOB], off[NJOB], tr[NJOB];
};
__global__ void wcvt_k(CvtJobs jb) {
  const int j = blockIdx.y;
  const int Cj = jb.C[j], Rj = jb.R[j];
  const int n = Rj * Cj;
  for (int i = blockIdx.x * 256 + threadIdx.x; i < n; i += gridDim.x * 256) {
    if (jb.tr[j]) {
      int r = i / Cj, c = i % Cj;
      jb.dst[j][(size_t)c * Rj + r] = f2b(jb.src[j][(size_t)(jb.off[j] + r) * Cj + c]);
    } else {
      jb.dst[j][i] = f2b(jb.src[j][i]);
    }
  }
}

// ------------------------------ CSR build (1 edge/thread — R6 measured best) ------------------------------
__global__ void count_edges_k(const int* __restrict__ ei, const int* __restrict__ flag,
                              int* __restrict__ cnt, int E) {
  int i = blockIdx.x * 256 + threadIdx.x;
  if (i >= E) return;
  const bool i64 = (*flag != 0);
  unsigned d = (unsigned)(i64 ? ei[2 * E + 2 * i] : ei[E + i]);
  if (d < NN) atomicAdd(&cnt[d], 1);
}

__global__ __launch_bounds__(256)
void scan1_k(const int* __restrict__ cnt, int* __restrict__ rowptr,
             int* __restrict__ bsum, int n) {
  __shared__ int ls[256];
  const int b = blockIdx.x, t = threadIdx.x;
  const int base = b * 1024 + t * 4;
  int v[4]; int s = 0;
#pragma unroll
  for (int j = 0; j < 4; ++j) { int i = base + j; v[j] = (i < n) ? cnt[i] : 0; s += v[j]; }
  ls[t] = s; __syncthreads();
  int x = s;
  for (int o = 1; o < 256; o <<= 1) {
    int a = (t >= o) ? ls[t - o] : 0; __syncthreads();
    x += a; ls[t] = x; __syncthreads();
  }
  int run = x - s;
#pragma unroll
  for (int j = 0; j < 4; ++j) { run += v[j]; int i = base + j; if (i < n) rowptr[i + 1] = run; }
  if (t == 255) bsum[b] = x;
}

__global__ void scan2_k(const int* __restrict__ bsum, int* __restrict__ boff, int nb) {
  __shared__ int ls[128];
  int t = threadIdx.x;
  int v = (t < nb) ? bsum[t] : 0;
  ls[t] = v; __syncthreads();
  int x = v;
  for (int o = 1; o < 128; o <<= 1) {
    int a = (t >= o) ? ls[t - o] : 0; __syncthreads();
    x += a; ls[t] = x; __syncthreads();
  }
  if (t < nb) boff[t] = x - v;
}

__global__ void scan3_k(const int* __restrict__ cnt, int* __restrict__ rowptr,
                        int* __restrict__ cursor, const int* __restrict__ boff, int n) {
  int i = blockIdx.x * 256 + threadIdx.x;
  if (i == 0) rowptr[0] = 0;
  if (i < n) {
    int r = rowptr[i + 1] + boff[i >> 10];
    rowptr[i + 1] = r;
    cursor[i] = r - cnt[i];
  }
}

__global__ void fill_edges_k(const int* __restrict__ ei, const int* __restrict__ flag,
                             int* __restrict__ cursor, int* __restrict__ eidx, int E) {
  int i = blockIdx.x * 256 + threadIdx.x;
  if (i >= E) return;
  const bool i64 = (*flag != 0);
  unsigned s = (unsigned)(i64 ? ei[2 * i] : ei[i]);
  unsigned d = (unsigned)(i64 ? ei[2 * E + 2 * i] : ei[E + i]);
  if (d < NN && s < NN) {
    int p = atomicAdd(&cursor[d], 1);
    if ((unsigned)p < (unsigned)E) eidx[p] = (int)s;
  }
}

// ------------------------------ aggregation ------------------------------
// agg64: wave = 4 edge-slots x 16 dim-lanes (ushort4). Dependent chain /4.
__global__ void agg64_k(const ushort* __restrict__ X, const int* __restrict__ rowptr,
                        const int* __restrict__ eidx, ushort* __restrict__ mean,
                        int r0, int M) {
  int nl = blockIdx.x * 4 + (threadIdx.x >> 6);
  int l = threadIdx.x & 63;
  int e4 = l >> 4;      // edge slot 0..3
  int d4 = l & 15;      // dim group (4 dims)
  if (nl >= M) return;
  int node = r0 + nl;
  int s = rowptr[node], e = rowptr[node + 1];
  float a0 = 0.f, a1 = 0.f, a2 = 0.f, a3 = 0.f;
  for (int i = s + e4; i < e; i += 4) {
    unsigned sc = (unsigned)eidx[i];
    if (sc < NN) {
      ushort4 v = ((const ushort4*)(X + (size_t)sc * 64))[d4];
      a0 += b2f(v.x); a1 += b2f(v.y); a2 += b2f(v.z); a3 += b2f(v.w);
    }
  }
  a0 += __shfl_xor(a0, 16); a0 += __shfl_xor(a0, 32);
  a1 += __shfl_xor(a1, 16); a1 += __shfl_xor(a1, 32);
  a2 += __shfl_xor(a2, 16); a2 += __shfl_xor(a2, 32);
  a3 += __shfl_xor(a3, 16); a3 += __shfl_xor(a3, 32);
  if (e4 == 0) {
    float inv = 1.f / (float)max(e - s, 1);
    ushort4 o; o.x = f2b(a0 * inv); o.y = f2b(a1 * inv); o.z = f2b(a2 * inv); o.w = f2b(a3 * inv);
    ((ushort4*)(mean + (size_t)nl * 64))[d4] = o;
  }
}

// agg256: wave = 2 edge-slots x 32 lanes x ushort8 (512B row), unroll-2.
__global__ void agg256_k(const ushort* __restrict__ X, const int* __restrict__ rowptr,
                         const int* __restrict__ eidx, ushort* __restrict__ mean,
                         int r0, int M) {
  int nl = blockIdx.x * 4 + (threadIdx.x >> 6);
  int l = threadIdx.x & 63;
  int g = l >> 5;       // edge slot 0..1
  int d = l & 31;       // 8-dim group
  if (nl >= M) return;
  int node = r0 + nl;
  int s = rowptr[node], e = rowptr[node + 1];
  float a[8], c[8];
#pragma unroll
  for (int k = 0; k < 8; ++k) { a[k] = 0.f; c[k] = 0.f; }
  for (int i = s + g; i < e; i += 4) {
    unsigned s0 = (unsigned)eidx[i];
    if (s0 < NN) {
      ushort8 v = *(const ushort8*)(X + (size_t)s0 * 256 + d * 8);
#pragma unroll
      for (int k = 0; k < 8; ++k) a[k] += b2f((ushort)v[k]);
    }
    int i2 = i + 2;
    if (i2 < e) {
      unsigned s1 = (unsigned)eidx[i2];
      if (s1 < NN) {
        ushort8 v = *(const ushort8*)(X + (size_t)s1 * 256 + d * 8);
#pragma unroll
        for (int k = 0; k < 8; ++k) c[k] += b2f((ushort)v[k]);
      }
    }
  }
  float inv = 1.f / (float)max(e - s, 1);
  ushort8 o;
#pragma unroll
  for (int k = 0; k < 8; ++k) {
    float t = a[k] + c[k];
    t += __shfl_xor(t, 32);
    o[k] = (short)f2b(t * inv);
  }
  if (g == 0) *(ushort8*)(mean + (size_t)nl * 256 + d * 8) = o;
}

// ------------------------------ bf16 MFMA GEMM ------------------------------
// C[M,Nc] = act(A1@B1 + A2@B2 + bias): A [M,K] bf16 rm, BT [Nc,K] bf16 rm.
// BM=128, BN in {64,128}, BK=64, 256 thr = 4 waves (2x2), 16x16x32 MFMA.
// XOR slot swizzle (kb ^= row&7), global_load_lds w/ pre-swizzled source.
template<int BN, bool RELU, bool OUTBF>
__global__ __launch_bounds__(256)
void mfma_gemm_k(const ushort* __restrict__ A1, const ushort* __restrict__ BT1, int K1,
                 const ushort* __restrict__ A2, const ushort* __restrict__ BT2, int K2,
                 const float* __restrict__ bias, void* __restrict__ Cv, int M, int Nc) {
  constexpr int NR = BN / 32;
  constexpr int WTN = BN / 2;
  __shared__ __align__(16) char As[128 * 64 * 2];
  __shared__ __align__(16) char Bs[BN * 64 * 2];
  const int tid = threadIdx.x;
  const int l = tid & 63;
  const int w = tid >> 6;
  const int wm = w >> 1, wn = w & 1;
  const int bm = blockIdx.x * 128, bn = blockIdx.y * BN;
  const int r15 = l & 15, g4 = l >> 4;

  f32x4 acc[4][NR];
  const f32x4 zz = {0.f, 0.f, 0.f, 0.f};
#pragma unroll
  for (int m = 0; m < 4; ++m)
#pragma unroll
    for (int n = 0; n < NR; ++n) acc[m][n] = zz;

  for (int pass = 0; pass < 2; ++pass) {
    const ushort* A = pass ? A2 : A1;
    const ushort* BT = pass ? BT2 : BT1;
    const int K = pass ? K2 : K1;
    if (!A) break;
    for (int k0 = 0; k0 < K; k0 += 64) {
#pragma unroll
      for (int p = 0; p < 4; ++p) {
        int idx = tid + p * 256;
        int row = idx >> 3, slot = idx & 7;
        int kb = slot ^ (row & 7);
        int grow = bm + row; if (grow >= M) grow = M - 1;
        gl_lds16(A + (size_t)grow * K + k0 + kb * 8, As + idx * 16);
      }
#pragma unroll
      for (int p = 0; p < BN / 32; ++p) {
        int idx = tid + p * 256;
        int row = idx >> 3, slot = idx & 7;
        int kb = slot ^ (row & 7);
        gl_lds16(BT + (size_t)(bn + row) * K + k0 + kb * 8, Bs + idx * 16);
      }
      __syncthreads();
#pragma unroll
      for (int s = 0; s < 2; ++s) {
        short8 a[4], b[NR];
        const int slotx = (((s * 4 + g4) ^ (r15 & 7)) << 4);
#pragma unroll
        for (int m = 0; m < 4; ++m) {
          int row = wm * 64 + m * 16 + r15;
          a[m] = *(const short8*)(As + row * 128 + slotx);
        }
#pragma unroll
        for (int n = 0; n < NR; ++n) {
          int row = wn * WTN + n * 16 + r15;
          b[n] = *(const short8*)(Bs + row * 128 + slotx);
        }
#pragma unroll
        for (int m = 0; m < 4; ++m)
#pragma unroll
          for (int n = 0; n < NR; ++n)
            acc[m][n] = __builtin_amdgcn_mfma_f32_16x16x32_bf16(a[m], b[n], acc[m][n], 0, 0, 0);
      }
      __syncthreads();
    }
  }
#pragma unroll
  for (int n = 0; n < NR; ++n) {
    int col = bn + wn * WTN + n * 16 + r15;
    float bv = bias ? bias[col] : 0.f;
#pragma unroll
    for (int m = 0; m < 4; ++m) {
#pragma unroll
      for (int j = 0; j < 4; ++j) {
        int row = bm + wm * 64 + m * 16 + g4 * 4 + j;
        if (row < M) {
          float v = acc[m][n][j] + bv;
          if (RELU) v = fmaxf(v, 0.f);
          if (OUTBF) ((ushort*)Cv)[(size_t)row * Nc + col] = f2b(v);
          else       ((float*)Cv)[(size_t)row * Nc + col] = v;
        }
      }
    }
  }
}

// ------------------------------ fused MLP + output head ------------------------------
// hidden = relu(h2@Wm1a + g@Wm1b + bm1) computed in-register (BN=256, grid.y=1),
// then out[row][0:2] = hidden . Wm2 + bm2 via lane/wave reduction. No hidden buffer.
__global__ __launch_bounds__(256)
void mlp_out_k(const ushort* __restrict__ A1, const ushort* __restrict__ BT1,
               const ushort* __restrict__ A2, const ushort* __restrict__ BT2,
               const float* __restrict__ bias, const float* __restrict__ Wm2,
               const float* __restrict__ bm2, float* __restrict__ out, int M) {
  constexpr int NR = 8;      // 256/32
  constexpr int WTN = 128;
  __shared__ __align__(16) char As[128 * 64 * 2];
  __shared__ __align__(16) char Bs[256 * 64 * 2];
  const int tid = threadIdx.x;
  const int l = tid & 63;
  const int w = tid >> 6;
  const int wm = w >> 1, wn = w & 1;
  const int bm = blockIdx.x * 128;
  const int r15 = l & 15, g4 = l >> 4;

  f32x4 acc[4][NR];
  const f32x4 zz = {0.f, 0.f, 0.f, 0.f};
#pragma unroll
  for (int m = 0; m < 4; ++m)
#pragma unroll
    for (int n = 0; n < NR; ++n) acc[m][n] = zz;

  for (int pass = 0; pass < 2; ++pass) {
    const ushort* A = pass ? A2 : A1;
    const ushort* BT = pass ? BT2 : BT1;
    for (int k0 = 0; k0 < 256; k0 += 64) {
#pragma unroll
      for (int p = 0; p < 4; ++p) {
        int idx = tid + p * 256;
        int row = idx >> 3, slot = idx & 7;
        int kb = slot ^ (row & 7);
        int grow = bm + row; if (grow >= M) grow = M - 1;
        gl_lds16(A + (size_t)grow * 256 + k0 + kb * 8, As + idx * 16);
      }
#pragma unroll
      for (int p = 0; p < 8; ++p) {
        int idx = tid + p * 256;
        int row = idx >> 3, slot = idx & 7;
        int kb = slot ^ (row & 7);
        gl_lds16(BT + (size_t)row * 256 + k0 + kb * 8, Bs + idx * 16);
      }
      __syncthreads();
#pragma unroll
      for (int s = 0; s < 2; ++s) {
        short8 a[4], b[NR];
        const int slotx = (((s * 4 + g4) ^ (r15 & 7)) << 4);
#pragma unroll
        for (int m = 0; m < 4; ++m) {
          int row = wm * 64 + m * 16 + r15;
          a[m] = *(const short8*)(As + row * 128 + slotx);
        }
#pragma unroll
        for (int n = 0; n < NR; ++n) {
          int row = wn * WTN + n * 16 + r15;
          b[n] = *(const short8*)(Bs + row * 128 + slotx);
        }
#pragma unroll
        for (int m = 0; m < 4; ++m)
#pragma unroll
          for (int n = 0; n < NR; ++n)
            acc[m][n] = __builtin_amdgcn_mfma_f32_16x16x32_bf16(a[m], b[n], acc[m][n], 0, 0, 0);
      }
      __syncthreads();
    }
  }
  // per-lane weights for its 8 cols
  float bv[NR], w20[NR], w21[NR];
#pragma unroll
  for (int n = 0; n < NR; ++n) {
    int col = wn * WTN + n * 16 + r15;
    bv[n] = bias[col];
    w20[n] = Wm2[col * 2 + 0];
    w21[n] = Wm2[col * 2 + 1];
  }
  // red[wn][row_local][j01]
  float* red = (float*)As;   // 2*128*2 floats = 2KB, LDS free after last barrier
#pragma unroll
  for (int m = 0; m < 4; ++m) {
#pragma unroll
    for (int j = 0; j < 4; ++j) {
      float p0 = 0.f, p1 = 0.f;
#pragma unroll
      for (int n = 0; n < NR; ++n) {
        float v = fmaxf(acc[m][n][j] + bv[n], 0.f);
        p0 += v * w20[n];
        p1 += v * w21[n];
      }
      p0 += __shfl_xor(p0, 1); p1 += __shfl_xor(p1, 1);
      p0 += __shfl_xor(p0, 2); p1 += __shfl_xor(p1, 2);
      p0 += __shfl_xor(p0, 4); p1 += __shfl_xor(p1, 4);
      p0 += __shfl_xor(p0, 8); p1 += __shfl_xor(p1, 8);
      if (r15 == 0) {
        int rl = wm * 64 + m * 16 + g4 * 4 + j;
        red[wn * 256 + rl * 2 + 0] = p0;
        red[wn * 256 + rl * 2 + 1] = p1;
      }
    }
  }
  __syncthreads();
  int rl = tid >> 1, j = tid & 1;
  int row = bm + rl;
  if (row < M)
    out[(size_t)row * 2 + j] = red[rl * 2 + j] + red[256 + rl * 2 + j] + bm2[j];
}

// ------------------------------ sbias[g] = dot(bq, Kmat[g]) ------------------------------
__global__ void sbias_k(const float* __restrict__ bq, const ushort* __restrict__ Kmat,
                        float* __restrict__ sbias) {
  int g = blockIdx.x * 4 + (threadIdx.x >> 6);
  int lane = threadIdx.x & 63;
  if (g >= 512) return;
  ushort4 kv = ((const ushort4*)(Kmat + (size_t)g * 256))[lane];
  float4 bv = ((const float4*)bq)[lane];
  float p = b2f(kv.x) * bv.x + b2f(kv.y) * bv.y + b2f(kv.z) * bv.z + b2f(kv.w) * bv.w;
  for (int off = 32; off; off >>= 1) p += __shfl_xor(p, off);
  if (lane == 0) sbias[g] = p;
}

// ------------------------------ softmax in place (bf16 logits -> bf16 P), scale 1/16 ------------------------------
__global__ void softmax_k(ushort* __restrict__ SP, int M) {
  int row = blockIdx.x * 4 + (threadIdx.x >> 6);
  int lane = threadIdx.x & 63;
  if (row >= M) return;
  ushort4* p = (ushort4*)(SP + (size_t)row * 512);
  ushort4 ua = p[lane];
  ushort4 ub = p[lane + 64];
  const float sc = 0.0625f;
  float ax = b2f(ua.x) * sc, ay = b2f(ua.y) * sc, az = b2f(ua.z) * sc, aw = b2f(ua.w) * sc;
  float bx = b2f(ub.x) * sc, by = b2f(ub.y) * sc, bz = b2f(ub.z) * sc, bw = b2f(ub.w) * sc;
  float m = fmaxf(fmaxf(fmaxf(ax, ay), fmaxf(az, aw)),
                  fmaxf(fmaxf(bx, by), fmaxf(bz, bw)));
  for (int off = 32; off; off >>= 1) m = fmaxf(m, __shfl_xor(m, off));
  ax = expf(ax - m); ay = expf(ay - m); az = expf(az - m); aw = expf(aw - m);
  bx = expf(bx - m); by = expf(by - m); bz = expf(bz - m); bw = expf(bw - m);
  float s = ax + ay + az + aw + bx + by + bz + bw;
  for (int off = 32; off; off >>= 1) s += __shfl_xor(s, off);
  float inv = 1.f / s;
  ushort4 oa, ob;
  oa.x = f2b(ax * inv); oa.y = f2b(ay * inv); oa.z = f2b(az * inv); oa.w = f2b(aw * inv);
  ob.x = f2b(bx * inv); ob.y = f2b(by * inv); ob.z = f2b(bz * inv); ob.w = f2b(bw * inv);
  p[lane] = oa;
  p[lane + 64] = ob;
}

// ------------------------------ launch ------------------------------
extern "C" void kernel_launch(void* const* d_in, const int* in_sizes, int n_in,
                              void* d_out, int out_size, void* d_ws, size_t ws_size,
                              hipStream_t stream) {
  const int N = NN, E = NE;
  const float* x   = (const float*)d_in[0];
  const int*   ei  = (const int*)d_in[1];
  const float* gc  = (const float*)d_in[2];
  const float* Wp  = (const float*)d_in[3];
  const float* bp  = (const float*)d_in[4];
  const float* W1l = (const float*)d_in[5];
  const float* b1l = (const float*)d_in[6];
  const float* W1r = (const float*)d_in[7];
  const float* W2l = (const float*)d_in[8];
  const float* b2l = (const float*)d_in[9];
  const float* W2r = (const float*)d_in[10];
  const float* Wq  = (const float*)d_in[11];
  const float* bq  = (const float*)d_in[12];
  const float* Wk  = (const float*)d_in[13];
  const float* bk  = (const float*)d_in[14];
  const float* Wv  = (const float*)d_in[15];
  const float* bv  = (const float*)d_in[16];
  const float* Wm1 = (const float*)d_in[17];
  const float* bm1 = (const float*)d_in[18];
  const float* Wm2 = (const float*)d_in[19];
  const float* bm2 = (const float*)d_in[20];
  float* out = (float*)d_out;

  char* base = (char*)d_ws;
  size_t off = 0;
  auto take = [&](size_t bytes) -> void* {
    void* r = base + off;
    off += (bytes + 255) & ~(size_t)255;
    return r;
  };
  // CSR + misc
  int* cnt    = (int*)take((size_t)N * 4);
  int* rowptr = (int*)take((size_t)(N + 1) * 4);
  int* cursor = (int*)take((size_t)N * 4);
  int* eidx   = (int*)take((size_t)E * 4);
  int* eflag  = (int*)take(256);
  int* bsum   = (int*)take(NB1 * 4);
  int* boff   = (int*)take(NB1 * 4);
  // bf16 weights
  ushort* WpT   = (ushort*)take((size_t)64 * 128 * 2);
  ushort* W1lT  = (ushort*)take((size_t)256 * 64 * 2);
  ushort* W1rT  = (ushort*)take((size_t)256 * 64 * 2);
  ushort* W2lT  = (ushort*)take((size_t)256 * 256 * 2);
  ushort* W2rT  = (ushort*)take((size_t)256 * 256 * 2);
  ushort* WkT   = (ushort*)take((size_t)256 * 256 * 2);
  ushort* WvT   = (ushort*)take((size_t)256 * 256 * 2);
  ushort* Wqb   = (ushort*)take((size_t)256 * 256 * 2);
  ushort* Wm1aT = (ushort*)take((size_t)256 * 256 * 2);
  ushort* Wm1bT = (ushort*)take((size_t)256 * 256 * 2);
  // attention small
  ushort* gcb   = (ushort*)take((size_t)512 * 256 * 2);
  ushort* Kmatb = (ushort*)take((size_t)512 * 256 * 2);
  float*  Vmatf = (float*)take((size_t)512 * 256 * 4);
  ushort* VT    = (ushort*)take((size_t)256 * 512 * 2);
  ushort* KWqT  = (ushort*)take((size_t)512 * 256 * 2);
  float*  sbias = (float*)take((size_t)512 * 4);
  // region U: pre-loop {xb, x_emb, mean1} then chunk buffers (2560B/row)
  const size_t szU_pre = (size_t)N * 128 * 2 + (size_t)N * 64 * 2 + (size_t)N * 64 * 2;
  const size_t szU_chunk = (size_t)CR * 2560;
  char* U = (char*)take(szU_pre > szU_chunk ? szU_pre : szU_chunk);
  ushort* h = (ushort*)take((size_t)N * 256 * 2);   // live whole run
  if (off > ws_size) return;

  ushort* xb    = (ushort*)U;
  ushort* x_emb = (ushort*)(U + (size_t)N * 128 * 2);
  ushort* mean1 = (ushort*)(U + (size_t)N * 128 * 2 + (size_t)N * 64 * 2);
  ushort* mean2_c  = (ushort*)U;                        // CR*256 bf16
  ushort* h2_c     = (ushort*)(U + (size_t)CR * 512);   // CR*256 bf16
  ushort* SP_c     = (ushort*)(U + (size_t)CR * 1024);  // CR*512 bf16 (S then P)
  ushort* g_c      = (ushort*)(U + (size_t)CR * 2048);  // CR*256 bf16

  const int MB = (N + 127) / 128;
  dim3 thr(256);

  // CSR build
  zero_i32_k<<<(N + 255) / 256, thr, 0, stream>>>(cnt, N);
  detect_i64_k<<<1, 256, 0, stream>>>(ei, eflag);
  count_edges_k<<<(E + 255) / 256, thr, 0, stream>>>(ei, eflag, cnt, E);
  scan1_k<<<NB1, thr, 0, stream>>>(cnt, rowptr, bsum, N);
  scan2_k<<<1, 128, 0, stream>>>(bsum, boff, NB1);
  scan3_k<<<(N + 255) / 256, thr, 0, stream>>>(cnt, rowptr, cursor, boff, N);
  fill_edges_k<<<(E + 255) / 256, thr, 0, stream>>>(ei, eflag, cursor, eidx, E);

  // input conversion (big) + merged weight conversions
  cvt4_k<<<(N * 128 / 4 + 255) / 256, thr, 0, stream>>>(x, xb, N * 128 / 4);
  {
    CvtJobs jb;
    const float* s_[NJOB] = {gc, Wq, Wp, W1l, W1r, W2l, W2r, Wk, Wv, Wm1, Wm1};
    ushort* d_[NJOB] = {gcb, Wqb, WpT, W1lT, W1rT, W2lT, W2rT, WkT, WvT, Wm1aT, Wm1bT};
    int R_[NJOB] = {512, 256, 128, 64, 64, 256, 256, 256, 256, 256, 256};
    int C_[NJOB] = {256, 256, 64, 256, 256, 256, 256, 256, 256, 256, 256};
    int o_[NJOB] = {0, 0, 0, 0, 0, 0, 0, 0, 0, 0, 256};
    int t_[NJOB] = {0, 0, 1, 1, 1, 1, 1, 1, 1, 1, 1};
    for (int j = 0; j < NJOB; ++j) {
      jb.src[j] = s_[j]; jb.dst[j] = d_[j]; jb.R[j] = R_[j]; jb.C[j] = C_[j];
      jb.off[j] = o_[j]; jb.tr[j] = t_[j];
    }
    wcvt_k<<<dim3(32, NJOB), thr, 0, stream>>>(jb);
  }

  // attention pre: Kmat(bf16), Vmat(f32)->VT, KWqT = Kmat @ Wq^T, sbias
  mfma_gemm_k<128, false, true><<<dim3(4, 2), thr, 0, stream>>>(
      gcb, WkT, 256, nullptr, nullptr, 0, bk, Kmatb, 512, 256);
  mfma_gemm_k<128, false, false><<<dim3(4, 2), thr, 0, stream>>>(
      gcb, WvT, 256, nullptr, nullptr, 0, bv, Vmatf, 512, 256);
  tcvt_k<<<(512 * 256 + 255) / 256, thr, 0, stream>>>(Vmatf, VT, 512, 256, 0);
  mfma_gemm_k<128, false, true><<<dim3(4, 2), thr, 0, stream>>>(
      Kmatb, Wqb, 256, nullptr, nullptr, 0, nullptr, KWqT, 512, 256);
  sbias_k<<<128, thr, 0, stream>>>(bq, Kmatb, sbias);

  // embed: x_emb = relu(xb @ Wp + bp)
  mfma_gemm_k<64, true, true><<<dim3(MB, 1), thr, 0, stream>>>(
      xb, WpT, 128, nullptr, nullptr, 0, bp, x_emb, N, 64);
  // SAGE1
  agg64_k<<<(N + 3) / 4, thr, 0, stream>>>(x_emb, rowptr, eidx, mean1, 0, N);
  mfma_gemm_k<128, true, true><<<dim3(MB, 2), thr, 0, stream>>>(
      mean1, W1lT, 64, x_emb, W1rT, 64, b1l, h, N, 256);

  // chunked SAGE2 + attention + fused MLP/out
  for (int r0 = 0; r0 < N; r0 += CR) {
    const int CRc = (N - r0 < CR) ? (N - r0) : CR;
    const int MBc = (CRc + 127) / 128;
    agg256_k<<<(CRc + 3) / 4, thr, 0, stream>>>(h, rowptr, eidx, mean2_c, r0, CRc);
    mfma_gemm_k<128, false, true><<<dim3(MBc, 2), thr, 0, stream>>>(
        mean2_c, W2lT, 256, h + (size_t)r0 * 256, W2rT, 256, b2l, h2_c, CRc, 256);
    mfma_gemm_k<128, false, true><<<dim3(MBc, 4), thr, 0, stream>>>(
        h2_c, KWqT, 256, nullptr, nullptr, 0, sbias, SP_c, CRc, 512);
    softmax_k<<<(CRc + 3) / 4, thr, 0, stream>>>(SP_c, CRc);
    mfma_gemm_k<128, false, true><<<dim3(MBc, 2), thr, 0, stream>>>(
        SP_c, VT, 512, nullptr, nullptr, 0, nullptr, g_c, CRc, 256);
    mlp_out_k<<<dim3(MBc, 1), thr, 0, stream>>>(
        h2_c, Wm1aT, g_c, Wm1bT, bm1, Wm2, bm2, out + (size_t)r0 * 2, CRc);
  }
}

// Round 9
// 730.891 us; speedup vs baseline: 3.7930x; 1.0493x over previous
//
#include <hip/hip_runtime.h>
#include <cstdint>
#include <cstddef>

// GAAPModelB on MI355X: bf16-MFMA GEMM stack + CSR gather aggregation.
// N=100000, E=800000, IN=128, H=256, G=512. Chunked post-SAGE1 pipeline.
// R9: single-atomic-pass CSR (count stores loc[i]=old; fill is atomic-free),
// x->bf16 conversion fused into count kernel (role-split) to overlap the
// atomic stalls with streaming work.

#define NN 100000
#define NE 800000
#define CR 32768   // chunk rows
#define NB1 98     // ceil(100000/1024) scan blocks
#define CNTB 3125  // ceil(800000/256) count-role blocks

typedef __attribute__((ext_vector_type(8))) short short8;
typedef __attribute__((ext_vector_type(8))) unsigned short ushort8;
typedef __attribute__((ext_vector_type(4))) float f32x4;

__device__ __forceinline__ float b2f(ushort u) {
  union { unsigned u; float f; } v; v.u = ((unsigned)u) << 16; return v.f;
}
__device__ __forceinline__ ushort f2b(float f) {
  union { float f; unsigned u; } v; v.f = f;
  unsigned r = v.u + 0x7FFFu + ((v.u >> 16) & 1u);
  return (ushort)(r >> 16);
}
__device__ __forceinline__ void gl_lds16(const void* g, void* l) {
  __builtin_amdgcn_global_load_lds((const __attribute__((address_space(1))) void*)g,
                                   (__attribute__((address_space(3))) void*)l, 16, 0, 0);
}

// ------------------------------ utility ------------------------------
__global__ void zero_i32_k(int* __restrict__ p, int n) {
  int i = blockIdx.x * 256 + threadIdx.x;
  if (i < n) p[i] = 0;
}

// flag=1 iff edge_index is int64 (odd words of first 256 entries all zero)
__global__ void detect_i64_k(const int* __restrict__ ei, int* __restrict__ flag) {
  __shared__ int ok;
  int t = threadIdx.x;
  if (t == 0) ok = 1;
  __syncthreads();
  if (ei[2 * t + 1] != 0) ok = 0;
  __syncthreads();
  if (t == 0) *flag = ok;
}

// transpose-convert: dst[c*R + r] = bf16(src[(row_off+r)*C + c])
__global__ void tcvt_k(const float* __restrict__ src, ushort* __restrict__ dst,
                       int R, int C, int row_off) {
  int i = blockIdx.x * 256 + threadIdx.x;
  if (i < R * C) {
    int r = i / C, c = i % C;
    dst[(size_t)c * R + r] = f2b(src[(size_t)(row_off + r) * C + c]);
  }
}

// merged small weight conversions: 11 jobs, grid.y = job
#define NJOB 11
struct CvtJobs {
  const float* src[NJOB];
  ushort* dst[NJOB];
  int R[NJOB], C[NJOB], off[NJOB], tr[NJOB];
};
__global__ void wcvt_k(CvtJobs jb) {
  const int j = blockIdx.y;
  const int Cj = jb.C[j], Rj = jb.R[j];
  const int n = Rj * Cj;
  for (int i = blockIdx.x * 256 + threadIdx.x; i < n; i += gridDim.x * 256) {
    if (jb.tr[j]) {
      int r = i / Cj, c = i % Cj;
      jb.dst[j][(size_t)c * Rj + r] = f2b(jb.src[j][(size_t)(jb.off[j] + r) * Cj + c]);
    } else {
      jb.dst[j][i] = f2b(jb.src[j][i]);
    }
  }
}

// ------------------------------ CSR build ------------------------------
// role-split: blocks [0,CNTB) count edges (atomicAdd, store old as loc);
// blocks [CNTB,...) convert x f32->bf16 (streaming, overlaps atomic stalls).
__global__ void count_cvt_k(const int* __restrict__ ei, const int* __restrict__ flag,
                            int* __restrict__ cnt, int* __restrict__ loc,
                            const float* __restrict__ x, ushort* __restrict__ xb,
                            int E, int n4) {
  int b = blockIdx.x;
  if (b < CNTB) {
    int i = b * 256 + threadIdx.x;
    if (i >= E) return;
    const bool i64 = (*flag != 0);
    unsigned d = (unsigned)(i64 ? ei[2 * E + 2 * i] : ei[E + i]);
    int p = -1;
    if (d < NN) p = atomicAdd(&cnt[d], 1);
    loc[i] = p;
  } else {
    int i = (b - CNTB) * 256 + threadIdx.x;
    if (i < n4) {
      float4 v = ((const float4*)x)[i];
      ushort4 o; o.x = f2b(v.x); o.y = f2b(v.y); o.z = f2b(v.z); o.w = f2b(v.w);
      ((ushort4*)xb)[i] = o;
    }
  }
}

__global__ __launch_bounds__(256)
void scan1_k(const int* __restrict__ cnt, int* __restrict__ rowptr,
             int* __restrict__ bsum, int n) {
  __shared__ int ls[256];
  const int b = blockIdx.x, t = threadIdx.x;
  const int base = b * 1024 + t * 4;
  int v[4]; int s = 0;
#pragma unroll
  for (int j = 0; j < 4; ++j) { int i = base + j; v[j] = (i < n) ? cnt[i] : 0; s += v[j]; }
  ls[t] = s; __syncthreads();
  int x = s;
  for (int o = 1; o < 256; o <<= 1) {
    int a = (t >= o) ? ls[t - o] : 0; __syncthreads();
    x += a; ls[t] = x; __syncthreads();
  }
  int run = x - s;
#pragma unroll
  for (int j = 0; j < 4; ++j) { run += v[j]; int i = base + j; if (i < n) rowptr[i + 1] = run; }
  if (t == 255) bsum[b] = x;
}

__global__ void scan2_k(const int* __restrict__ bsum, int* __restrict__ boff, int nb) {
  __shared__ int ls[128];
  int t = threadIdx.x;
  int v = (t < nb) ? bsum[t] : 0;
  ls[t] = v; __syncthreads();
  int x = v;
  for (int o = 1; o < 128; o <<= 1) {
    int a = (t >= o) ? ls[t - o] : 0; __syncthreads();
    x += a; ls[t] = x; __syncthreads();
  }
  if (t < nb) boff[t] = x - v;
}

__global__ void scan3_k(int* __restrict__ rowptr, const int* __restrict__ boff, int n) {
  int i = blockIdx.x * 256 + threadIdx.x;
  if (i == 0) rowptr[0] = 0;
  if (i < n) rowptr[i + 1] += boff[i >> 10];
}

// atomic-free fill: position = rowptr[d] + loc[i]
__global__ void fill_edges_k(const int* __restrict__ ei, const int* __restrict__ flag,
                             const int* __restrict__ rowptr, const int* __restrict__ loc,
                             int* __restrict__ eidx, int E) {
  int i = blockIdx.x * 256 + threadIdx.x;
  if (i >= E) return;
  const bool i64 = (*flag != 0);
  unsigned s = (unsigned)(i64 ? ei[2 * i] : ei[i]);
  unsigned d = (unsigned)(i64 ? ei[2 * E + 2 * i] : ei[E + i]);
  int lc = loc[i];
  if (d < NN && s < NN && lc >= 0) {
    unsigned p = (unsigned)(rowptr[d] + lc);
    if (p < (unsigned)E) eidx[p] = (int)s;
  }
}

// ------------------------------ aggregation ------------------------------
// agg64: wave = 4 edge-slots x 16 dim-lanes (ushort4). Dependent chain /4.
__global__ void agg64_k(const ushort* __restrict__ X, const int* __restrict__ rowptr,
                        const int* __restrict__ eidx, ushort* __restrict__ mean,
                        int r0, int M) {
  int nl = blockIdx.x * 4 + (threadIdx.x >> 6);
  int l = threadIdx.x & 63;
  int e4 = l >> 4;      // edge slot 0..3
  int d4 = l & 15;      // dim group (4 dims)
  if (nl >= M) return;
  int node = r0 + nl;
  int s = rowptr[node], e = rowptr[node + 1];
  float a0 = 0.f, a1 = 0.f, a2 = 0.f, a3 = 0.f;
  for (int i = s + e4; i < e; i += 4) {
    unsigned sc = (unsigned)eidx[i];
    if (sc < NN) {
      ushort4 v = ((const ushort4*)(X + (size_t)sc * 64))[d4];
      a0 += b2f(v.x); a1 += b2f(v.y); a2 += b2f(v.z); a3 += b2f(v.w);
    }
  }
  a0 += __shfl_xor(a0, 16); a0 += __shfl_xor(a0, 32);
  a1 += __shfl_xor(a1, 16); a1 += __shfl_xor(a1, 32);
  a2 += __shfl_xor(a2, 16); a2 += __shfl_xor(a2, 32);
  a3 += __shfl_xor(a3, 16); a3 += __shfl_xor(a3, 32);
  if (e4 == 0) {
    float inv = 1.f / (float)max(e - s, 1);
    ushort4 o; o.x = f2b(a0 * inv); o.y = f2b(a1 * inv); o.z = f2b(a2 * inv); o.w = f2b(a3 * inv);
    ((ushort4*)(mean + (size_t)nl * 64))[d4] = o;
  }
}

// agg256: wave = 2 edge-slots x 32 lanes x ushort8 (512B row), unroll-2.
__global__ void agg256_k(const ushort* __restrict__ X, const int* __restrict__ rowptr,
                         const int* __restrict__ eidx, ushort* __restrict__ mean,
                         int r0, int M) {
  int nl = blockIdx.x * 4 + (threadIdx.x >> 6);
  int l = threadIdx.x & 63;
  int g = l >> 5;       // edge slot 0..1
  int d = l & 31;       // 8-dim group
  if (nl >= M) return;
  int node = r0 + nl;
  int s = rowptr[node], e = rowptr[node + 1];
  float a[8], c[8];
#pragma unroll
  for (int k = 0; k < 8; ++k) { a[k] = 0.f; c[k] = 0.f; }
  for (int i = s + g; i < e; i += 4) {
    unsigned s0 = (unsigned)eidx[i];
    if (s0 < NN) {
      ushort8 v = *(const ushort8*)(X + (size_t)s0 * 256 + d * 8);
#pragma unroll
      for (int k = 0; k < 8; ++k) a[k] += b2f((ushort)v[k]);
    }
    int i2 = i + 2;
    if (i2 < e) {
      unsigned s1 = (unsigned)eidx[i2];
      if (s1 < NN) {
        ushort8 v = *(const ushort8*)(X + (size_t)s1 * 256 + d * 8);
#pragma unroll
        for (int k = 0; k < 8; ++k) c[k] += b2f((ushort)v[k]);
      }
    }
  }
  float inv = 1.f / (float)max(e - s, 1);
  ushort8 o;
#pragma unroll
  for (int k = 0; k < 8; ++k) {
    float t = a[k] + c[k];
    t += __shfl_xor(t, 32);
    o[k] = (short)f2b(t * inv);
  }
  if (g == 0) *(ushort8*)(mean + (size_t)nl * 256 + d * 8) = o;
}

// ------------------------------ bf16 MFMA GEMM ------------------------------
// C[M,Nc] = act(A1@B1 + A2@B2 + bias): A [M,K] bf16 rm, BT [Nc,K] bf16 rm.
// BM=128, BN in {64,128}, BK=64, 256 thr = 4 waves (2x2), 16x16x32 MFMA.
// XOR slot swizzle (kb ^= row&7), global_load_lds w/ pre-swizzled source.
template<int BN, bool RELU, bool OUTBF>
__global__ __launch_bounds__(256)
void mfma_gemm_k(const ushort* __restrict__ A1, const ushort* __restrict__ BT1, int K1,
                 const ushort* __restrict__ A2, const ushort* __restrict__ BT2, int K2,
                 const float* __restrict__ bias, void* __restrict__ Cv, int M, int Nc) {
  constexpr int NR = BN / 32;
  constexpr int WTN = BN / 2;
  __shared__ __align__(16) char As[128 * 64 * 2];
  __shared__ __align__(16) char Bs[BN * 64 * 2];
  const int tid = threadIdx.x;
  const int l = tid & 63;
  const int w = tid >> 6;
  const int wm = w >> 1, wn = w & 1;
  const int bm = blockIdx.x * 128, bn = blockIdx.y * BN;
  const int r15 = l & 15, g4 = l >> 4;

  f32x4 acc[4][NR];
  const f32x4 zz = {0.f, 0.f, 0.f, 0.f};
#pragma unroll
  for (int m = 0; m < 4; ++m)
#pragma unroll
    for (int n = 0; n < NR; ++n) acc[m][n] = zz;

  for (int pass = 0; pass < 2; ++pass) {
    const ushort* A = pass ? A2 : A1;
    const ushort* BT = pass ? BT2 : BT1;
    const int K = pass ? K2 : K1;
    if (!A) break;
    for (int k0 = 0; k0 < K; k0 += 64) {
#pragma unroll
      for (int p = 0; p < 4; ++p) {
        int idx = tid + p * 256;
        int row = idx >> 3, slot = idx & 7;
        int kb = slot ^ (row & 7);
        int grow = bm + row; if (grow >= M) grow = M - 1;
        gl_lds16(A + (size_t)grow * K + k0 + kb * 8, As + idx * 16);
      }
#pragma unroll
      for (int p = 0; p < BN / 32; ++p) {
        int idx = tid + p * 256;
        int row = idx >> 3, slot = idx & 7;
        int kb = slot ^ (row & 7);
        gl_lds16(BT + (size_t)(bn + row) * K + k0 + kb * 8, Bs + idx * 16);
      }
      __syncthreads();
#pragma unroll
      for (int s = 0; s < 2; ++s) {
        short8 a[4], b[NR];
        const int slotx = (((s * 4 + g4) ^ (r15 & 7)) << 4);
#pragma unroll
        for (int m = 0; m < 4; ++m) {
          int row = wm * 64 + m * 16 + r15;
          a[m] = *(const short8*)(As + row * 128 + slotx);
        }
#pragma unroll
        for (int n = 0; n < NR; ++n) {
          int row = wn * WTN + n * 16 + r15;
          b[n] = *(const short8*)(Bs + row * 128 + slotx);
        }
#pragma unroll
        for (int m = 0; m < 4; ++m)
#pragma unroll
          for (int n = 0; n < NR; ++n)
            acc[m][n] = __builtin_amdgcn_mfma_f32_16x16x32_bf16(a[m], b[n], acc[m][n], 0, 0, 0);
      }
      __syncthreads();
    }
  }
#pragma unroll
  for (int n = 0; n < NR; ++n) {
    int col = bn + wn * WTN + n * 16 + r15;
    float bv = bias ? bias[col] : 0.f;
#pragma unroll
    for (int m = 0; m < 4; ++m) {
#pragma unroll
      for (int j = 0; j < 4; ++j) {
        int row = bm + wm * 64 + m * 16 + g4 * 4 + j;
        if (row < M) {
          float v = acc[m][n][j] + bv;
          if (RELU) v = fmaxf(v, 0.f);
          if (OUTBF) ((ushort*)Cv)[(size_t)row * Nc + col] = f2b(v);
          else       ((float*)Cv)[(size_t)row * Nc + col] = v;
        }
      }
    }
  }
}

// ------------------------------ fused MLP + output head ------------------------------
__global__ __launch_bounds__(256)
void mlp_out_k(const ushort* __restrict__ A1, const ushort* __restrict__ BT1,
               const ushort* __restrict__ A2, const ushort* __restrict__ BT2,
               const float* __restrict__ bias, const float* __restrict__ Wm2,
               const float* __restrict__ bm2, float* __restrict__ out, int M) {
  constexpr int NR = 8;      // 256/32
  constexpr int WTN = 128;
  __shared__ __align__(16) char As[128 * 64 * 2];
  __shared__ __align__(16) char Bs[256 * 64 * 2];
  const int tid = threadIdx.x;
  const int l = tid & 63;
  const int w = tid >> 6;
  const int wm = w >> 1, wn = w & 1;
  const int bm = blockIdx.x * 128;
  const int r15 = l & 15, g4 = l >> 4;

  f32x4 acc[4][NR];
  const f32x4 zz = {0.f, 0.f, 0.f, 0.f};
#pragma unroll
  for (int m = 0; m < 4; ++m)
#pragma unroll
    for (int n = 0; n < NR; ++n) acc[m][n] = zz;

  for (int pass = 0; pass < 2; ++pass) {
    const ushort* A = pass ? A2 : A1;
    const ushort* BT = pass ? BT2 : BT1;
    for (int k0 = 0; k0 < 256; k0 += 64) {
#pragma unroll
      for (int p = 0; p < 4; ++p) {
        int idx = tid + p * 256;
        int row = idx >> 3, slot = idx & 7;
        int kb = slot ^ (row & 7);
        int grow = bm + row; if (grow >= M) grow = M - 1;
        gl_lds16(A + (size_t)grow * 256 + k0 + kb * 8, As + idx * 16);
      }
#pragma unroll
      for (int p = 0; p < 8; ++p) {
        int idx = tid + p * 256;
        int row = idx >> 3, slot = idx & 7;
        int kb = slot ^ (row & 7);
        gl_lds16(BT + (size_t)row * 256 + k0 + kb * 8, Bs + idx * 16);
      }
      __syncthreads();
#pragma unroll
      for (int s = 0; s < 2; ++s) {
        short8 a[4], b[NR];
        const int slotx = (((s * 4 + g4) ^ (r15 & 7)) << 4);
#pragma unroll
        for (int m = 0; m < 4; ++m) {
          int row = wm * 64 + m * 16 + r15;
          a[m] = *(const short8*)(As + row * 128 + slotx);
        }
#pragma unroll
        for (int n = 0; n < NR; ++n) {
          int row = wn * WTN + n * 16 + r15;
          b[n] = *(const short8*)(Bs + row * 128 + slotx);
        }
#pragma unroll
        for (int m = 0; m < 4; ++m)
#pragma unroll
          for (int n = 0; n < NR; ++n)
            acc[m][n] = __builtin_amdgcn_mfma_f32_16x16x32_bf16(a[m], b[n], acc[m][n], 0, 0, 0);
      }
      __syncthreads();
    }
  }
  float bv[NR], w20[NR], w21[NR];
#pragma unroll
  for (int n = 0; n < NR; ++n) {
    int col = wn * WTN + n * 16 + r15;
    bv[n] = bias[col];
    w20[n] = Wm2[col * 2 + 0];
    w21[n] = Wm2[col * 2 + 1];
  }
  float* red = (float*)As;   // 2KB, LDS free after last barrier
#pragma unroll
  for (int m = 0; m < 4; ++m) {
#pragma unroll
    for (int j = 0; j < 4; ++j) {
      float p0 = 0.f, p1 = 0.f;
#pragma unroll
      for (int n = 0; n < NR; ++n) {
        float v = fmaxf(acc[m][n][j] + bv[n], 0.f);
        p0 += v * w20[n];
        p1 += v * w21[n];
      }
      p0 += __shfl_xor(p0, 1); p1 += __shfl_xor(p1, 1);
      p0 += __shfl_xor(p0, 2); p1 += __shfl_xor(p1, 2);
      p0 += __shfl_xor(p0, 4); p1 += __shfl_xor(p1, 4);
      p0 += __shfl_xor(p0, 8); p1 += __shfl_xor(p1, 8);
      if (r15 == 0) {
        int rl = wm * 64 + m * 16 + g4 * 4 + j;
        red[wn * 256 + rl * 2 + 0] = p0;
        red[wn * 256 + rl * 2 + 1] = p1;
      }
    }
  }
  __syncthreads();
  int rl = tid >> 1, j = tid & 1;
  int row = bm + rl;
  if (row < M)
    out[(size_t)row * 2 + j] = red[rl * 2 + j] + red[256 + rl * 2 + j] + bm2[j];
}

// ------------------------------ sbias[g] = dot(bq, Kmat[g]) ------------------------------
__global__ void sbias_k(const float* __restrict__ bq, const ushort* __restrict__ Kmat,
                        float* __restrict__ sbias) {
  int g = blockIdx.x * 4 + (threadIdx.x >> 6);
  int lane = threadIdx.x & 63;
  if (g >= 512) return;
  ushort4 kv = ((const ushort4*)(Kmat + (size_t)g * 256))[lane];
  float4 bv = ((const float4*)bq)[lane];
  float p = b2f(kv.x) * bv.x + b2f(kv.y) * bv.y + b2f(kv.z) * bv.z + b2f(kv.w) * bv.w;
  for (int off = 32; off; off >>= 1) p += __shfl_xor(p, off);
  if (lane == 0) sbias[g] = p;
}

// ------------------------------ softmax in place (bf16 logits -> bf16 P), scale 1/16 ------------------------------
__global__ void softmax_k(ushort* __restrict__ SP, int M) {
  int row = blockIdx.x * 4 + (threadIdx.x >> 6);
  int lane = threadIdx.x & 63;
  if (row >= M) return;
  ushort4* p = (ushort4*)(SP + (size_t)row * 512);
  ushort4 ua = p[lane];
  ushort4 ub = p[lane + 64];
  const float sc = 0.0625f;
  float ax = b2f(ua.x) * sc, ay = b2f(ua.y) * sc, az = b2f(ua.z) * sc, aw = b2f(ua.w) * sc;
  float bx = b2f(ub.x) * sc, by = b2f(ub.y) * sc, bz = b2f(ub.z) * sc, bw = b2f(ub.w) * sc;
  float m = fmaxf(fmaxf(fmaxf(ax, ay), fmaxf(az, aw)),
                  fmaxf(fmaxf(bx, by), fmaxf(bz, bw)));
  for (int off = 32; off; off >>= 1) m = fmaxf(m, __shfl_xor(m, off));
  ax = expf(ax - m); ay = expf(ay - m); az = expf(az - m); aw = expf(aw - m);
  bx = expf(bx - m); by = expf(by - m); bz = expf(bz - m); bw = expf(bw - m);
  float s = ax + ay + az + aw + bx + by + bz + bw;
  for (int off = 32; off; off >>= 1) s += __shfl_xor(s, off);
  float inv = 1.f / s;
  ushort4 oa, ob;
  oa.x = f2b(ax * inv); oa.y = f2b(ay * inv); oa.z = f2b(az * inv); oa.w = f2b(aw * inv);
  ob.x = f2b(bx * inv); ob.y = f2b(by * inv); ob.z = f2b(bz * inv); ob.w = f2b(bw * inv);
  p[lane] = oa;
  p[lane + 64] = ob;
}

// ------------------------------ launch ------------------------------
extern "C" void kernel_launch(void* const* d_in, const int* in_sizes, int n_in,
                              void* d_out, int out_size, void* d_ws, size_t ws_size,
                              hipStream_t stream) {
  const int N = NN, E = NE;
  const float* x   = (const float*)d_in[0];
  const int*   ei  = (const int*)d_in[1];
  const float* gc  = (const float*)d_in[2];
  const float* Wp  = (const float*)d_in[3];
  const float* bp  = (const float*)d_in[4];
  const float* W1l = (const float*)d_in[5];
  const float* b1l = (const float*)d_in[6];
  const float* W1r = (const float*)d_in[7];
  const float* W2l = (const float*)d_in[8];
  const float* b2l = (const float*)d_in[9];
  const float* W2r = (const float*)d_in[10];
  const float* Wq  = (const float*)d_in[11];
  const float* bq  = (const float*)d_in[12];
  const float* Wk  = (const float*)d_in[13];
  const float* bk  = (const float*)d_in[14];
  const float* Wv  = (const float*)d_in[15];
  const float* bv  = (const float*)d_in[16];
  const float* Wm1 = (const float*)d_in[17];
  const float* bm1 = (const float*)d_in[18];
  const float* Wm2 = (const float*)d_in[19];
  const float* bm2 = (const float*)d_in[20];
  float* out = (float*)d_out;

  char* base = (char*)d_ws;
  size_t off = 0;
  auto take = [&](size_t bytes) -> void* {
    void* r = base + off;
    off += (bytes + 255) & ~(size_t)255;
    return r;
  };
  // CSR + misc
  int* cnt    = (int*)take((size_t)N * 4);
  int* rowptr = (int*)take((size_t)(N + 1) * 4);
  int* loc    = (int*)take((size_t)E * 4);
  int* eidx   = (int*)take((size_t)E * 4);
  int* eflag  = (int*)take(256);
  int* bsum   = (int*)take(NB1 * 4);
  int* boff   = (int*)take(NB1 * 4);
  // bf16 weights
  ushort* WpT   = (ushort*)take((size_t)64 * 128 * 2);
  ushort* W1lT  = (ushort*)take((size_t)256 * 64 * 2);
  ushort* W1rT  = (ushort*)take((size_t)256 * 64 * 2);
  ushort* W2lT  = (ushort*)take((size_t)256 * 256 * 2);
  ushort* W2rT  = (ushort*)take((size_t)256 * 256 * 2);
  ushort* WkT   = (ushort*)take((size_t)256 * 256 * 2);
  ushort* WvT   = (ushort*)take((size_t)256 * 256 * 2);
  ushort* Wqb   = (ushort*)take((size_t)256 * 256 * 2);
  ushort* Wm1aT = (ushort*)take((size_t)256 * 256 * 2);
  ushort* Wm1bT = (ushort*)take((size_t)256 * 256 * 2);
  // attention small
  ushort* gcb   = (ushort*)take((size_t)512 * 256 * 2);
  ushort* Kmatb = (ushort*)take((size_t)512 * 256 * 2);
  float*  Vmatf = (float*)take((size_t)512 * 256 * 4);
  ushort* VT    = (ushort*)take((size_t)256 * 512 * 2);
  ushort* KWqT  = (ushort*)take((size_t)512 * 256 * 2);
  float*  sbias = (float*)take((size_t)512 * 4);
  // region U: pre-loop {xb, x_emb, mean1} then chunk buffers (2560B/row)
  const size_t szU_pre = (size_t)N * 128 * 2 + (size_t)N * 64 * 2 + (size_t)N * 64 * 2;
  const size_t szU_chunk = (size_t)CR * 2560;
  char* U = (char*)take(szU_pre > szU_chunk ? szU_pre : szU_chunk);
  ushort* h = (ushort*)take((size_t)N * 256 * 2);   // live whole run
  if (off > ws_size) return;

  ushort* xb    = (ushort*)U;
  ushort* x_emb = (ushort*)(U + (size_t)N * 128 * 2);
  ushort* mean1 = (ushort*)(U + (size_t)N * 128 * 2 + (size_t)N * 64 * 2);
  ushort* mean2_c  = (ushort*)U;                        // CR*256 bf16
  ushort* h2_c     = (ushort*)(U + (size_t)CR * 512);   // CR*256 bf16
  ushort* SP_c     = (ushort*)(U + (size_t)CR * 1024);  // CR*512 bf16 (S then P)
  ushort* g_c      = (ushort*)(U + (size_t)CR * 2048);  // CR*256 bf16

  const int MB = (N + 127) / 128;
  const int n4 = N * 128 / 4;
  dim3 thr(256);

  // CSR build (single atomic pass; cvt of x fused into count via role-split)
  zero_i32_k<<<(N + 255) / 256, thr, 0, stream>>>(cnt, N);
  detect_i64_k<<<1, 256, 0, stream>>>(ei, eflag);
  count_cvt_k<<<CNTB + (n4 + 255) / 256, thr, 0, stream>>>(ei, eflag, cnt, loc, x, xb, E, n4);
  scan1_k<<<NB1, thr, 0, stream>>>(cnt, rowptr, bsum, N);
  scan2_k<<<1, 128, 0, stream>>>(bsum, boff, NB1);
  scan3_k<<<(N + 255) / 256, thr, 0, stream>>>(rowptr, boff, N);
  fill_edges_k<<<(E + 255) / 256, thr, 0, stream>>>(ei, eflag, rowptr, loc, eidx, E);

  // merged weight conversions
  {
    CvtJobs jb;
    const float* s_[NJOB] = {gc, Wq, Wp, W1l, W1r, W2l, W2r, Wk, Wv, Wm1, Wm1};
    ushort* d_[NJOB] = {gcb, Wqb, WpT, W1lT, W1rT, W2lT, W2rT, WkT, WvT, Wm1aT, Wm1bT};
    int R_[NJOB] = {512, 256, 128, 64, 64, 256, 256, 256, 256, 256, 256};
    int C_[NJOB] = {256, 256, 64, 256, 256, 256, 256, 256, 256, 256, 256};
    int o_[NJOB] = {0, 0, 0, 0, 0, 0, 0, 0, 0, 0, 256};
    int t_[NJOB] = {0, 0, 1, 1, 1, 1, 1, 1, 1, 1, 1};
    for (int j = 0; j < NJOB; ++j) {
      jb.src[j] = s_[j]; jb.dst[j] = d_[j]; jb.R[j] = R_[j]; jb.C[j] = C_[j];
      jb.off[j] = o_[j]; jb.tr[j] = t_[j];
    }
    wcvt_k<<<dim3(32, NJOB), thr, 0, stream>>>(jb);
  }

  // attention pre: Kmat(bf16), Vmat(f32)->VT, KWqT = Kmat @ Wq^T, sbias
  mfma_gemm_k<128, false, true><<<dim3(4, 2), thr, 0, stream>>>(
      gcb, WkT, 256, nullptr, nullptr, 0, bk, Kmatb, 512, 256);
  mfma_gemm_k<128, false, false><<<dim3(4, 2), thr, 0, stream>>>(
      gcb, WvT, 256, nullptr, nullptr, 0, bv, Vmatf, 512, 256);
  tcvt_k<<<(512 * 256 + 255) / 256, thr, 0, stream>>>(Vmatf, VT, 512, 256, 0);
  mfma_gemm_k<128, false, true><<<dim3(4, 2), thr, 0, stream>>>(
      Kmatb, Wqb, 256, nullptr, nullptr, 0, nullptr, KWqT, 512, 256);
  sbias_k<<<128, thr, 0, stream>>>(bq, Kmatb, sbias);

  // embed: x_emb = relu(xb @ Wp + bp)
  mfma_gemm_k<64, true, true><<<dim3(MB, 1), thr, 0, stream>>>(
      xb, WpT, 128, nullptr, nullptr, 0, bp, x_emb, N, 64);
  // SAGE1
  agg64_k<<<(N + 3) / 4, thr, 0, stream>>>(x_emb, rowptr, eidx, mean1, 0, N);
  mfma_gemm_k<128, true, true><<<dim3(MB, 2), thr, 0, stream>>>(
      mean1, W1lT, 64, x_emb, W1rT, 64, b1l, h, N, 256);

  // chunked SAGE2 + attention + fused MLP/out
  for (int r0 = 0; r0 < N; r0 += CR) {
    const int CRc = (N - r0 < CR) ? (N - r0) : CR;
    const int MBc = (CRc + 127) / 128;
    agg256_k<<<(CRc + 3) / 4, thr, 0, stream>>>(h, rowptr, eidx, mean2_c, r0, CRc);
    mfma_gemm_k<128, false, true><<<dim3(MBc, 2), thr, 0, stream>>>(
        mean2_c, W2lT, 256, h + (size_t)r0 * 256, W2rT, 256, b2l, h2_c, CRc, 256);
    mfma_gemm_k<128, false, true><<<dim3(MBc, 4), thr, 0, stream>>>(
        h2_c, KWqT, 256, nullptr, nullptr, 0, sbias, SP_c, CRc, 512);
    softmax_k<<<(CRc + 3) / 4, thr, 0, stream>>>(SP_c, CRc);
    mfma_gemm_k<128, false, true><<<dim3(MBc, 2), thr, 0, stream>>>(
        SP_c, VT, 512, nullptr, nullptr, 0, nullptr, g_c, CRc, 256);
    mlp_out_k<<<dim3(MBc, 1), thr, 0, stream>>>(
        h2_c, Wm1aT, g_c, Wm1bT, bm1, Wm2, bm2, out + (size_t)r0 * 2, CRc);
  }
}

// Round 10
// 598.688 us; speedup vs baseline: 4.6306x; 1.2208x over previous
//
#include <hip/hip_runtime.h>
#include <cstdint>
#include <cstddef>

// GAAPModelB on MI355X: bf16-MFMA GEMM stack + CSR gather aggregation.
// N=100000, E=800000, IN=128, H=256, G=512. Chunked post-SAGE1 pipeline.
// R10: LDS-staged GEMM epilogue -> coalesced ushort8 C-stores (kills the
// 3x write amplification from scattered 2B bf16 stores seen in R9 PMC).

#define NN 100000
#define NE 800000
#define CR 32768   // chunk rows
#define NB1 98     // ceil(100000/1024) scan blocks
#define CNTB 3125  // ceil(800000/256) count-role blocks

typedef __attribute__((ext_vector_type(8))) short short8;
typedef __attribute__((ext_vector_type(8))) unsigned short ushort8;
typedef __attribute__((ext_vector_type(4))) float f32x4;

__device__ __forceinline__ float b2f(ushort u) {
  union { unsigned u; float f; } v; v.u = ((unsigned)u) << 16; return v.f;
}
__device__ __forceinline__ ushort f2b(float f) {
  union { float f; unsigned u; } v; v.f = f;
  unsigned r = v.u + 0x7FFFu + ((v.u >> 16) & 1u);
  return (ushort)(r >> 16);
}
__device__ __forceinline__ void gl_lds16(const void* g, void* l) {
  __builtin_amdgcn_global_load_lds((const __attribute__((address_space(1))) void*)g,
                                   (__attribute__((address_space(3))) void*)l, 16, 0, 0);
}

// ------------------------------ utility ------------------------------
__global__ void zero_i32_k(int* __restrict__ p, int n) {
  int i = blockIdx.x * 256 + threadIdx.x;
  if (i < n) p[i] = 0;
}

// flag=1 iff edge_index is int64 (odd words of first 256 entries all zero)
__global__ void detect_i64_k(const int* __restrict__ ei, int* __restrict__ flag) {
  __shared__ int ok;
  int t = threadIdx.x;
  if (t == 0) ok = 1;
  __syncthreads();
  if (ei[2 * t + 1] != 0) ok = 0;
  __syncthreads();
  if (t == 0) *flag = ok;
}

// transpose-convert: dst[c*R + r] = bf16(src[(row_off+r)*C + c])
__global__ void tcvt_k(const float* __restrict__ src, ushort* __restrict__ dst,
                       int R, int C, int row_off) {
  int i = blockIdx.x * 256 + threadIdx.x;
  if (i < R * C) {
    int r = i / C, c = i % C;
    dst[(size_t)c * R + r] = f2b(src[(size_t)(row_off + r) * C + c]);
  }
}

// merged small weight conversions: 11 jobs, grid.y = job
#define NJOB 11
struct CvtJobs {
  const float* src[NJOB];
  ushort* dst[NJOB];
  int R[NJOB], C[NJOB], off[NJOB], tr[NJOB];
};
__global__ void wcvt_k(CvtJobs jb) {
  const int j = blockIdx.y;
  const int Cj = jb.C[j], Rj = jb.R[j];
  const int n = Rj * Cj;
  for (int i = blockIdx.x * 256 + threadIdx.x; i < n; i += gridDim.x * 256) {
    if (jb.tr[j]) {
      int r = i / Cj, c = i % Cj;
      jb.dst[j][(size_t)c * Rj + r] = f2b(jb.src[j][(size_t)(jb.off[j] + r) * Cj + c]);
    } else {
      jb.dst[j][i] = f2b(jb.src[j][i]);
    }
  }
}

// ------------------------------ CSR build ------------------------------
// role-split: blocks [0,CNTB) count edges (atomicAdd, store old as loc);
// blocks [CNTB,...) convert x f32->bf16 (streaming, overlaps atomic stalls).
__global__ void count_cvt_k(const int* __restrict__ ei, const int* __restrict__ flag,
                            int* __restrict__ cnt, int* __restrict__ loc,
                            const float* __restrict__ x, ushort* __restrict__ xb,
                            int E, int n4) {
  int b = blockIdx.x;
  if (b < CNTB) {
    int i = b * 256 + threadIdx.x;
    if (i >= E) return;
    const bool i64 = (*flag != 0);
    unsigned d = (unsigned)(i64 ? ei[2 * E + 2 * i] : ei[E + i]);
    int p = -1;
    if (d < NN) p = atomicAdd(&cnt[d], 1);
    loc[i] = p;
  } else {
    int i = (b - CNTB) * 256 + threadIdx.x;
    if (i < n4) {
      float4 v = ((const float4*)x)[i];
      ushort4 o; o.x = f2b(v.x); o.y = f2b(v.y); o.z = f2b(v.z); o.w = f2b(v.w);
      ((ushort4*)xb)[i] = o;
    }
  }
}

__global__ __launch_bounds__(256)
void scan1_k(const int* __restrict__ cnt, int* __restrict__ rowptr,
             int* __restrict__ bsum, int n) {
  __shared__ int ls[256];
  const int b = blockIdx.x, t = threadIdx.x;
  const int base = b * 1024 + t * 4;
  int v[4]; int s = 0;
#pragma unroll
  for (int j = 0; j < 4; ++j) { int i = base + j; v[j] = (i < n) ? cnt[i] : 0; s += v[j]; }
  ls[t] = s; __syncthreads();
  int x = s;
  for (int o = 1; o < 256; o <<= 1) {
    int a = (t >= o) ? ls[t - o] : 0; __syncthreads();
    x += a; ls[t] = x; __syncthreads();
  }
  int run = x - s;
#pragma unroll
  for (int j = 0; j < 4; ++j) { run += v[j]; int i = base + j; if (i < n) rowptr[i + 1] = run; }
  if (t == 255) bsum[b] = x;
}

__global__ void scan2_k(const int* __restrict__ bsum, int* __restrict__ boff, int nb) {
  __shared__ int ls[128];
  int t = threadIdx.x;
  int v = (t < nb) ? bsum[t] : 0;
  ls[t] = v; __syncthreads();
  int x = v;
  for (int o = 1; o < 128; o <<= 1) {
    int a = (t >= o) ? ls[t - o] : 0; __syncthreads();
    x += a; ls[t] = x; __syncthreads();
  }
  if (t < nb) boff[t] = x - v;
}

__global__ void scan3_k(int* __restrict__ rowptr, const int* __restrict__ boff, int n) {
  int i = blockIdx.x * 256 + threadIdx.x;
  if (i == 0) rowptr[0] = 0;
  if (i < n) rowptr[i + 1] += boff[i >> 10];
}

// atomic-free fill: position = rowptr[d] + loc[i]
__global__ void fill_edges_k(const int* __restrict__ ei, const int* __restrict__ flag,
                             const int* __restrict__ rowptr, const int* __restrict__ loc,
                             int* __restrict__ eidx, int E) {
  int i = blockIdx.x * 256 + threadIdx.x;
  if (i >= E) return;
  const bool i64 = (*flag != 0);
  unsigned s = (unsigned)(i64 ? ei[2 * i] : ei[i]);
  unsigned d = (unsigned)(i64 ? ei[2 * E + 2 * i] : ei[E + i]);
  int lc = loc[i];
  if (d < NN && s < NN && lc >= 0) {
    unsigned p = (unsigned)(rowptr[d] + lc);
    if (p < (unsigned)E) eidx[p] = (int)s;
  }
}

// ------------------------------ aggregation ------------------------------
// agg64: wave = 4 edge-slots x 16 dim-lanes (ushort4). Dependent chain /4.
__global__ void agg64_k(const ushort* __restrict__ X, const int* __restrict__ rowptr,
                        const int* __restrict__ eidx, ushort* __restrict__ mean,
                        int r0, int M) {
  int nl = blockIdx.x * 4 + (threadIdx.x >> 6);
  int l = threadIdx.x & 63;
  int e4 = l >> 4;      // edge slot 0..3
  int d4 = l & 15;      // dim group (4 dims)
  if (nl >= M) return;
  int node = r0 + nl;
  int s = rowptr[node], e = rowptr[node + 1];
  float a0 = 0.f, a1 = 0.f, a2 = 0.f, a3 = 0.f;
  for (int i = s + e4; i < e; i += 4) {
    unsigned sc = (unsigned)eidx[i];
    if (sc < NN) {
      ushort4 v = ((const ushort4*)(X + (size_t)sc * 64))[d4];
      a0 += b2f(v.x); a1 += b2f(v.y); a2 += b2f(v.z); a3 += b2f(v.w);
    }
  }
  a0 += __shfl_xor(a0, 16); a0 += __shfl_xor(a0, 32);
  a1 += __shfl_xor(a1, 16); a1 += __shfl_xor(a1, 32);
  a2 += __shfl_xor(a2, 16); a2 += __shfl_xor(a2, 32);
  a3 += __shfl_xor(a3, 16); a3 += __shfl_xor(a3, 32);
  if (e4 == 0) {
    float inv = 1.f / (float)max(e - s, 1);
    ushort4 o; o.x = f2b(a0 * inv); o.y = f2b(a1 * inv); o.z = f2b(a2 * inv); o.w = f2b(a3 * inv);
    ((ushort4*)(mean + (size_t)nl * 64))[d4] = o;
  }
}

// agg256: wave = 2 edge-slots x 32 lanes x ushort8 (512B row), unroll-2.
__global__ void agg256_k(const ushort* __restrict__ X, const int* __restrict__ rowptr,
                         const int* __restrict__ eidx, ushort* __restrict__ mean,
                         int r0, int M) {
  int nl = blockIdx.x * 4 + (threadIdx.x >> 6);
  int l = threadIdx.x & 63;
  int g = l >> 5;       // edge slot 0..1
  int d = l & 31;       // 8-dim group
  if (nl >= M) return;
  int node = r0 + nl;
  int s = rowptr[node], e = rowptr[node + 1];
  float a[8], c[8];
#pragma unroll
  for (int k = 0; k < 8; ++k) { a[k] = 0.f; c[k] = 0.f; }
  for (int i = s + g; i < e; i += 4) {
    unsigned s0 = (unsigned)eidx[i];
    if (s0 < NN) {
      ushort8 v = *(const ushort8*)(X + (size_t)s0 * 256 + d * 8);
#pragma unroll
      for (int k = 0; k < 8; ++k) a[k] += b2f((ushort)v[k]);
    }
    int i2 = i + 2;
    if (i2 < e) {
      unsigned s1 = (unsigned)eidx[i2];
      if (s1 < NN) {
        ushort8 v = *(const ushort8*)(X + (size_t)s1 * 256 + d * 8);
#pragma unroll
        for (int k = 0; k < 8; ++k) c[k] += b2f((ushort)v[k]);
      }
    }
  }
  float inv = 1.f / (float)max(e - s, 1);
  ushort8 o;
#pragma unroll
  for (int k = 0; k < 8; ++k) {
    float t = a[k] + c[k];
    t += __shfl_xor(t, 32);
    o[k] = (short)f2b(t * inv);
  }
  if (g == 0) *(ushort8*)(mean + (size_t)nl * 256 + d * 8) = o;
}

// ------------------------------ bf16 MFMA GEMM ------------------------------
// C[M,Nc] = act(A1@B1 + A2@B2 + bias): A [M,K] bf16 rm, BT [Nc,K] bf16 rm.
// BM=128, BN in {64,128}, BK=64, 256 thr = 4 waves (2x2), 16x16x32 MFMA.
// XOR slot swizzle (kb ^= row&7), global_load_lds w/ pre-swizzled source.
// bf16 epilogue goes through padded LDS tile -> ushort8 coalesced stores.
template<int BN, bool RELU, bool OUTBF>
__global__ __launch_bounds__(256)
void mfma_gemm_k(const ushort* __restrict__ A1, const ushort* __restrict__ BT1, int K1,
                 const ushort* __restrict__ A2, const ushort* __restrict__ BT2, int K2,
                 const float* __restrict__ bias, void* __restrict__ Cv, int M, int Nc) {
  constexpr int NR = BN / 32;
  constexpr int WTN = BN / 2;
  constexpr int CP = BN + 8;                       // padded C-tile row (ushorts)
  constexpr int SZ_STAGE = 128 * 64 * 2 + BN * 64 * 2;
  constexpr int SZ_EPI = 128 * CP * 2;
  __shared__ __align__(16) char smem[SZ_STAGE > SZ_EPI ? SZ_STAGE : SZ_EPI];
  char* As = smem;
  char* Bs = smem + 128 * 64 * 2;
  const int tid = threadIdx.x;
  const int l = tid & 63;
  const int w = tid >> 6;
  const int wm = w >> 1, wn = w & 1;
  const int bm = blockIdx.x * 128, bn = blockIdx.y * BN;
  const int r15 = l & 15, g4 = l >> 4;

  f32x4 acc[4][NR];
  const f32x4 zz = {0.f, 0.f, 0.f, 0.f};
#pragma unroll
  for (int m = 0; m < 4; ++m)
#pragma unroll
    for (int n = 0; n < NR; ++n) acc[m][n] = zz;

  for (int pass = 0; pass < 2; ++pass) {
    const ushort* A = pass ? A2 : A1;
    const ushort* BT = pass ? BT2 : BT1;
    const int K = pass ? K2 : K1;
    if (!A) break;
    for (int k0 = 0; k0 < K; k0 += 64) {
#pragma unroll
      for (int p = 0; p < 4; ++p) {
        int idx = tid + p * 256;
        int row = idx >> 3, slot = idx & 7;
        int kb = slot ^ (row & 7);
        int grow = bm + row; if (grow >= M) grow = M - 1;
        gl_lds16(A + (size_t)grow * K + k0 + kb * 8, As + idx * 16);
      }
#pragma unroll
      for (int p = 0; p < BN / 32; ++p) {
        int idx = tid + p * 256;
        int row = idx >> 3, slot = idx & 7;
        int kb = slot ^ (row & 7);
        gl_lds16(BT + (size_t)(bn + row) * K + k0 + kb * 8, Bs + idx * 16);
      }
      __syncthreads();
#pragma unroll
      for (int s = 0; s < 2; ++s) {
        short8 a[4], b[NR];
        const int slotx = (((s * 4 + g4) ^ (r15 & 7)) << 4);
#pragma unroll
        for (int m = 0; m < 4; ++m) {
          int row = wm * 64 + m * 16 + r15;
          a[m] = *(const short8*)(As + row * 128 + slotx);
        }
#pragma unroll
        for (int n = 0; n < NR; ++n) {
          int row = wn * WTN + n * 16 + r15;
          b[n] = *(const short8*)(Bs + row * 128 + slotx);
        }
#pragma unroll
        for (int m = 0; m < 4; ++m)
#pragma unroll
          for (int n = 0; n < NR; ++n)
            acc[m][n] = __builtin_amdgcn_mfma_f32_16x16x32_bf16(a[m], b[n], acc[m][n], 0, 0, 0);
      }
      __syncthreads();
    }
  }
  if (OUTBF) {
    // stage C tile in LDS (padded rows), then coalesced 16B stores
    ushort* Cs = (ushort*)smem;
#pragma unroll
    for (int n = 0; n < NR; ++n) {
      int col = wn * WTN + n * 16 + r15;
      float bv = bias ? bias[bn + col] : 0.f;
#pragma unroll
      for (int m = 0; m < 4; ++m) {
#pragma unroll
        for (int j = 0; j < 4; ++j) {
          int row = wm * 64 + m * 16 + g4 * 4 + j;
          float v = acc[m][n][j] + bv;
          if (RELU) v = fmaxf(v, 0.f);
          Cs[row * CP + col] = f2b(v);
        }
      }
    }
    __syncthreads();
    constexpr int C8 = BN / 8;           // ushort8 chunks per row
    for (int it = tid; it < 128 * C8; it += 256) {
      int row = it / C8, c8 = it % C8;
      if (bm + row < M)
        *(ushort8*)((ushort*)Cv + (size_t)(bm + row) * Nc + bn + c8 * 8) =
            *(const ushort8*)(Cs + row * CP + c8 * 8);
    }
  } else {
#pragma unroll
    for (int n = 0; n < NR; ++n) {
      int col = bn + wn * WTN + n * 16 + r15;
      float bv = bias ? bias[col] : 0.f;
#pragma unroll
      for (int m = 0; m < 4; ++m) {
#pragma unroll
        for (int j = 0; j < 4; ++j) {
          int row = bm + wm * 64 + m * 16 + g4 * 4 + j;
          if (row < M) {
            float v = acc[m][n][j] + bv;
            if (RELU) v = fmaxf(v, 0.f);
            ((float*)Cv)[(size_t)row * Nc + col] = v;
          }
        }
      }
    }
  }
}

// ------------------------------ fused MLP + output head ------------------------------
__global__ __launch_bounds__(256)
void mlp_out_k(const ushort* __restrict__ A1, const ushort* __restrict__ BT1,
               const ushort* __restrict__ A2, const ushort* __restrict__ BT2,
               const float* __restrict__ bias, const float* __restrict__ Wm2,
               const float* __restrict__ bm2, float* __restrict__ out, int M) {
  constexpr int NR = 8;      // 256/32
  constexpr int WTN = 128;
  __shared__ __align__(16) char As[128 * 64 * 2];
  __shared__ __align__(16) char Bs[256 * 64 * 2];
  const int tid = threadIdx.x;
  const int l = tid & 63;
  const int w = tid >> 6;
  const int wm = w >> 1, wn = w & 1;
  const int bm = blockIdx.x * 128;
  const int r15 = l & 15, g4 = l >> 4;

  f32x4 acc[4][NR];
  const f32x4 zz = {0.f, 0.f, 0.f, 0.f};
#pragma unroll
  for (int m = 0; m < 4; ++m)
#pragma unroll
    for (int n = 0; n < NR; ++n) acc[m][n] = zz;

  for (int pass = 0; pass < 2; ++pass) {
    const ushort* A = pass ? A2 : A1;
    const ushort* BT = pass ? BT2 : BT1;
    for (int k0 = 0; k0 < 256; k0 += 64) {
#pragma unroll
      for (int p = 0; p < 4; ++p) {
        int idx = tid + p * 256;
        int row = idx >> 3, slot = idx & 7;
        int kb = slot ^ (row & 7);
        int grow = bm + row; if (grow >= M) grow = M - 1;
        gl_lds16(A + (size_t)grow * 256 + k0 + kb * 8, As + idx * 16);
      }
#pragma unroll
      for (int p = 0; p < 8; ++p) {
        int idx = tid + p * 256;
        int row = idx >> 3, slot = idx & 7;
        int kb = slot ^ (row & 7);
        gl_lds16(BT + (size_t)row * 256 + k0 + kb * 8, Bs + idx * 16);
      }
      __syncthreads();
#pragma unroll
      for (int s = 0; s < 2; ++s) {
        short8 a[4], b[NR];
        const int slotx = (((s * 4 + g4) ^ (r15 & 7)) << 4);
#pragma unroll
        for (int m = 0; m < 4; ++m) {
          int row = wm * 64 + m * 16 + r15;
          a[m] = *(const short8*)(As + row * 128 + slotx);
        }
#pragma unroll
        for (int n = 0; n < NR; ++n) {
          int row = wn * WTN + n * 16 + r15;
          b[n] = *(const short8*)(Bs + row * 128 + slotx);
        }
#pragma unroll
        for (int m = 0; m < 4; ++m)
#pragma unroll
          for (int n = 0; n < NR; ++n)
            acc[m][n] = __builtin_amdgcn_mfma_f32_16x16x32_bf16(a[m], b[n], acc[m][n], 0, 0, 0);
      }
      __syncthreads();
    }
  }
  float bv[NR], w20[NR], w21[NR];
#pragma unroll
  for (int n = 0; n < NR; ++n) {
    int col = wn * WTN + n * 16 + r15;
    bv[n] = bias[col];
    w20[n] = Wm2[col * 2 + 0];
    w21[n] = Wm2[col * 2 + 1];
  }
  float* red = (float*)As;   // 2KB, LDS free after last barrier
#pragma unroll
  for (int m = 0; m < 4; ++m) {
#pragma unroll
    for (int j = 0; j < 4; ++j) {
      float p0 = 0.f, p1 = 0.f;
#pragma unroll
      for (int n = 0; n < NR; ++n) {
        float v = fmaxf(acc[m][n][j] + bv[n], 0.f);
        p0 += v * w20[n];
        p1 += v * w21[n];
      }
      p0 += __shfl_xor(p0, 1); p1 += __shfl_xor(p1, 1);
      p0 += __shfl_xor(p0, 2); p1 += __shfl_xor(p1, 2);
      p0 += __shfl_xor(p0, 4); p1 += __shfl_xor(p1, 4);
      p0 += __shfl_xor(p0, 8); p1 += __shfl_xor(p1, 8);
      if (r15 == 0) {
        int rl = wm * 64 + m * 16 + g4 * 4 + j;
        red[wn * 256 + rl * 2 + 0] = p0;
        red[wn * 256 + rl * 2 + 1] = p1;
      }
    }
  }
  __syncthreads();
  int rl = tid >> 1, j = tid & 1;
  int row = bm + rl;
  if (row < M)
    out[(size_t)row * 2 + j] = red[rl * 2 + j] + red[256 + rl * 2 + j] + bm2[j];
}

// ------------------------------ sbias[g] = dot(bq, Kmat[g]) ------------------------------
__global__ void sbias_k(const float* __restrict__ bq, const ushort* __restrict__ Kmat,
                        float* __restrict__ sbias) {
  int g = blockIdx.x * 4 + (threadIdx.x >> 6);
  int lane = threadIdx.x & 63;
  if (g >= 512) return;
  ushort4 kv = ((const ushort4*)(Kmat + (size_t)g * 256))[lane];
  float4 bv = ((const float4*)bq)[lane];
  float p = b2f(kv.x) * bv.x + b2f(kv.y) * bv.y + b2f(kv.z) * bv.z + b2f(kv.w) * bv.w;
  for (int off = 32; off; off >>= 1) p += __shfl_xor(p, off);
  if (lane == 0) sbias[g] = p;
}

// ------------------------------ softmax in place (bf16 logits -> bf16 P), scale 1/16 ------------------------------
__global__ void softmax_k(ushort* __restrict__ SP, int M) {
  int row = blockIdx.x * 4 + (threadIdx.x >> 6);
  int lane = threadIdx.x & 63;
  if (row >= M) return;
  ushort4* p = (ushort4*)(SP + (size_t)row * 512);
  ushort4 ua = p[lane];
  ushort4 ub = p[lane + 64];
  const float sc = 0.0625f;
  float ax = b2f(ua.x) * sc, ay = b2f(ua.y) * sc, az = b2f(ua.z) * sc, aw = b2f(ua.w) * sc;
  float bx = b2f(ub.x) * sc, by = b2f(ub.y) * sc, bz = b2f(ub.z) * sc, bw = b2f(ub.w) * sc;
  float m = fmaxf(fmaxf(fmaxf(ax, ay), fmaxf(az, aw)),
                  fmaxf(fmaxf(bx, by), fmaxf(bz, bw)));
  for (int off = 32; off; off >>= 1) m = fmaxf(m, __shfl_xor(m, off));
  ax = expf(ax - m); ay = expf(ay - m); az = expf(az - m); aw = expf(aw - m);
  bx = expf(bx - m); by = expf(by - m); bz = expf(bz - m); bw = expf(bw - m);
  float s = ax + ay + az + aw + bx + by + bz + bw;
  for (int off = 32; off; off >>= 1) s += __shfl_xor(s, off);
  float inv = 1.f / s;
  ushort4 oa, ob;
  oa.x = f2b(ax * inv); oa.y = f2b(ay * inv); oa.z = f2b(az * inv); oa.w = f2b(aw * inv);
  ob.x = f2b(bx * inv); ob.y = f2b(by * inv); ob.z = f2b(bz * inv); ob.w = f2b(bw * inv);
  p[lane] = oa;
  p[lane + 64] = ob;
}

// ------------------------------ launch ------------------------------
extern "C" void kernel_launch(void* const* d_in, const int* in_sizes, int n_in,
                              void* d_out, int out_size, void* d_ws, size_t ws_size,
                              hipStream_t stream) {
  const int N = NN, E = NE;
  const float* x   = (const float*)d_in[0];
  const int*   ei  = (const int*)d_in[1];
  const float* gc  = (const float*)d_in[2];
  const float* Wp  = (const float*)d_in[3];
  const float* bp  = (const float*)d_in[4];
  const float* W1l = (const float*)d_in[5];
  const float* b1l = (const float*)d_in[6];
  const float* W1r = (const float*)d_in[7];
  const float* W2l = (const float*)d_in[8];
  const float* b2l = (const float*)d_in[9];
  const float* W2r = (const float*)d_in[10];
  const float* Wq  = (const float*)d_in[11];
  const float* bq  = (const float*)d_in[12];
  const float* Wk  = (const float*)d_in[13];
  const float* bk  = (const float*)d_in[14];
  const float* Wv  = (const float*)d_in[15];
  const float* bv  = (const float*)d_in[16];
  const float* Wm1 = (const float*)d_in[17];
  const float* bm1 = (const float*)d_in[18];
  const float* Wm2 = (const float*)d_in[19];
  const float* bm2 = (const float*)d_in[20];
  float* out = (float*)d_out;

  char* base = (char*)d_ws;
  size_t off = 0;
  auto take = [&](size_t bytes) -> void* {
    void* r = base + off;
    off += (bytes + 255) & ~(size_t)255;
    return r;
  };
  // CSR + misc
  int* cnt    = (int*)take((size_t)N * 4);
  int* rowptr = (int*)take((size_t)(N + 1) * 4);
  int* loc    = (int*)take((size_t)E * 4);
  int* eidx   = (int*)take((size_t)E * 4);
  int* eflag  = (int*)take(256);
  int* bsum   = (int*)take(NB1 * 4);
  int* boff   = (int*)take(NB1 * 4);
  // bf16 weights
  ushort* WpT   = (ushort*)take((size_t)64 * 128 * 2);
  ushort* W1lT  = (ushort*)take((size_t)256 * 64 * 2);
  ushort* W1rT  = (ushort*)take((size_t)256 * 64 * 2);
  ushort* W2lT  = (ushort*)take((size_t)256 * 256 * 2);
  ushort* W2rT  = (ushort*)take((size_t)256 * 256 * 2);
  ushort* WkT   = (ushort*)take((size_t)256 * 256 * 2);
  ushort* WvT   = (ushort*)take((size_t)256 * 256 * 2);
  ushort* Wqb   = (ushort*)take((size_t)256 * 256 * 2);
  ushort* Wm1aT = (ushort*)take((size_t)256 * 256 * 2);
  ushort* Wm1bT = (ushort*)take((size_t)256 * 256 * 2);
  // attention small
  ushort* gcb   = (ushort*)take((size_t)512 * 256 * 2);
  ushort* Kmatb = (ushort*)take((size_t)512 * 256 * 2);
  float*  Vmatf = (float*)take((size_t)512 * 256 * 4);
  ushort* VT    = (ushort*)take((size_t)256 * 512 * 2);
  ushort* KWqT  = (ushort*)take((size_t)512 * 256 * 2);
  float*  sbias = (float*)take((size_t)512 * 4);
  // region U: pre-loop {xb, x_emb, mean1} then chunk buffers (2560B/row)
  const size_t szU_pre = (size_t)N * 128 * 2 + (size_t)N * 64 * 2 + (size_t)N * 64 * 2;
  const size_t szU_chunk = (size_t)CR * 2560;
  char* U = (char*)take(szU_pre > szU_chunk ? szU_pre : szU_chunk);
  ushort* h = (ushort*)take((size_t)N * 256 * 2);   // live whole run
  if (off > ws_size) return;

  ushort* xb    = (ushort*)U;
  ushort* x_emb = (ushort*)(U + (size_t)N * 128 * 2);
  ushort* mean1 = (ushort*)(U + (size_t)N * 128 * 2 + (size_t)N * 64 * 2);
  ushort* mean2_c  = (ushort*)U;                        // CR*256 bf16
  ushort* h2_c     = (ushort*)(U + (size_t)CR * 512);   // CR*256 bf16
  ushort* SP_c     = (ushort*)(U + (size_t)CR * 1024);  // CR*512 bf16 (S then P)
  ushort* g_c      = (ushort*)(U + (size_t)CR * 2048);  // CR*256 bf16

  const int MB = (N + 127) / 128;
  const int n4 = N * 128 / 4;
  dim3 thr(256);

  // CSR build (single atomic pass; cvt of x fused into count via role-split)
  zero_i32_k<<<(N + 255) / 256, thr, 0, stream>>>(cnt, N);
  detect_i64_k<<<1, 256, 0, stream>>>(ei, eflag);
  count_cvt_k<<<CNTB + (n4 + 255) / 256, thr, 0, stream>>>(ei, eflag, cnt, loc, x, xb, E, n4);
  scan1_k<<<NB1, thr, 0, stream>>>(cnt, rowptr, bsum, N);
  scan2_k<<<1, 128, 0, stream>>>(bsum, boff, NB1);
  scan3_k<<<(N + 255) / 256, thr, 0, stream>>>(rowptr, boff, N);
  fill_edges_k<<<(E + 255) / 256, thr, 0, stream>>>(ei, eflag, rowptr, loc, eidx, E);

  // merged weight conversions
  {
    CvtJobs jb;
    const float* s_[NJOB] = {gc, Wq, Wp, W1l, W1r, W2l, W2r, Wk, Wv, Wm1, Wm1};
    ushort* d_[NJOB] = {gcb, Wqb, WpT, W1lT, W1rT, W2lT, W2rT, WkT, WvT, Wm1aT, Wm1bT};
    int R_[NJOB] = {512, 256, 128, 64, 64, 256, 256, 256, 256, 256, 256};
    int C_[NJOB] = {256, 256, 64, 256, 256, 256, 256, 256, 256, 256, 256};
    int o_[NJOB] = {0, 0, 0, 0, 0, 0, 0, 0, 0, 0, 256};
    int t_[NJOB] = {0, 0, 1, 1, 1, 1, 1, 1, 1, 1, 1};
    for (int j = 0; j < NJOB; ++j) {
      jb.src[j] = s_[j]; jb.dst[j] = d_[j]; jb.R[j] = R_[j]; jb.C[j] = C_[j];
      jb.off[j] = o_[j]; jb.tr[j] = t_[j];
    }
    wcvt_k<<<dim3(32, NJOB), thr, 0, stream>>>(jb);
  }

  // attention pre: Kmat(bf16), Vmat(f32)->VT, KWqT = Kmat @ Wq^T, sbias
  mfma_gemm_k<128, false, true><<<dim3(4, 2), thr, 0, stream>>>(
      gcb, WkT, 256, nullptr, nullptr, 0, bk, Kmatb, 512, 256);
  mfma_gemm_k<128, false, false><<<dim3(4, 2), thr, 0, stream>>>(
      gcb, WvT, 256, nullptr, nullptr, 0, bv, Vmatf, 512, 256);
  tcvt_k<<<(512 * 256 + 255) / 256, thr, 0, stream>>>(Vmatf, VT, 512, 256, 0);
  mfma_gemm_k<128, false, true><<<dim3(4, 2), thr, 0, stream>>>(
      Kmatb, Wqb, 256, nullptr, nullptr, 0, nullptr, KWqT, 512, 256);
  sbias_k<<<128, thr, 0, stream>>>(bq, Kmatb, sbias);

  // embed: x_emb = relu(xb @ Wp + bp)
  mfma_gemm_k<64, true, true><<<dim3(MB, 1), thr, 0, stream>>>(
      xb, WpT, 128, nullptr, nullptr, 0, bp, x_emb, N, 64);
  // SAGE1
  agg64_k<<<(N + 3) / 4, thr, 0, stream>>>(x_emb, rowptr, eidx, mean1, 0, N);
  mfma_gemm_k<128, true, true><<<dim3(MB, 2), thr, 0, stream>>>(
      mean1, W1lT, 64, x_emb, W1rT, 64, b1l, h, N, 256);

  // chunked SAGE2 + attention + fused MLP/out
  for (int r0 = 0; r0 < N; r0 += CR) {
    const int CRc = (N - r0 < CR) ? (N - r0) : CR;
    const int MBc = (CRc + 127) / 128;
    agg256_k<<<(CRc + 3) / 4, thr, 0, stream>>>(h, rowptr, eidx, mean2_c, r0, CRc);
    mfma_gemm_k<128, false, true><<<dim3(MBc, 2), thr, 0, stream>>>(
        mean2_c, W2lT, 256, h + (size_t)r0 * 256, W2rT, 256, b2l, h2_c, CRc, 256);
    mfma_gemm_k<128, false, true><<<dim3(MBc, 4), thr, 0, stream>>>(
        h2_c, KWqT, 256, nullptr, nullptr, 0, sbias, SP_c, CRc, 512);
    softmax_k<<<(CRc + 3) / 4, thr, 0, stream>>>(SP_c, CRc);
    mfma_gemm_k<128, false, true><<<dim3(MBc, 2), thr, 0, stream>>>(
        SP_c, VT, 512, nullptr, nullptr, 0, nullptr, g_c, CRc, 256);
    mlp_out_k<<<dim3(MBc, 1), thr, 0, stream>>>(
        h2_c, Wm1aT, g_c, Wm1bT, bm1, Wm2, bm2, out + (size_t)r0 * 2, CRc);
  }
}

// Round 11
// 567.267 us; speedup vs baseline: 4.8870x; 1.0554x over previous
//
#include <hip/hip_runtime.h>
#include <cstdint>
#include <cstddef>

// GAAPModelB on MI355X: bf16-MFMA GEMM stack + CSR gather aggregation.
// N=100000, E=800000, IN=128, H=256, G=512. Chunked post-SAGE1 pipeline.
// R11: double-buffered 2-phase GEMM pipeline (stage t+1 issued before
// compute t, ONE barrier per K-step) — T3-minimum recipe. LDS 32->64KB.

#define NN 100000
#define NE 800000
#define CR 32768   // chunk rows
#define NB1 98     // ceil(100000/1024) scan blocks
#define CNTB 3125  // ceil(800000/256) count-role blocks

typedef __attribute__((ext_vector_type(8))) short short8;
typedef __attribute__((ext_vector_type(8))) unsigned short ushort8;
typedef __attribute__((ext_vector_type(4))) float f32x4;

__device__ __forceinline__ float b2f(ushort u) {
  union { unsigned u; float f; } v; v.u = ((unsigned)u) << 16; return v.f;
}
__device__ __forceinline__ ushort f2b(float f) {
  union { float f; unsigned u; } v; v.f = f;
  unsigned r = v.u + 0x7FFFu + ((v.u >> 16) & 1u);
  return (ushort)(r >> 16);
}
__device__ __forceinline__ void gl_lds16(const void* g, void* l) {
  __builtin_amdgcn_global_load_lds((const __attribute__((address_space(1))) void*)g,
                                   (__attribute__((address_space(3))) void*)l, 16, 0, 0);
}

// ------------------------------ utility ------------------------------
__global__ void zero_i32_k(int* __restrict__ p, int n) {
  int i = blockIdx.x * 256 + threadIdx.x;
  if (i < n) p[i] = 0;
}

// flag=1 iff edge_index is int64 (odd words of first 256 entries all zero)
__global__ void detect_i64_k(const int* __restrict__ ei, int* __restrict__ flag) {
  __shared__ int ok;
  int t = threadIdx.x;
  if (t == 0) ok = 1;
  __syncthreads();
  if (ei[2 * t + 1] != 0) ok = 0;
  __syncthreads();
  if (t == 0) *flag = ok;
}

// transpose-convert: dst[c*R + r] = bf16(src[(row_off+r)*C + c])
__global__ void tcvt_k(const float* __restrict__ src, ushort* __restrict__ dst,
                       int R, int C, int row_off) {
  int i = blockIdx.x * 256 + threadIdx.x;
  if (i < R * C) {
    int r = i / C, c = i % C;
    dst[(size_t)c * R + r] = f2b(src[(size_t)(row_off + r) * C + c]);
  }
}

// merged small weight conversions: 11 jobs, grid.y = job
#define NJOB 11
struct CvtJobs {
  const float* src[NJOB];
  ushort* dst[NJOB];
  int R[NJOB], C[NJOB], off[NJOB], tr[NJOB];
};
__global__ void wcvt_k(CvtJobs jb) {
  const int j = blockIdx.y;
  const int Cj = jb.C[j], Rj = jb.R[j];
  const int n = Rj * Cj;
  for (int i = blockIdx.x * 256 + threadIdx.x; i < n; i += gridDim.x * 256) {
    if (jb.tr[j]) {
      int r = i / Cj, c = i % Cj;
      jb.dst[j][(size_t)c * Rj + r] = f2b(jb.src[j][(size_t)(jb.off[j] + r) * Cj + c]);
    } else {
      jb.dst[j][i] = f2b(jb.src[j][i]);
    }
  }
}

// ------------------------------ CSR build ------------------------------
// role-split: blocks [0,CNTB) count edges (atomicAdd, store old as loc);
// blocks [CNTB,...) convert x f32->bf16 (streaming, overlaps atomic stalls).
__global__ void count_cvt_k(const int* __restrict__ ei, const int* __restrict__ flag,
                            int* __restrict__ cnt, int* __restrict__ loc,
                            const float* __restrict__ x, ushort* __restrict__ xb,
                            int E, int n4) {
  int b = blockIdx.x;
  if (b < CNTB) {
    int i = b * 256 + threadIdx.x;
    if (i >= E) return;
    const bool i64 = (*flag != 0);
    unsigned d = (unsigned)(i64 ? ei[2 * E + 2 * i] : ei[E + i]);
    int p = -1;
    if (d < NN) p = atomicAdd(&cnt[d], 1);
    loc[i] = p;
  } else {
    int i = (b - CNTB) * 256 + threadIdx.x;
    if (i < n4) {
      float4 v = ((const float4*)x)[i];
      ushort4 o; o.x = f2b(v.x); o.y = f2b(v.y); o.z = f2b(v.z); o.w = f2b(v.w);
      ((ushort4*)xb)[i] = o;
    }
  }
}

__global__ __launch_bounds__(256)
void scan1_k(const int* __restrict__ cnt, int* __restrict__ rowptr,
             int* __restrict__ bsum, int n) {
  __shared__ int ls[256];
  const int b = blockIdx.x, t = threadIdx.x;
  const int base = b * 1024 + t * 4;
  int v[4]; int s = 0;
#pragma unroll
  for (int j = 0; j < 4; ++j) { int i = base + j; v[j] = (i < n) ? cnt[i] : 0; s += v[j]; }
  ls[t] = s; __syncthreads();
  int x = s;
  for (int o = 1; o < 256; o <<= 1) {
    int a = (t >= o) ? ls[t - o] : 0; __syncthreads();
    x += a; ls[t] = x; __syncthreads();
  }
  int run = x - s;
#pragma unroll
  for (int j = 0; j < 4; ++j) { run += v[j]; int i = base + j; if (i < n) rowptr[i + 1] = run; }
  if (t == 255) bsum[b] = x;
}

__global__ void scan2_k(const int* __restrict__ bsum, int* __restrict__ boff, int nb) {
  __shared__ int ls[128];
  int t = threadIdx.x;
  int v = (t < nb) ? bsum[t] : 0;
  ls[t] = v; __syncthreads();
  int x = v;
  for (int o = 1; o < 128; o <<= 1) {
    int a = (t >= o) ? ls[t - o] : 0; __syncthreads();
    x += a; ls[t] = x; __syncthreads();
  }
  if (t < nb) boff[t] = x - v;
}

__global__ void scan3_k(int* __restrict__ rowptr, const int* __restrict__ boff, int n) {
  int i = blockIdx.x * 256 + threadIdx.x;
  if (i == 0) rowptr[0] = 0;
  if (i < n) rowptr[i + 1] += boff[i >> 10];
}

// atomic-free fill: position = rowptr[d] + loc[i]
__global__ void fill_edges_k(const int* __restrict__ ei, const int* __restrict__ flag,
                             const int* __restrict__ rowptr, const int* __restrict__ loc,
                             int* __restrict__ eidx, int E) {
  int i = blockIdx.x * 256 + threadIdx.x;
  if (i >= E) return;
  const bool i64 = (*flag != 0);
  unsigned s = (unsigned)(i64 ? ei[2 * i] : ei[i]);
  unsigned d = (unsigned)(i64 ? ei[2 * E + 2 * i] : ei[E + i]);
  int lc = loc[i];
  if (d < NN && s < NN && lc >= 0) {
    unsigned p = (unsigned)(rowptr[d] + lc);
    if (p < (unsigned)E) eidx[p] = (int)s;
  }
}

// ------------------------------ aggregation ------------------------------
// agg64: wave = 4 edge-slots x 16 dim-lanes (ushort4). Dependent chain /4.
__global__ void agg64_k(const ushort* __restrict__ X, const int* __restrict__ rowptr,
                        const int* __restrict__ eidx, ushort* __restrict__ mean,
                        int r0, int M) {
  int nl = blockIdx.x * 4 + (threadIdx.x >> 6);
  int l = threadIdx.x & 63;
  int e4 = l >> 4;      // edge slot 0..3
  int d4 = l & 15;      // dim group (4 dims)
  if (nl >= M) return;
  int node = r0 + nl;
  int s = rowptr[node], e = rowptr[node + 1];
  float a0 = 0.f, a1 = 0.f, a2 = 0.f, a3 = 0.f;
  for (int i = s + e4; i < e; i += 4) {
    unsigned sc = (unsigned)eidx[i];
    if (sc < NN) {
      ushort4 v = ((const ushort4*)(X + (size_t)sc * 64))[d4];
      a0 += b2f(v.x); a1 += b2f(v.y); a2 += b2f(v.z); a3 += b2f(v.w);
    }
  }
  a0 += __shfl_xor(a0, 16); a0 += __shfl_xor(a0, 32);
  a1 += __shfl_xor(a1, 16); a1 += __shfl_xor(a1, 32);
  a2 += __shfl_xor(a2, 16); a2 += __shfl_xor(a2, 32);
  a3 += __shfl_xor(a3, 16); a3 += __shfl_xor(a3, 32);
  if (e4 == 0) {
    float inv = 1.f / (float)max(e - s, 1);
    ushort4 o; o.x = f2b(a0 * inv); o.y = f2b(a1 * inv); o.z = f2b(a2 * inv); o.w = f2b(a3 * inv);
    ((ushort4*)(mean + (size_t)nl * 64))[d4] = o;
  }
}

// agg256: wave = 2 edge-slots x 32 lanes x ushort8 (512B row), unroll-2.
__global__ void agg256_k(const ushort* __restrict__ X, const int* __restrict__ rowptr,
                         const int* __restrict__ eidx, ushort* __restrict__ mean,
                         int r0, int M) {
  int nl = blockIdx.x * 4 + (threadIdx.x >> 6);
  int l = threadIdx.x & 63;
  int g = l >> 5;       // edge slot 0..1
  int d = l & 31;       // 8-dim group
  if (nl >= M) return;
  int node = r0 + nl;
  int s = rowptr[node], e = rowptr[node + 1];
  float a[8], c[8];
#pragma unroll
  for (int k = 0; k < 8; ++k) { a[k] = 0.f; c[k] = 0.f; }
  for (int i = s + g; i < e; i += 4) {
    unsigned s0 = (unsigned)eidx[i];
    if (s0 < NN) {
      ushort8 v = *(const ushort8*)(X + (size_t)s0 * 256 + d * 8);
#pragma unroll
      for (int k = 0; k < 8; ++k) a[k] += b2f((ushort)v[k]);
    }
    int i2 = i + 2;
    if (i2 < e) {
      unsigned s1 = (unsigned)eidx[i2];
      if (s1 < NN) {
        ushort8 v = *(const ushort8*)(X + (size_t)s1 * 256 + d * 8);
#pragma unroll
        for (int k = 0; k < 8; ++k) c[k] += b2f((ushort)v[k]);
      }
    }
  }
  float inv = 1.f / (float)max(e - s, 1);
  ushort8 o;
#pragma unroll
  for (int k = 0; k < 8; ++k) {
    float t = a[k] + c[k];
    t += __shfl_xor(t, 32);
    o[k] = (short)f2b(t * inv);
  }
  if (g == 0) *(ushort8*)(mean + (size_t)nl * 256 + d * 8) = o;
}

// ------------------------------ bf16 MFMA GEMM (2-phase dbuf) ------------------------------
// C[M,Nc] = act(A1@B1 + A2@B2 + bias): A [M,K] bf16 rm, BT [Nc,K] bf16 rm.
// BM=128, BN in {64,128}, BK=64, 256 thr = 4 waves (2x2), 16x16x32 MFMA.
// Double-buffered LDS: stage tile t+1 BEFORE computing tile t; ONE barrier
// per K-step (its implicit vmcnt(0) drains the overlapped stage).
// bf16 epilogue via padded LDS tile -> ushort8 coalesced stores.
template<int BN, bool RELU, bool OUTBF>
__global__ __launch_bounds__(256)
void mfma_gemm_k(const ushort* __restrict__ A1, const ushort* __restrict__ BT1, int K1,
                 const ushort* __restrict__ A2, const ushort* __restrict__ BT2, int K2,
                 const float* __restrict__ bias, void* __restrict__ Cv, int M, int Nc) {
  constexpr int NR = BN / 32;
  constexpr int WTN = BN / 2;
  constexpr int ABYT = 128 * 64 * 2;
  constexpr int BBYT = BN * 64 * 2;
  constexpr int BUF = ABYT + BBYT;                 // 24KB (BN=64) / 32KB (BN=128)
  constexpr int CP = BN + 8;                       // padded C-tile row (ushorts)
  constexpr int SZ_EPI = 128 * CP * 2;
  constexpr int SZ = (2 * BUF > SZ_EPI) ? 2 * BUF : SZ_EPI;
  __shared__ __align__(16) char smem[SZ];
  const int tid = threadIdx.x;
  const int l = tid & 63;
  const int w = tid >> 6;
  const int wm = w >> 1, wn = w & 1;
  const int bm = blockIdx.x * 128, bn = blockIdx.y * BN;
  const int r15 = l & 15, g4 = l >> 4;

  const int nt1 = K1 >> 6;
  const int nt2 = A2 ? (K2 >> 6) : 0;
  const int nt = nt1 + nt2;

  auto STAGE = [&](int buf, int t) {
    const ushort* A = (t < nt1) ? A1 : A2;
    const ushort* BT = (t < nt1) ? BT1 : BT2;
    const int K = (t < nt1) ? K1 : K2;
    const int k0 = ((t < nt1) ? t : t - nt1) << 6;
    char* As = smem + buf * BUF;
    char* Bs = As + ABYT;
#pragma unroll
    for (int p = 0; p < 4; ++p) {
      int idx = tid + p * 256;
      int row = idx >> 3, slot = idx & 7;
      int kb = slot ^ (row & 7);
      int grow = bm + row; if (grow >= M) grow = M - 1;
      gl_lds16(A + (size_t)grow * K + k0 + kb * 8, As + idx * 16);
    }
#pragma unroll
    for (int p = 0; p < BN / 32; ++p) {
      int idx = tid + p * 256;
      int row = idx >> 3, slot = idx & 7;
      int kb = slot ^ (row & 7);
      gl_lds16(BT + (size_t)(bn + row) * K + k0 + kb * 8, Bs + idx * 16);
    }
  };

  f32x4 acc[4][NR];
  const f32x4 zz = {0.f, 0.f, 0.f, 0.f};
#pragma unroll
  for (int m = 0; m < 4; ++m)
#pragma unroll
    for (int n = 0; n < NR; ++n) acc[m][n] = zz;

  STAGE(0, 0);
  int cur = 0;
  for (int t = 0; t < nt; ++t) {
    __syncthreads();                 // tile t staged & visible (drains vmcnt)
    if (t + 1 < nt) STAGE(cur ^ 1, t + 1);   // overlap next stage with compute
    const char* As = smem + cur * BUF;
    const char* Bs = As + ABYT;
#pragma unroll
    for (int s = 0; s < 2; ++s) {
      short8 a[4], b[NR];
      const int slotx = (((s * 4 + g4) ^ (r15 & 7)) << 4);
#pragma unroll
      for (int m = 0; m < 4; ++m) {
        int row = wm * 64 + m * 16 + r15;
        a[m] = *(const short8*)(As + row * 128 + slotx);
      }
#pragma unroll
      for (int n = 0; n < NR; ++n) {
        int row = wn * WTN + n * 16 + r15;
        b[n] = *(const short8*)(Bs + row * 128 + slotx);
      }
#pragma unroll
      for (int m = 0; m < 4; ++m)
#pragma unroll
        for (int n = 0; n < NR; ++n)
          acc[m][n] = __builtin_amdgcn_mfma_f32_16x16x32_bf16(a[m], b[n], acc[m][n], 0, 0, 0);
    }
    cur ^= 1;
  }
  __syncthreads();                   // all reads done; smem reusable for epilogue
  if (OUTBF) {
    // stage C tile in LDS (padded rows), then coalesced 16B stores
    ushort* Cs = (ushort*)smem;
#pragma unroll
    for (int n = 0; n < NR; ++n) {
      int col = wn * WTN + n * 16 + r15;
      float bv = bias ? bias[bn + col] : 0.f;
#pragma unroll
      for (int m = 0; m < 4; ++m) {
#pragma unroll
        for (int j = 0; j < 4; ++j) {
          int row = wm * 64 + m * 16 + g4 * 4 + j;
          float v = acc[m][n][j] + bv;
          if (RELU) v = fmaxf(v, 0.f);
          Cs[row * CP + col] = f2b(v);
        }
      }
    }
    __syncthreads();
    constexpr int C8 = BN / 8;           // ushort8 chunks per row
    for (int it = tid; it < 128 * C8; it += 256) {
      int row = it / C8, c8 = it % C8;
      if (bm + row < M)
        *(ushort8*)((ushort*)Cv + (size_t)(bm + row) * Nc + bn + c8 * 8) =
            *(const ushort8*)(Cs + row * CP + c8 * 8);
    }
  } else {
#pragma unroll
    for (int n = 0; n < NR; ++n) {
      int col = bn + wn * WTN + n * 16 + r15;
      float bv = bias ? bias[col] : 0.f;
#pragma unroll
      for (int m = 0; m < 4; ++m) {
#pragma unroll
        for (int j = 0; j < 4; ++j) {
          int row = bm + wm * 64 + m * 16 + g4 * 4 + j;
          if (row < M) {
            float v = acc[m][n][j] + bv;
            if (RELU) v = fmaxf(v, 0.f);
            ((float*)Cv)[(size_t)row * Nc + col] = v;
          }
        }
      }
    }
  }
}

// ------------------------------ fused MLP + output head ------------------------------
__global__ __launch_bounds__(256)
void mlp_out_k(const ushort* __restrict__ A1, const ushort* __restrict__ BT1,
               const ushort* __restrict__ A2, const ushort* __restrict__ BT2,
               const float* __restrict__ bias, const float* __restrict__ Wm2,
               const float* __restrict__ bm2, float* __restrict__ out, int M) {
  constexpr int NR = 8;      // 256/32
  constexpr int WTN = 128;
  __shared__ __align__(16) char As[128 * 64 * 2];
  __shared__ __align__(16) char Bs[256 * 64 * 2];
  const int tid = threadIdx.x;
  const int l = tid & 63;
  const int w = tid >> 6;
  const int wm = w >> 1, wn = w & 1;
  const int bm = blockIdx.x * 128;
  const int r15 = l & 15, g4 = l >> 4;

  f32x4 acc[4][NR];
  const f32x4 zz = {0.f, 0.f, 0.f, 0.f};
#pragma unroll
  for (int m = 0; m < 4; ++m)
#pragma unroll
    for (int n = 0; n < NR; ++n) acc[m][n] = zz;

  for (int pass = 0; pass < 2; ++pass) {
    const ushort* A = pass ? A2 : A1;
    const ushort* BT = pass ? BT2 : BT1;
    for (int k0 = 0; k0 < 256; k0 += 64) {
#pragma unroll
      for (int p = 0; p < 4; ++p) {
        int idx = tid + p * 256;
        int row = idx >> 3, slot = idx & 7;
        int kb = slot ^ (row & 7);
        int grow = bm + row; if (grow >= M) grow = M - 1;
        gl_lds16(A + (size_t)grow * 256 + k0 + kb * 8, As + idx * 16);
      }
#pragma unroll
      for (int p = 0; p < 8; ++p) {
        int idx = tid + p * 256;
        int row = idx >> 3, slot = idx & 7;
        int kb = slot ^ (row & 7);
        gl_lds16(BT + (size_t)row * 256 + k0 + kb * 8, Bs + idx * 16);
      }
      __syncthreads();
#pragma unroll
      for (int s = 0; s < 2; ++s) {
        short8 a[4], b[NR];
        const int slotx = (((s * 4 + g4) ^ (r15 & 7)) << 4);
#pragma unroll
        for (int m = 0; m < 4; ++m) {
          int row = wm * 64 + m * 16 + r15;
          a[m] = *(const short8*)(As + row * 128 + slotx);
        }
#pragma unroll
        for (int n = 0; n < NR; ++n) {
          int row = wn * WTN + n * 16 + r15;
          b[n] = *(const short8*)(Bs + row * 128 + slotx);
        }
#pragma unroll
        for (int m = 0; m < 4; ++m)
#pragma unroll
          for (int n = 0; n < NR; ++n)
            acc[m][n] = __builtin_amdgcn_mfma_f32_16x16x32_bf16(a[m], b[n], acc[m][n], 0, 0, 0);
      }
      __syncthreads();
    }
  }
  float bv[NR], w20[NR], w21[NR];
#pragma unroll
  for (int n = 0; n < NR; ++n) {
    int col = wn * WTN + n * 16 + r15;
    bv[n] = bias[col];
    w20[n] = Wm2[col * 2 + 0];
    w21[n] = Wm2[col * 2 + 1];
  }
  float* red = (float*)As;   // 2KB, LDS free after last barrier
#pragma unroll
  for (int m = 0; m < 4; ++m) {
#pragma unroll
    for (int j = 0; j < 4; ++j) {
      float p0 = 0.f, p1 = 0.f;
#pragma unroll
      for (int n = 0; n < NR; ++n) {
        float v = fmaxf(acc[m][n][j] + bv[n], 0.f);
        p0 += v * w20[n];
        p1 += v * w21[n];
      }
      p0 += __shfl_xor(p0, 1); p1 += __shfl_xor(p1, 1);
      p0 += __shfl_xor(p0, 2); p1 += __shfl_xor(p1, 2);
      p0 += __shfl_xor(p0, 4); p1 += __shfl_xor(p1, 4);
      p0 += __shfl_xor(p0, 8); p1 += __shfl_xor(p1, 8);
      if (r15 == 0) {
        int rl = wm * 64 + m * 16 + g4 * 4 + j;
        red[wn * 256 + rl * 2 + 0] = p0;
        red[wn * 256 + rl * 2 + 1] = p1;
      }
    }
  }
  __syncthreads();
  int rl = tid >> 1, j = tid & 1;
  int row = bm + rl;
  if (row < M)
    out[(size_t)row * 2 + j] = red[rl * 2 + j] + red[256 + rl * 2 + j] + bm2[j];
}

// ------------------------------ sbias[g] = dot(bq, Kmat[g]) ------------------------------
__global__ void sbias_k(const float* __restrict__ bq, const ushort* __restrict__ Kmat,
                        float* __restrict__ sbias) {
  int g = blockIdx.x * 4 + (threadIdx.x >> 6);
  int lane = threadIdx.x & 63;
  if (g >= 512) return;
  ushort4 kv = ((const ushort4*)(Kmat + (size_t)g * 256))[lane];
  float4 bv = ((const float4*)bq)[lane];
  float p = b2f(kv.x) * bv.x + b2f(kv.y) * bv.y + b2f(kv.z) * bv.z + b2f(kv.w) * bv.w;
  for (int off = 32; off; off >>= 1) p += __shfl_xor(p, off);
  if (lane == 0) sbias[g] = p;
}

// ------------------------------ softmax in place (bf16 logits -> bf16 P), scale 1/16 ------------------------------
__global__ void softmax_k(ushort* __restrict__ SP, int M) {
  int row = blockIdx.x * 4 + (threadIdx.x >> 6);
  int lane = threadIdx.x & 63;
  if (row >= M) return;
  ushort4* p = (ushort4*)(SP + (size_t)row * 512);
  ushort4 ua = p[lane];
  ushort4 ub = p[lane + 64];
  const float sc = 0.0625f;
  float ax = b2f(ua.x) * sc, ay = b2f(ua.y) * sc, az = b2f(ua.z) * sc, aw = b2f(ua.w) * sc;
  float bx = b2f(ub.x) * sc, by = b2f(ub.y) * sc, bz = b2f(ub.z) * sc, bw = b2f(ub.w) * sc;
  float m = fmaxf(fmaxf(fmaxf(ax, ay), fmaxf(az, aw)),
                  fmaxf(fmaxf(bx, by), fmaxf(bz, bw)));
  for (int off = 32; off; off >>= 1) m = fmaxf(m, __shfl_xor(m, off));
  ax = expf(ax - m); ay = expf(ay - m); az = expf(az - m); aw = expf(aw - m);
  bx = expf(bx - m); by = expf(by - m); bz = expf(bz - m); bw = expf(bw - m);
  float s = ax + ay + az + aw + bx + by + bz + bw;
  for (int off = 32; off; off >>= 1) s += __shfl_xor(s, off);
  float inv = 1.f / s;
  ushort4 oa, ob;
  oa.x = f2b(ax * inv); oa.y = f2b(ay * inv); oa.z = f2b(az * inv); oa.w = f2b(aw * inv);
  ob.x = f2b(bx * inv); ob.y = f2b(by * inv); ob.z = f2b(bz * inv); ob.w = f2b(bw * inv);
  p[lane] = oa;
  p[lane + 64] = ob;
}

// ------------------------------ launch ------------------------------
extern "C" void kernel_launch(void* const* d_in, const int* in_sizes, int n_in,
                              void* d_out, int out_size, void* d_ws, size_t ws_size,
                              hipStream_t stream) {
  const int N = NN, E = NE;
  const float* x   = (const float*)d_in[0];
  const int*   ei  = (const int*)d_in[1];
  const float* gc  = (const float*)d_in[2];
  const float* Wp  = (const float*)d_in[3];
  const float* bp  = (const float*)d_in[4];
  const float* W1l = (const float*)d_in[5];
  const float* b1l = (const float*)d_in[6];
  const float* W1r = (const float*)d_in[7];
  const float* W2l = (const float*)d_in[8];
  const float* b2l = (const float*)d_in[9];
  const float* W2r = (const float*)d_in[10];
  const float* Wq  = (const float*)d_in[11];
  const float* bq  = (const float*)d_in[12];
  const float* Wk  = (const float*)d_in[13];
  const float* bk  = (const float*)d_in[14];
  const float* Wv  = (const float*)d_in[15];
  const float* bv  = (const float*)d_in[16];
  const float* Wm1 = (const float*)d_in[17];
  const float* bm1 = (const float*)d_in[18];
  const float* Wm2 = (const float*)d_in[19];
  const float* bm2 = (const float*)d_in[20];
  float* out = (float*)d_out;

  char* base = (char*)d_ws;
  size_t off = 0;
  auto take = [&](size_t bytes) -> void* {
    void* r = base + off;
    off += (bytes + 255) & ~(size_t)255;
    return r;
  };
  // CSR + misc
  int* cnt    = (int*)take((size_t)N * 4);
  int* rowptr = (int*)take((size_t)(N + 1) * 4);
  int* loc    = (int*)take((size_t)E * 4);
  int* eidx   = (int*)take((size_t)E * 4);
  int* eflag  = (int*)take(256);
  int* bsum   = (int*)take(NB1 * 4);
  int* boff   = (int*)take(NB1 * 4);
  // bf16 weights
  ushort* WpT   = (ushort*)take((size_t)64 * 128 * 2);
  ushort* W1lT  = (ushort*)take((size_t)256 * 64 * 2);
  ushort* W1rT  = (ushort*)take((size_t)256 * 64 * 2);
  ushort* W2lT  = (ushort*)take((size_t)256 * 256 * 2);
  ushort* W2rT  = (ushort*)take((size_t)256 * 256 * 2);
  ushort* WkT   = (ushort*)take((size_t)256 * 256 * 2);
  ushort* WvT   = (ushort*)take((size_t)256 * 256 * 2);
  ushort* Wqb   = (ushort*)take((size_t)256 * 256 * 2);
  ushort* Wm1aT = (ushort*)take((size_t)256 * 256 * 2);
  ushort* Wm1bT = (ushort*)take((size_t)256 * 256 * 2);
  // attention small
  ushort* gcb   = (ushort*)take((size_t)512 * 256 * 2);
  ushort* Kmatb = (ushort*)take((size_t)512 * 256 * 2);
  float*  Vmatf = (float*)take((size_t)512 * 256 * 4);
  ushort* VT    = (ushort*)take((size_t)256 * 512 * 2);
  ushort* KWqT  = (ushort*)take((size_t)512 * 256 * 2);
  float*  sbias = (float*)take((size_t)512 * 4);
  // region U: pre-loop {xb, x_emb, mean1} then chunk buffers (2560B/row)
  const size_t szU_pre = (size_t)N * 128 * 2 + (size_t)N * 64 * 2 + (size_t)N * 64 * 2;
  const size_t szU_chunk = (size_t)CR * 2560;
  char* U = (char*)take(szU_pre > szU_chunk ? szU_pre : szU_chunk);
  ushort* h = (ushort*)take((size_t)N * 256 * 2);   // live whole run
  if (off > ws_size) return;

  ushort* xb    = (ushort*)U;
  ushort* x_emb = (ushort*)(U + (size_t)N * 128 * 2);
  ushort* mean1 = (ushort*)(U + (size_t)N * 128 * 2 + (size_t)N * 64 * 2);
  ushort* mean2_c  = (ushort*)U;                        // CR*256 bf16
  ushort* h2_c     = (ushort*)(U + (size_t)CR * 512);   // CR*256 bf16
  ushort* SP_c     = (ushort*)(U + (size_t)CR * 1024);  // CR*512 bf16 (S then P)
  ushort* g_c      = (ushort*)(U + (size_t)CR * 2048);  // CR*256 bf16

  const int MB = (N + 127) / 128;
  const int n4 = N * 128 / 4;
  dim3 thr(256);

  // CSR build (single atomic pass; cvt of x fused into count via role-split)
  zero_i32_k<<<(N + 255) / 256, thr, 0, stream>>>(cnt, N);
  detect_i64_k<<<1, 256, 0, stream>>>(ei, eflag);
  count_cvt_k<<<CNTB + (n4 + 255) / 256, thr, 0, stream>>>(ei, eflag, cnt, loc, x, xb, E, n4);
  scan1_k<<<NB1, thr, 0, stream>>>(cnt, rowptr, bsum, N);
  scan2_k<<<1, 128, 0, stream>>>(bsum, boff, NB1);
  scan3_k<<<(N + 255) / 256, thr, 0, stream>>>(rowptr, boff, N);
  fill_edges_k<<<(E + 255) / 256, thr, 0, stream>>>(ei, eflag, rowptr, loc, eidx, E);

  // merged weight conversions
  {
    CvtJobs jb;
    const float* s_[NJOB] = {gc, Wq, Wp, W1l, W1r, W2l, W2r, Wk, Wv, Wm1, Wm1};
    ushort* d_[NJOB] = {gcb, Wqb, WpT, W1lT, W1rT, W2lT, W2rT, WkT, WvT, Wm1aT, Wm1bT};
    int R_[NJOB] = {512, 256, 128, 64, 64, 256, 256, 256, 256, 256, 256};
    int C_[NJOB] = {256, 256, 64, 256, 256, 256, 256, 256, 256, 256, 256};
    int o_[NJOB] = {0, 0, 0, 0, 0, 0, 0, 0, 0, 0, 256};
    int t_[NJOB] = {0, 0, 1, 1, 1, 1, 1, 1, 1, 1, 1};
    for (int j = 0; j < NJOB; ++j) {
      jb.src[j] = s_[j]; jb.dst[j] = d_[j]; jb.R[j] = R_[j]; jb.C[j] = C_[j];
      jb.off[j] = o_[j]; jb.tr[j] = t_[j];
    }
    wcvt_k<<<dim3(32, NJOB), thr, 0, stream>>>(jb);
  }

  // attention pre: Kmat(bf16), Vmat(f32)->VT, KWqT = Kmat @ Wq^T, sbias
  mfma_gemm_k<128, false, true><<<dim3(4, 2), thr, 0, stream>>>(
      gcb, WkT, 256, nullptr, nullptr, 0, bk, Kmatb, 512, 256);
  mfma_gemm_k<128, false, false><<<dim3(4, 2), thr, 0, stream>>>(
      gcb, WvT, 256, nullptr, nullptr, 0, bv, Vmatf, 512, 256);
  tcvt_k<<<(512 * 256 + 255) / 256, thr, 0, stream>>>(Vmatf, VT, 512, 256, 0);
  mfma_gemm_k<128, false, true><<<dim3(4, 2), thr, 0, stream>>>(
      Kmatb, Wqb, 256, nullptr, nullptr, 0, nullptr, KWqT, 512, 256);
  sbias_k<<<128, thr, 0, stream>>>(bq, Kmatb, sbias);

  // embed: x_emb = relu(xb @ Wp + bp)
  mfma_gemm_k<64, true, true><<<dim3(MB, 1), thr, 0, stream>>>(
      xb, WpT, 128, nullptr, nullptr, 0, bp, x_emb, N, 64);
  // SAGE1
  agg64_k<<<(N + 3) / 4, thr, 0, stream>>>(x_emb, rowptr, eidx, mean1, 0, N);
  mfma_gemm_k<128, true, true><<<dim3(MB, 2), thr, 0, stream>>>(
      mean1, W1lT, 64, x_emb, W1rT, 64, b1l, h, N, 256);

  // chunked SAGE2 + attention + fused MLP/out
  for (int r0 = 0; r0 < N; r0 += CR) {
    const int CRc = (N - r0 < CR) ? (N - r0) : CR;
    const int MBc = (CRc + 127) / 128;
    agg256_k<<<(CRc + 3) / 4, thr, 0, stream>>>(h, rowptr, eidx, mean2_c, r0, CRc);
    mfma_gemm_k<128, false, true><<<dim3(MBc, 2), thr, 0, stream>>>(
        mean2_c, W2lT, 256, h + (size_t)r0 * 256, W2rT, 256, b2l, h2_c, CRc, 256);
    mfma_gemm_k<128, false, true><<<dim3(MBc, 4), thr, 0, stream>>>(
        h2_c, KWqT, 256, nullptr, nullptr, 0, sbias, SP_c, CRc, 512);
    softmax_k<<<(CRc + 3) / 4, thr, 0, stream>>>(SP_c, CRc);
    mfma_gemm_k<128, false, true><<<dim3(MBc, 2), thr, 0, stream>>>(
        SP_c, VT, 512, nullptr, nullptr, 0, nullptr, g_c, CRc, 256);
    mlp_out_k<<<dim3(MBc, 1), thr, 0, stream>>>(
        h2_c, Wm1aT, g_c, Wm1bT, bm1, Wm2, bm2, out + (size_t)r0 * 2, CRc);
  }
}